// Round 6
// baseline (1049.384 us; speedup 1.0000x reference)
//
#include <hip/hip_runtime.h>
#include <math.h>

#define HID 128

__device__ __forceinline__ float gelu_f(float x){
  return 0.5f*x*(1.0f+erff(x*0.70710678118654752440f));
}

// ---- fused KQV GEMM for both node types ----
// o[row, j] = sum_k x[row,k]*W[k,j] + b[j]   (x is nrows x 128, W is 128 x 384)
// 128 threads; RPB rows/block; k stepped by 4 with float4 LDS broadcast reads.
template<int RPB>
__global__ void rowmm2(const float* __restrict__ xa, const float* __restrict__ xb,
                       const float* __restrict__ Wa, const float* __restrict__ Wb,
                       const float* __restrict__ ba_, const float* __restrict__ bb_,
                       float* __restrict__ oa, float* __restrict__ ob, int Na, int Nb) {
  const int OUT = 384, NJ = 3;
  int nba = (Na + RPB - 1)/RPB;
  const float *x, *W, *b; float* o; int nrows, r0;
  if ((int)blockIdx.x < nba) { x=xa; W=Wa; b=ba_; o=oa; nrows=Na; r0=blockIdx.x*RPB; }
  else { x=xb; W=Wb; b=bb_; o=ob; nrows=Nb; r0=(blockIdx.x-nba)*RPB; }
  int t = threadIdx.x;            // 128 threads
  __shared__ float xs[RPB][128];
#pragma unroll
  for (int r = 0; r < RPB; r++) {
    int row = r0 + r;
    xs[r][t] = (row < nrows) ? x[(size_t)row*128 + t] : 0.f;
  }
  __syncthreads();
  float acc[RPB][NJ] = {};
  for (int k0 = 0; k0 < 128; k0 += 4) {
    float wv[4][NJ];
#pragma unroll
    for (int kk = 0; kk < 4; kk++)
#pragma unroll
      for (int jj = 0; jj < NJ; jj++)
        wv[kk][jj] = W[(size_t)(k0+kk)*OUT + t + jj*128];
#pragma unroll
    for (int r = 0; r < RPB; r++) {
      float4 xv = *(const float4*)&xs[r][k0];   // broadcast, conflict-free
#pragma unroll
      for (int jj = 0; jj < NJ; jj++)
        acc[r][jj] += xv.x*wv[0][jj] + xv.y*wv[1][jj] + xv.z*wv[2][jj] + xv.w*wv[3][jj];
    }
  }
#pragma unroll
  for (int r = 0; r < RPB; r++) {
    int row = r0 + r;
    if (row >= nrows) break;
#pragma unroll
    for (int jj = 0; jj < NJ; jj++)
      o[(size_t)row*OUT + t + jj*128] = acc[r][jj] + b[t + jj*128];
  }
}

// ---- fused relation transform, all 3 edge types, one unified ktv buffer ----
// ktv slot layout: [slot][h][0..31]=k*prel/sqrt(d)*log2e, [h][32..63]=v.  1KB/slot.
// slots: type0 -> [0,Na), type1 -> [Na,2Na), type2 -> [2Na, 2Na+Nb)
__global__ void rel3(const float* __restrict__ o_a, const float* __restrict__ o_b,
                     const float* __restrict__ arelL, const float* __restrict__ mrelL,
                     const float* __restrict__ prelL,
                     float* __restrict__ ktv, int Na, int Nb, int Ga, int Gb) {
  int t = threadIdx.x;            // 128
  int h = t >> 5, e = t & 31;
  int type, blk;
  if ((int)blockIdx.x < Ga)        { type = 0; blk = blockIdx.x; }
  else if ((int)blockIdx.x < 2*Ga) { type = 1; blk = blockIdx.x - Ga; }
  else                             { type = 2; blk = blockIdx.x - 2*Ga; }
  const float* o = (type < 2) ? o_a : o_b;
  int n = (type < 2) ? Na : Nb;
  int G = (type < 2) ? Ga : Gb;
  int slotbase = type * Na;
  const float* ar_ = arelL + type*4096;
  const float* mr_ = mrelL + type*4096;
  float psc = prelL[type*4 + h] * 0.17677669529663688f * 1.4426950408889634f;
  float ar[32], mr[32];
#pragma unroll
  for (int d = 0; d < 32; d++) {
    ar[d] = ar_[(h*32 + d)*32 + e];
    mr[d] = mr_[(h*32 + d)*32 + e];
  }
  __shared__ float ks[128], vs[128];
  int rpb = (n + G - 1)/G;
  int rbeg = blk * rpb;
  int rend = rbeg + rpb; if (rend > n) rend = n;
  for (int row = rbeg; row < rend; row++) {
    __syncthreads();
    ks[t] = o[(size_t)row*384 + t];
    vs[t] = o[(size_t)row*384 + 256 + t];
    __syncthreads();
    float ak = 0.f, av = 0.f;
#pragma unroll
    for (int d = 0; d < 32; d++) {
      ak += ks[h*32 + d] * ar[d];
      av += vs[h*32 + d] * mr[d];
    }
    ktv[(size_t)(slotbase + row)*256 + h*64 + e]      = ak * psc;
    ktv[(size_t)(slotbase + row)*256 + h*64 + 32 + e] = av;
  }
}

// ---------- CSR build (dst-sorted; pure edges, no self loops) ----------
__global__ void hist_init(int* __restrict__ hist, int N) {
  int i = blockIdx.x*blockDim.x + threadIdx.x;
  if (i < N) hist[i] = 0;
}
__global__ void hist_count_all(const int* __restrict__ aa, const int* __restrict__ ab,
                               const int* __restrict__ ba,
                               int Eaa, int Eab, int Eba, int Na, int* __restrict__ hist) {
  int i = blockIdx.x*blockDim.x + threadIdx.x;
  int tot = Eaa + Eab + Eba;
  if (i >= tot) return;
  int dst;
  if (i < Eaa)            dst = aa[Eaa + i];
  else if (i < Eaa + Eab) dst = ab[Eab + (i - Eaa)] + Na;
  else                    dst = ba[Eba + (i - Eaa - Eab)];
  atomicAdd(hist + dst, 1);
}
__global__ void scan_excl(const int* __restrict__ hist, int* __restrict__ roff, int N) {
  __shared__ int part[1024];
  int t = threadIdx.x;
  int chunk = (N + 1023) / 1024;
  int b = t*chunk, e = b + chunk; if (e > N) e = N; if (b > N) b = N;
  int sum = 0;
  for (int i = b; i < e; i++) sum += hist[i];
  part[t] = sum;
  __syncthreads();
  for (int o = 1; o < 1024; o <<= 1) {
    int v = (t >= o) ? part[t - o] : 0;
    __syncthreads();
    part[t] += v;
    __syncthreads();
  }
  int run = (t == 0) ? 0 : part[t - 1];
  for (int i = b; i < e; i++) { roff[i] = run; run += hist[i]; }
  if (t == 1023) roff[N] = run;
}
// epack stores the unified ktv slot directly.
__global__ void fill_all(const int* __restrict__ aa, const int* __restrict__ ab,
                         const int* __restrict__ ba,
                         int Eaa, int Eab, int Eba, int Na,
                         int* __restrict__ cursor, int* __restrict__ epack) {
  int i = blockIdx.x*blockDim.x + threadIdx.x;
  int tot = Eaa + Eab + Eba;
  if (i >= tot) return;
  int dst, slot;
  if (i < Eaa)            { dst = aa[Eaa + i];                slot = aa[i]; }
  else if (i < Eaa + Eab) { int j = i - Eaa;       dst = ab[Eab + j] + Na; slot = ab[j] + Na; }
  else                    { int j = i - Eaa - Eab; dst = ba[Eba + j];      slot = ba[j] + 2*Na; }
  int pos = atomicAdd(cursor + dst, 1);
  epack[pos] = slot;
}

// ---------- fused HGT attention: score + online softmax (base-2) + aggregate ----------
// one wave per dst node; quarter-wave (16 lanes) per head, 2 dims per lane.
__global__ void seg_attn(const float* __restrict__ o_a, const float* __restrict__ o_b,
                         const float* __restrict__ ktv,
                         const int* __restrict__ roff, const int* __restrict__ epack,
                         float* __restrict__ agg, int Na, int N) {
  int wid = (blockIdx.x*blockDim.x + threadIdx.x) >> 6;
  int lane = threadIdx.x & 63;
  if (wid >= N) return;
  int h = lane >> 4;            // head
  int d0 = (lane & 15) * 2;     // dims d0, d0+1 of head h
  const float* qrow = (wid < Na) ? (o_a + (size_t)wid*384 + 128)
                                 : (o_b + (size_t)(wid - Na)*384 + 128);
  float2 q = *(const float2*)(qrow + h*32 + d0);
  int beg = roff[wid], end = roff[wid + 1];
  float m = -INFINITY, s = 0.f, a0 = 0.f, a1 = 0.f;
  if (beg < end) {
    const float* kp = ktv + (size_t)epack[beg]*256 + h*64 + d0;
    float2 kv = *(const float2*)kp;
    float2 vv = *(const float2*)(kp + 32);
    for (int i = beg; i < end; i++) {
      float2 ck = kv, cv = vv;
      if (i + 1 < end) {   // prefetch next edge
        const float* kpn = ktv + (size_t)epack[i+1]*256 + h*64 + d0;
        kv = *(const float2*)kpn;
        vv = *(const float2*)(kpn + 32);
      }
      float sc = q.x*ck.x + q.y*ck.y;
      sc += __shfl_xor(sc, 1, 64);
      sc += __shfl_xor(sc, 2, 64);
      sc += __shfl_xor(sc, 4, 64);
      sc += __shfl_xor(sc, 8, 64);   // per-head score, base-2 scaled
      float nm = fmaxf(m, sc);
      float scale = exp2f(m - nm);   // first edge: exp2(-inf)=0
      float e = exp2f(sc - nm);
      s  = s*scale  + e;
      a0 = a0*scale + e*cv.x;
      a1 = a1*scale + e*cv.y;
      m = nm;
    }
  }
  float inv = 1.f / (s + 1e-16f);
  float2 o2; o2.x = a0*inv; o2.y = a1*inv;
  *(float2*)(agg + (size_t)wid*128 + h*32 + d0) = o2;
}

// ---- fused finish for both types: gelu(agg) @ Wout + bout, gated skip, opt gelu ----
template<int RPB>
__global__ void finish2(const float* __restrict__ agg,
                        const float* __restrict__ xa, const float* __restrict__ xb,
                        float* __restrict__ ha, float* __restrict__ hb,
                        const float* __restrict__ WoL, const float* __restrict__ boL,
                        const float* __restrict__ skipL, int do_gelu, int Na, int Nb) {
  int nba = (Na + RPB - 1)/RPB;
  const float *xsrc, *Wo, *bo; float* h; float sgraw; int nrows, r0, aggoff;
  if ((int)blockIdx.x < nba) { xsrc=xa; h=ha; Wo=WoL; bo=boL; sgraw=skipL[0]; nrows=Na; r0=blockIdx.x*RPB; aggoff=0; }
  else { xsrc=xb; h=hb; Wo=WoL+16384; bo=boL+128; sgraw=skipL[1]; nrows=Nb; r0=(blockIdx.x-nba)*RPB; aggoff=Na; }
  int t = threadIdx.x;            // 128
  __shared__ float gs[RPB][128];
#pragma unroll
  for (int r = 0; r < RPB; r++) {
    int row = r0 + r;
    float a = (row < nrows) ? agg[(size_t)(row + aggoff)*128 + t] : 0.f;
    gs[r][t] = gelu_f(a);
  }
  __syncthreads();
  float acc[RPB] = {};
  for (int k0 = 0; k0 < 128; k0 += 4) {
    float wv[4];
#pragma unroll
    for (int kk = 0; kk < 4; kk++) wv[kk] = Wo[(size_t)(k0+kk)*128 + t];
#pragma unroll
    for (int r = 0; r < RPB; r++) {
      float4 xv = *(const float4*)&gs[r][k0];   // broadcast, conflict-free
      acc[r] += xv.x*wv[0] + xv.y*wv[1] + xv.z*wv[2] + xv.w*wv[3];
    }
  }
  float sg = 1.f/(1.f + expf(-sgraw));
#pragma unroll
  for (int r = 0; r < RPB; r++) {
    int row = r0 + r;
    if (row >= nrows) break;
    float g = acc[r] + bo[t];
    float v = sg*g + (1.f - sg)*xsrc[(size_t)row*128 + t];
    h[(size_t)row*128 + t] = do_gelu ? gelu_f(v) : v;
  }
}

// LayerNorm over 128 then gelu, in place, both types. One wave per row.
__global__ void ln_gelu2(float* __restrict__ h, const float* __restrict__ g,
                         const float* __restrict__ b, int Na, int N) {
  int idx = blockIdx.x*blockDim.x + threadIdx.x;
  int row = idx >> 6, lane = idx & 63;
  if (row >= N) return;
  int po = (row < Na) ? 0 : 128;
  float x0 = h[(size_t)row*128 + lane];
  float x1 = h[(size_t)row*128 + 64 + lane];
  float sum = x0 + x1;
#pragma unroll
  for (int o = 32; o; o >>= 1) sum += __shfl_xor(sum, o, 64);
  float mu = sum * (1.f/128.f);
  float d0 = x0 - mu, d1 = x1 - mu;
  float vs = d0*d0 + d1*d1;
#pragma unroll
  for (int o = 32; o; o >>= 1) vs += __shfl_xor(vs, o, 64);
  float inv = 1.f / sqrtf(vs*(1.f/128.f) + 1e-5f);
  h[(size_t)row*128 + lane]      = gelu_f(d0*inv*g[po + lane] + b[po + lane]);
  h[(size_t)row*128 + 64 + lane] = gelu_f(d1*inv*g[po + 64 + lane] + b[po + 64 + lane]);
}

// x1[n] = dot(h[n,:], Wgat[:,0]) — one wave per row
__global__ void gat_x1(const float* __restrict__ h, const float* __restrict__ Wg,
                       float* __restrict__ x1, int N) {
  int idx = blockIdx.x*blockDim.x + threadIdx.x;
  int row = idx >> 6, lane = idx & 63;
  if (row >= N) return;
  float a = h[(size_t)row*128 + lane]*Wg[lane] + h[(size_t)row*128 + 64 + lane]*Wg[64 + lane];
#pragma unroll
  for (int o = 32; o; o >>= 1) a += __shfl_xor(a, o, 64);
  if (lane == 0) x1[row] = a;
}

// fused GAT scorer via CSR: thread per node, online softmax (self-loop handled inline)
__global__ void gat_all(const float* __restrict__ x1, const int* __restrict__ roff,
                        const int* __restrict__ epack,
                        const float* __restrict__ asrc, const float* __restrict__ adst,
                        int Na, int N, float* __restrict__ score) {
  int n = blockIdx.x*blockDim.x + threadIdx.x;
  if (n >= N) return;
  float xd = x1[n];
  float as_ = asrc[0], ad = adst[0];
  // self loop first: e = leaky(xd*as + xd*ad), weight exp(0)=1 at m=e
  float e0 = xd*as_ + xd*ad;
  e0 = (e0 > 0.f) ? e0 : 0.2f*e0;
  float m = e0, s = 1.f, acc = xd;
  int beg = roff[n], end = roff[n + 1];
  for (int i = beg; i < end; i++) {
    int slot = epack[i];
    int sg = (slot < Na) ? slot : slot - Na;   // global src node index
    float xs = x1[sg];
    float e = xs*as_ + xd*ad;
    e = (e > 0.f) ? e : 0.2f*e;
    float nm = fmaxf(m, e);
    float sc = __expf(m - nm), ee = __expf(e - nm);
    s = s*sc + ee;  acc = acc*sc + ee*xs;  m = nm;
  }
  score[n] = acc / (s + 1e-16f);
}

// ---- parallel top-8 ----
__global__ void topk_stage1(const float* __restrict__ score, const float* __restrict__ bgat,
                            int N, float* __restrict__ cvals, int* __restrict__ cidx) {
  __shared__ float bv[256];
  __shared__ int   bi[256];
  int t = threadIdx.x;
  int chunk = (N + gridDim.x - 1) / gridDim.x;   // <= 256 by construction
  int i = blockIdx.x * chunk + t;
  float bg = bgat[0];
  bool valid = (t < chunk && i < N);
  float myv = valid ? score[i] + bg : -INFINITY;
  int   myi = valid ? i : 0x7FFFFFFF;
  for (int k = 0; k < 8; k++) {
    bv[t] = myv; bi[t] = myi;
    __syncthreads();
    for (int o = 128; o; o >>= 1) {
      if (t < o) {
        if (bv[t+o] > bv[t] || (bv[t+o] == bv[t] && bi[t+o] < bi[t])) { bv[t]=bv[t+o]; bi[t]=bi[t+o]; }
      }
      __syncthreads();
    }
    if (t == 0) { cvals[blockIdx.x*8 + k] = bv[0]; cidx[blockIdx.x*8 + k] = bi[0]; }
    if (myi == bi[0]) myv = -INFINITY;   // pop winner
    __syncthreads();
  }
}

__global__ void topk_stage2(const float* __restrict__ cvals, const int* __restrict__ cidx,
                            int C, float* __restrict__ vals, int* __restrict__ perm) {
  __shared__ float bv[256];
  __shared__ int   bi[256];
  __shared__ int   seli[8];
  int t = threadIdx.x;
  for (int k = 0; k < 8; k++) {
    float best = -INFINITY; int besti = 0x7FFFFFFF;
    for (int i = t; i < C; i += 256) {
      int id = cidx[i];
      bool taken = false;
      for (int j = 0; j < k; j++) if (seli[j] == id) taken = true;
      if (taken) continue;
      float v = cvals[i];
      if (v > best || (v == best && id < besti)) { best = v; besti = id; }
    }
    bv[t] = best; bi[t] = besti;
    __syncthreads();
    for (int o = 128; o; o >>= 1) {
      if (t < o) {
        if (bv[t+o] > bv[t] || (bv[t+o] == bv[t] && bi[t+o] < bi[t])) { bv[t]=bv[t+o]; bi[t]=bi[t+o]; }
      }
      __syncthreads();
    }
    if (t == 0) { seli[k] = bi[0]; vals[k] = bv[0]; perm[k] = bi[0]; }
    __syncthreads();
  }
}

__global__ void mlp_final(const float* __restrict__ h, const float* __restrict__ vals,
                          const int* __restrict__ perm,
                          const float* __restrict__ W1, const float* __restrict__ b1,
                          const float* __restrict__ W2, const float* __restrict__ b2,
                          const float* __restrict__ W3, const float* __restrict__ b3,
                          float* __restrict__ out) {
  __shared__ float hp[1024], v1[128], v2[64];
  int t = threadIdx.x;  // 256
  for (int i = t; i < 1024; i += 256) {
    int r = i >> 7, d = i & 127;
    hp[i] = h[(size_t)perm[r]*128 + d] * tanhf(vals[r]);
  }
  __syncthreads();
  if (t < 128) {
    float a = 0.f;
    for (int k = 0; k < 1024; k++) a += hp[k]*W1[(size_t)k*128 + t];
    v1[t] = gelu_f(a + b1[t]);
  }
  __syncthreads();
  if (t < 64) {
    float a = 0.f;
    for (int k = 0; k < 128; k++) a += v1[k]*W2[(size_t)k*64 + t];
    v2[t] = gelu_f(a + b2[t]);
  }
  __syncthreads();
  if (t < 16) {
    float a = 0.f;
    for (int k = 0; k < 64; k++) a += v2[k]*W3[(size_t)k*16 + t];
    float r = gelu_f(a + b3[t]);
    if (isnan(r)) r = 0.f;
    else if (isinf(r)) r = (r > 0.f) ? 3.4028234663852886e38f : -3.4028234663852886e38f;
    out[t] = r;
  }
}

extern "C" void kernel_launch(void* const* d_in, const int* in_sizes, int n_in,
                              void* d_out, int out_size, void* d_ws, size_t ws_size,
                              hipStream_t stream) {
  const float* x_a  = (const float*)d_in[0];
  const float* x_b  = (const float*)d_in[1];
  const int* ei_aa  = (const int*)d_in[2];
  const int* ei_ab  = (const int*)d_in[3];
  const int* ei_ba  = (const int*)d_in[4];
  const float* Wkqv = (const float*)d_in[5];
  const float* bkqv = (const float*)d_in[6];
  const float* Wout = (const float*)d_in[7];
  const float* bout = (const float*)d_in[8];
  const float* skip = (const float*)d_in[9];
  const float* arel = (const float*)d_in[10];
  const float* mrel = (const float*)d_in[11];
  const float* prel = (const float*)d_in[12];
  const float* ln_g = (const float*)d_in[13];
  const float* ln_b = (const float*)d_in[14];
  const float* Wgat = (const float*)d_in[15];
  const float* att_src = (const float*)d_in[16];
  const float* att_dst = (const float*)d_in[17];
  const float* bgat = (const float*)d_in[18];
  const float* W1 = (const float*)d_in[19];
  const float* b1 = (const float*)d_in[20];
  const float* W2 = (const float*)d_in[21];
  const float* b2 = (const float*)d_in[22];
  const float* W3 = (const float*)d_in[23];
  const float* b3 = (const float*)d_in[24];

  int Na = in_sizes[0]/128, Nb = in_sizes[1]/128, N = Na + Nb;
  int Eaa = in_sizes[2]/2, Eab = in_sizes[3]/2, Eba = in_sizes[4]/2;
  int Etot = Eaa + Eab + Eba;

  // workspace layout
  float* w = (float*)d_ws;
  size_t off = 0;
  auto alloc = [&](size_t n) { float* p = w + off; off += n; return p; };
  float* hbuf = alloc((size_t)N*128);
  float* o_a  = alloc((size_t)Na*384);
  float* o_b  = alloc((size_t)Nb*384);
  float* ktvA = alloc((size_t)(2*Na + Nb)*256);   // unified, slot-indexed
  float* agg   = alloc((size_t)N*128);
  float* x1buf = alloc((size_t)N);
  float* score = alloc((size_t)N);
  float* valsb = alloc(8);
  int*   permb = (int*)alloc(8);
  float* cvals = alloc(2048);
  int*   cidx  = (int*)alloc(2048);
  int*   hist  = (int*)alloc((size_t)N);
  int*   roff  = (int*)alloc((size_t)N + 1);
  int*   cursor= (int*)alloc((size_t)N);
  int*   epack = (int*)alloc((size_t)Etot);

  float* h_a = hbuf;
  float* h_b = hbuf + (size_t)Na*128;

  // ---- build dst-sorted CSR once (pure edges; self-loops handled analytically) ----
  hist_init<<<dim3((N+255)/256),dim3(256),0,stream>>>(hist, N);
  hist_count_all<<<dim3((Etot+255)/256),dim3(256),0,stream>>>(ei_aa, ei_ab, ei_ba, Eaa, Eab, Eba, Na, hist);
  scan_excl<<<dim3(1),dim3(1024),0,stream>>>(hist, roff, N);
  hipMemcpyAsync(cursor, roff, (size_t)N*sizeof(int), hipMemcpyDeviceToDevice, stream);
  fill_all<<<dim3((Etot+255)/256),dim3(256),0,stream>>>(ei_aa, ei_ab, ei_ba, Eaa, Eab, Eba, Na, cursor, epack);

  const int RPB = 16;
  int nba = (Na + RPB - 1)/RPB, nbb = (Nb + RPB - 1)/RPB;
  const int Ga = 1024, Gb = 1024;

  for (int L = 0; L < 3; L++) {
    const float* xa_in = (L == 0) ? x_a : h_a;
    const float* xb_in = (L == 0) ? x_b : h_b;
    const float* WL = Wkqv + (size_t)L*2*49152;
    const float* bL = bkqv + (size_t)L*2*384;
    rowmm2<RPB><<<dim3(nba + nbb),dim3(128),0,stream>>>(xa_in, xb_in, WL, WL + 49152,
                                                        bL, bL + 384, o_a, o_b, Na, Nb);
    rel3<<<dim3(2*Ga + Gb),dim3(128),0,stream>>>(o_a, o_b,
                                                 arel + (size_t)L*3*4096, mrel + (size_t)L*3*4096,
                                                 prel + (size_t)L*3*4, ktvA, Na, Nb, Ga, Gb);
    seg_attn<<<dim3((N+3)/4),dim3(256),0,stream>>>(o_a, o_b, ktvA, roff, epack, agg, Na, N);
    int do_gelu = (L == 0) ? 0 : 1;
    finish2<RPB><<<dim3(nba + nbb),dim3(128),0,stream>>>(agg, xa_in, xb_in, h_a, h_b,
                                                         Wout + (size_t)L*2*16384,
                                                         bout + (size_t)L*2*128,
                                                         skip + L*2, do_gelu, Na, Nb);
    if (L == 0) {
      ln_gelu2<<<dim3((N+3)/4),dim3(256),0,stream>>>(hbuf, ln_g, ln_b, Na, N);
    }
  }

  // ---- GAT scorer + SAGPool top-k + MLP ----
  gat_x1<<<dim3((N+3)/4),dim3(256),0,stream>>>(hbuf, Wgat, x1buf, N);
  gat_all<<<dim3((N+255)/256),dim3(256),0,stream>>>(x1buf, roff, epack, att_src, att_dst, Na, N, score);
  int tk_blocks = (N + 255)/256;
  topk_stage1<<<dim3(tk_blocks),dim3(256),0,stream>>>(score, bgat, N, cvals, cidx);
  topk_stage2<<<dim3(1),dim3(256),0,stream>>>(cvals, cidx, tk_blocks*8, valsb, permb);
  mlp_final<<<dim3(1),dim3(256),0,stream>>>(hbuf, valsb, permb, W1, b1, W2, b2, W3, b3, (float*)d_out);
}

// Round 7
// 1031.095 us; speedup vs baseline: 1.0177x; 1.0177x over previous
//
#include <hip/hip_runtime.h>
#include <math.h>

#define HID 128

__device__ __forceinline__ float gelu_f(float x){
  return 0.5f*x*(1.0f+erff(x*0.70710678118654752440f));
}

// ---- fused KQV GEMM for both node types ----
// o[row, j] = sum_k x[row,k]*W[k,j] + b[j]   (x is nrows x 128, W is 128 x 384)
// 128 threads; RPB=8 rows/block (occupancy sweet spot); k stepped by 4, float4 LDS broadcast.
template<int RPB>
__global__ void rowmm2(const float* __restrict__ xa, const float* __restrict__ xb,
                       const float* __restrict__ Wa, const float* __restrict__ Wb,
                       const float* __restrict__ ba_, const float* __restrict__ bb_,
                       float* __restrict__ oa, float* __restrict__ ob, int Na, int Nb) {
  const int OUT = 384, NJ = 3;
  int nba = (Na + RPB - 1)/RPB;
  const float *x, *W, *b; float* o; int nrows, r0;
  if ((int)blockIdx.x < nba) { x=xa; W=Wa; b=ba_; o=oa; nrows=Na; r0=blockIdx.x*RPB; }
  else { x=xb; W=Wb; b=bb_; o=ob; nrows=Nb; r0=(blockIdx.x-nba)*RPB; }
  int t = threadIdx.x;            // 128 threads
  __shared__ float xs[RPB][128];
#pragma unroll
  for (int r = 0; r < RPB; r++) {
    int row = r0 + r;
    xs[r][t] = (row < nrows) ? x[(size_t)row*128 + t] : 0.f;
  }
  __syncthreads();
  float acc[RPB][NJ] = {};
  for (int k0 = 0; k0 < 128; k0 += 4) {
    float wv[4][NJ];
#pragma unroll
    for (int kk = 0; kk < 4; kk++)
#pragma unroll
      for (int jj = 0; jj < NJ; jj++)
        wv[kk][jj] = W[(size_t)(k0+kk)*OUT + t + jj*128];
#pragma unroll
    for (int r = 0; r < RPB; r++) {
      float4 xv = *(const float4*)&xs[r][k0];   // broadcast, conflict-free
#pragma unroll
      for (int jj = 0; jj < NJ; jj++)
        acc[r][jj] += xv.x*wv[0][jj] + xv.y*wv[1][jj] + xv.z*wv[2][jj] + xv.w*wv[3][jj];
    }
  }
#pragma unroll
  for (int r = 0; r < RPB; r++) {
    int row = r0 + r;
    if (row >= nrows) break;
#pragma unroll
    for (int jj = 0; jj < NJ; jj++)
      o[(size_t)row*OUT + t + jj*128] = acc[r][jj] + b[t + jj*128];
  }
}

// ---- fused relation transform, all 3 edge types, one unified ktv buffer ----
// ktv slot layout: [slot][h][0..31]=k*prel/sqrt(d)*log2e, [h][32..63]=v.  1KB/slot.
// slots: type0 -> [0,Na), type1 -> [Na,2Na), type2 -> [2Na, 2Na+Nb)
__global__ void rel3(const float* __restrict__ o_a, const float* __restrict__ o_b,
                     const float* __restrict__ arelL, const float* __restrict__ mrelL,
                     const float* __restrict__ prelL,
                     float* __restrict__ ktv, int Na, int Nb, int Ga, int Gb) {
  int t = threadIdx.x;            // 128
  int h = t >> 5, e = t & 31;
  int type, blk;
  if ((int)blockIdx.x < Ga)        { type = 0; blk = blockIdx.x; }
  else if ((int)blockIdx.x < 2*Ga) { type = 1; blk = blockIdx.x - Ga; }
  else                             { type = 2; blk = blockIdx.x - 2*Ga; }
  const float* o = (type < 2) ? o_a : o_b;
  int n = (type < 2) ? Na : Nb;
  int G = (type < 2) ? Ga : Gb;
  int slotbase = type * Na;
  const float* ar_ = arelL + type*4096;
  const float* mr_ = mrelL + type*4096;
  float psc = prelL[type*4 + h] * 0.17677669529663688f * 1.4426950408889634f;
  float ar[32], mr[32];
#pragma unroll
  for (int d = 0; d < 32; d++) {
    ar[d] = ar_[(h*32 + d)*32 + e];
    mr[d] = mr_[(h*32 + d)*32 + e];
  }
  __shared__ float ks[128], vs[128];
  int rpb = (n + G - 1)/G;
  int rbeg = blk * rpb;
  int rend = rbeg + rpb; if (rend > n) rend = n;
  for (int row = rbeg; row < rend; row++) {
    __syncthreads();
    ks[t] = o[(size_t)row*384 + t];
    vs[t] = o[(size_t)row*384 + 256 + t];
    __syncthreads();
    float ak = 0.f, av = 0.f;
#pragma unroll
    for (int d = 0; d < 32; d++) {
      ak += ks[h*32 + d] * ar[d];
      av += vs[h*32 + d] * mr[d];
    }
    ktv[(size_t)(slotbase + row)*256 + h*64 + e]      = ak * psc;
    ktv[(size_t)(slotbase + row)*256 + h*64 + 32 + e] = av;
  }
}

// ---------- CSR build (dst-sorted; pure edges, no self loops) ----------
__global__ void hist_init(int* __restrict__ hist, int N) {
  int i = blockIdx.x*blockDim.x + threadIdx.x;
  if (i < N) hist[i] = 0;
}
__global__ void hist_count_all(const int* __restrict__ aa, const int* __restrict__ ab,
                               const int* __restrict__ ba,
                               int Eaa, int Eab, int Eba, int Na, int* __restrict__ hist) {
  int i = blockIdx.x*blockDim.x + threadIdx.x;
  int tot = Eaa + Eab + Eba;
  if (i >= tot) return;
  int dst;
  if (i < Eaa)            dst = aa[Eaa + i];
  else if (i < Eaa + Eab) dst = ab[Eab + (i - Eaa)] + Na;
  else                    dst = ba[Eba + (i - Eaa - Eab)];
  atomicAdd(hist + dst, 1);
}
__global__ void scan_excl(const int* __restrict__ hist, int* __restrict__ roff, int N) {
  __shared__ int part[1024];
  int t = threadIdx.x;
  int chunk = (N + 1023) / 1024;
  int b = t*chunk, e = b + chunk; if (e > N) e = N; if (b > N) b = N;
  int sum = 0;
  for (int i = b; i < e; i++) sum += hist[i];
  part[t] = sum;
  __syncthreads();
  for (int o = 1; o < 1024; o <<= 1) {
    int v = (t >= o) ? part[t - o] : 0;
    __syncthreads();
    part[t] += v;
    __syncthreads();
  }
  int run = (t == 0) ? 0 : part[t - 1];
  for (int i = b; i < e; i++) { roff[i] = run; run += hist[i]; }
  if (t == 1023) roff[N] = run;
}
// epack stores the unified ktv slot directly.
__global__ void fill_all(const int* __restrict__ aa, const int* __restrict__ ab,
                         const int* __restrict__ ba,
                         int Eaa, int Eab, int Eba, int Na,
                         int* __restrict__ cursor, int* __restrict__ epack) {
  int i = blockIdx.x*blockDim.x + threadIdx.x;
  int tot = Eaa + Eab + Eba;
  if (i >= tot) return;
  int dst, slot;
  if (i < Eaa)            { dst = aa[Eaa + i];                slot = aa[i]; }
  else if (i < Eaa + Eab) { int j = i - Eaa;       dst = ab[Eab + j] + Na; slot = ab[j] + Na; }
  else                    { int j = i - Eaa - Eab; dst = ba[Eba + j];      slot = ba[j] + 2*Na; }
  int pos = atomicAdd(cursor + dst, 1);
  epack[pos] = slot;
}

// ---------- fused HGT attention: score + online softmax (base-2) + aggregate ----------
// one wave per dst node; quarter-wave (16 lanes) per head, 2 dims per lane.
__global__ void seg_attn(const float* __restrict__ o_a, const float* __restrict__ o_b,
                         const float* __restrict__ ktv,
                         const int* __restrict__ roff, const int* __restrict__ epack,
                         float* __restrict__ agg, int Na, int N) {
  int wid = (blockIdx.x*blockDim.x + threadIdx.x) >> 6;
  int lane = threadIdx.x & 63;
  if (wid >= N) return;
  int h = lane >> 4;            // head
  int d0 = (lane & 15) * 2;     // dims d0, d0+1 of head h
  const float* qrow = (wid < Na) ? (o_a + (size_t)wid*384 + 128)
                                 : (o_b + (size_t)(wid - Na)*384 + 128);
  float2 q = *(const float2*)(qrow + h*32 + d0);
  int beg = roff[wid], end = roff[wid + 1];
  float m = -INFINITY, s = 0.f, a0 = 0.f, a1 = 0.f;
  if (beg < end) {
    const float* kp = ktv + (size_t)epack[beg]*256 + h*64 + d0;
    float2 kv = *(const float2*)kp;
    float2 vv = *(const float2*)(kp + 32);
    for (int i = beg; i < end; i++) {
      float2 ck = kv, cv = vv;
      if (i + 1 < end) {   // prefetch next edge
        const float* kpn = ktv + (size_t)epack[i+1]*256 + h*64 + d0;
        kv = *(const float2*)kpn;
        vv = *(const float2*)(kpn + 32);
      }
      float sc = q.x*ck.x + q.y*ck.y;
      sc += __shfl_xor(sc, 1, 64);
      sc += __shfl_xor(sc, 2, 64);
      sc += __shfl_xor(sc, 4, 64);
      sc += __shfl_xor(sc, 8, 64);   // per-head score, base-2 scaled
      float nm = fmaxf(m, sc);
      float scale = exp2f(m - nm);   // first edge: exp2(-inf)=0
      float e = exp2f(sc - nm);
      s  = s*scale  + e;
      a0 = a0*scale + e*cv.x;
      a1 = a1*scale + e*cv.y;
      m = nm;
    }
  }
  float inv = 1.f / (s + 1e-16f);
  float2 o2; o2.x = a0*inv; o2.y = a1*inv;
  *(float2*)(agg + (size_t)wid*128 + h*32 + d0) = o2;
}

// ---- fused finish for both types: gelu(agg) @ Wout + bout, gated skip, opt gelu ----
template<int RPB>
__global__ void finish2(const float* __restrict__ agg,
                        const float* __restrict__ xa, const float* __restrict__ xb,
                        float* __restrict__ ha, float* __restrict__ hb,
                        const float* __restrict__ WoL, const float* __restrict__ boL,
                        const float* __restrict__ skipL, int do_gelu, int Na, int Nb) {
  int nba = (Na + RPB - 1)/RPB;
  const float *xsrc, *Wo, *bo; float* h; float sgraw; int nrows, r0, aggoff;
  if ((int)blockIdx.x < nba) { xsrc=xa; h=ha; Wo=WoL; bo=boL; sgraw=skipL[0]; nrows=Na; r0=blockIdx.x*RPB; aggoff=0; }
  else { xsrc=xb; h=hb; Wo=WoL+16384; bo=boL+128; sgraw=skipL[1]; nrows=Nb; r0=(blockIdx.x-nba)*RPB; aggoff=Na; }
  int t = threadIdx.x;            // 128
  __shared__ float gs[RPB][128];
#pragma unroll
  for (int r = 0; r < RPB; r++) {
    int row = r0 + r;
    float a = (row < nrows) ? agg[(size_t)(row + aggoff)*128 + t] : 0.f;
    gs[r][t] = gelu_f(a);
  }
  __syncthreads();
  float acc[RPB] = {};
  for (int k0 = 0; k0 < 128; k0 += 4) {
    float wv[4];
#pragma unroll
    for (int kk = 0; kk < 4; kk++) wv[kk] = Wo[(size_t)(k0+kk)*128 + t];
#pragma unroll
    for (int r = 0; r < RPB; r++) {
      float4 xv = *(const float4*)&gs[r][k0];   // broadcast, conflict-free
      acc[r] += xv.x*wv[0] + xv.y*wv[1] + xv.z*wv[2] + xv.w*wv[3];
    }
  }
  float sg = 1.f/(1.f + expf(-sgraw));
#pragma unroll
  for (int r = 0; r < RPB; r++) {
    int row = r0 + r;
    if (row >= nrows) break;
    float g = acc[r] + bo[t];
    float v = sg*g + (1.f - sg)*xsrc[(size_t)row*128 + t];
    h[(size_t)row*128 + t] = do_gelu ? gelu_f(v) : v;
  }
}

// LayerNorm over 128 then gelu, in place, both types. One wave per row.
__global__ void ln_gelu2(float* __restrict__ h, const float* __restrict__ g,
                         const float* __restrict__ b, int Na, int N) {
  int idx = blockIdx.x*blockDim.x + threadIdx.x;
  int row = idx >> 6, lane = idx & 63;
  if (row >= N) return;
  int po = (row < Na) ? 0 : 128;
  float x0 = h[(size_t)row*128 + lane];
  float x1 = h[(size_t)row*128 + 64 + lane];
  float sum = x0 + x1;
#pragma unroll
  for (int o = 32; o; o >>= 1) sum += __shfl_xor(sum, o, 64);
  float mu = sum * (1.f/128.f);
  float d0 = x0 - mu, d1 = x1 - mu;
  float vs = d0*d0 + d1*d1;
#pragma unroll
  for (int o = 32; o; o >>= 1) vs += __shfl_xor(vs, o, 64);
  float inv = 1.f / sqrtf(vs*(1.f/128.f) + 1e-5f);
  h[(size_t)row*128 + lane]      = gelu_f(d0*inv*g[po + lane] + b[po + lane]);
  h[(size_t)row*128 + 64 + lane] = gelu_f(d1*inv*g[po + 64 + lane] + b[po + 64 + lane]);
}

// x1[n] = dot(h[n,:], Wgat[:,0]) — one wave per row
__global__ void gat_x1(const float* __restrict__ h, const float* __restrict__ Wg,
                       float* __restrict__ x1, int N) {
  int idx = blockIdx.x*blockDim.x + threadIdx.x;
  int row = idx >> 6, lane = idx & 63;
  if (row >= N) return;
  float a = h[(size_t)row*128 + lane]*Wg[lane] + h[(size_t)row*128 + 64 + lane]*Wg[64 + lane];
#pragma unroll
  for (int o = 32; o; o >>= 1) a += __shfl_xor(a, o, 64);
  if (lane == 0) x1[row] = a;
}

// fused GAT scorer via CSR: thread per node, online softmax (self-loop handled inline)
__global__ void gat_all(const float* __restrict__ x1, const int* __restrict__ roff,
                        const int* __restrict__ epack,
                        const float* __restrict__ asrc, const float* __restrict__ adst,
                        int Na, int N, float* __restrict__ score) {
  int n = blockIdx.x*blockDim.x + threadIdx.x;
  if (n >= N) return;
  float xd = x1[n];
  float as_ = asrc[0], ad = adst[0];
  // self loop first: e = leaky(xd*as + xd*ad), weight exp(0)=1 at m=e
  float e0 = xd*as_ + xd*ad;
  e0 = (e0 > 0.f) ? e0 : 0.2f*e0;
  float m = e0, s = 1.f, acc = xd;
  int beg = roff[n], end = roff[n + 1];
  for (int i = beg; i < end; i++) {
    int slot = epack[i];
    int sg = (slot < Na) ? slot : slot - Na;   // global src node index
    float xs = x1[sg];
    float e = xs*as_ + xd*ad;
    e = (e > 0.f) ? e : 0.2f*e;
    float nm = fmaxf(m, e);
    float sc = __expf(m - nm), ee = __expf(e - nm);
    s = s*sc + ee;  acc = acc*sc + ee*xs;  m = nm;
  }
  score[n] = acc / (s + 1e-16f);
}

// ---- parallel top-8 ----
__global__ void topk_stage1(const float* __restrict__ score, const float* __restrict__ bgat,
                            int N, float* __restrict__ cvals, int* __restrict__ cidx) {
  __shared__ float bv[256];
  __shared__ int   bi[256];
  int t = threadIdx.x;
  int chunk = (N + gridDim.x - 1) / gridDim.x;   // <= 256 by construction
  int i = blockIdx.x * chunk + t;
  float bg = bgat[0];
  bool valid = (t < chunk && i < N);
  float myv = valid ? score[i] + bg : -INFINITY;
  int   myi = valid ? i : 0x7FFFFFFF;
  for (int k = 0; k < 8; k++) {
    bv[t] = myv; bi[t] = myi;
    __syncthreads();
    for (int o = 128; o; o >>= 1) {
      if (t < o) {
        if (bv[t+o] > bv[t] || (bv[t+o] == bv[t] && bi[t+o] < bi[t])) { bv[t]=bv[t+o]; bi[t]=bi[t+o]; }
      }
      __syncthreads();
    }
    if (t == 0) { cvals[blockIdx.x*8 + k] = bv[0]; cidx[blockIdx.x*8 + k] = bi[0]; }
    if (myi == bi[0]) myv = -INFINITY;   // pop winner
    __syncthreads();
  }
}

__global__ void topk_stage2(const float* __restrict__ cvals, const int* __restrict__ cidx,
                            int C, float* __restrict__ vals, int* __restrict__ perm) {
  __shared__ float bv[256];
  __shared__ int   bi[256];
  __shared__ int   seli[8];
  int t = threadIdx.x;
  for (int k = 0; k < 8; k++) {
    float best = -INFINITY; int besti = 0x7FFFFFFF;
    for (int i = t; i < C; i += 256) {
      int id = cidx[i];
      bool taken = false;
      for (int j = 0; j < k; j++) if (seli[j] == id) taken = true;
      if (taken) continue;
      float v = cvals[i];
      if (v > best || (v == best && id < besti)) { best = v; besti = id; }
    }
    bv[t] = best; bi[t] = besti;
    __syncthreads();
    for (int o = 128; o; o >>= 1) {
      if (t < o) {
        if (bv[t+o] > bv[t] || (bv[t+o] == bv[t] && bi[t+o] < bi[t])) { bv[t]=bv[t+o]; bi[t]=bi[t+o]; }
      }
      __syncthreads();
    }
    if (t == 0) { seli[k] = bi[0]; vals[k] = bv[0]; perm[k] = bi[0]; }
    __syncthreads();
  }
}

__global__ void mlp_final(const float* __restrict__ h, const float* __restrict__ vals,
                          const int* __restrict__ perm,
                          const float* __restrict__ W1, const float* __restrict__ b1,
                          const float* __restrict__ W2, const float* __restrict__ b2,
                          const float* __restrict__ W3, const float* __restrict__ b3,
                          float* __restrict__ out) {
  __shared__ float hp[1024], v1[128], v2[64];
  int t = threadIdx.x;  // 256
  for (int i = t; i < 1024; i += 256) {
    int r = i >> 7, d = i & 127;
    hp[i] = h[(size_t)perm[r]*128 + d] * tanhf(vals[r]);
  }
  __syncthreads();
  if (t < 128) {
    float a = 0.f;
    for (int k = 0; k < 1024; k++) a += hp[k]*W1[(size_t)k*128 + t];
    v1[t] = gelu_f(a + b1[t]);
  }
  __syncthreads();
  if (t < 64) {
    float a = 0.f;
    for (int k = 0; k < 128; k++) a += v1[k]*W2[(size_t)k*64 + t];
    v2[t] = gelu_f(a + b2[t]);
  }
  __syncthreads();
  if (t < 16) {
    float a = 0.f;
    for (int k = 0; k < 64; k++) a += v2[k]*W3[(size_t)k*16 + t];
    float r = gelu_f(a + b3[t]);
    if (isnan(r)) r = 0.f;
    else if (isinf(r)) r = (r > 0.f) ? 3.4028234663852886e38f : -3.4028234663852886e38f;
    out[t] = r;
  }
}

extern "C" void kernel_launch(void* const* d_in, const int* in_sizes, int n_in,
                              void* d_out, int out_size, void* d_ws, size_t ws_size,
                              hipStream_t stream) {
  const float* x_a  = (const float*)d_in[0];
  const float* x_b  = (const float*)d_in[1];
  const int* ei_aa  = (const int*)d_in[2];
  const int* ei_ab  = (const int*)d_in[3];
  const int* ei_ba  = (const int*)d_in[4];
  const float* Wkqv = (const float*)d_in[5];
  const float* bkqv = (const float*)d_in[6];
  const float* Wout = (const float*)d_in[7];
  const float* bout = (const float*)d_in[8];
  const float* skip = (const float*)d_in[9];
  const float* arel = (const float*)d_in[10];
  const float* mrel = (const float*)d_in[11];
  const float* prel = (const float*)d_in[12];
  const float* ln_g = (const float*)d_in[13];
  const float* ln_b = (const float*)d_in[14];
  const float* Wgat = (const float*)d_in[15];
  const float* att_src = (const float*)d_in[16];
  const float* att_dst = (const float*)d_in[17];
  const float* bgat = (const float*)d_in[18];
  const float* W1 = (const float*)d_in[19];
  const float* b1 = (const float*)d_in[20];
  const float* W2 = (const float*)d_in[21];
  const float* b2 = (const float*)d_in[22];
  const float* W3 = (const float*)d_in[23];
  const float* b3 = (const float*)d_in[24];

  int Na = in_sizes[0]/128, Nb = in_sizes[1]/128, N = Na + Nb;
  int Eaa = in_sizes[2]/2, Eab = in_sizes[3]/2, Eba = in_sizes[4]/2;
  int Etot = Eaa + Eab + Eba;

  // workspace layout
  float* w = (float*)d_ws;
  size_t off = 0;
  auto alloc = [&](size_t n) { float* p = w + off; off += n; return p; };
  float* hbuf = alloc((size_t)N*128);
  float* o_a  = alloc((size_t)Na*384);
  float* o_b  = alloc((size_t)Nb*384);
  float* ktvA = alloc((size_t)(2*Na + Nb)*256);   // unified, slot-indexed
  float* agg   = alloc((size_t)N*128);
  float* x1buf = alloc((size_t)N);
  float* score = alloc((size_t)N);
  float* valsb = alloc(8);
  int*   permb = (int*)alloc(8);
  float* cvals = alloc(2048);
  int*   cidx  = (int*)alloc(2048);
  int*   hist  = (int*)alloc((size_t)N);
  int*   roff  = (int*)alloc((size_t)N + 1);
  int*   cursor= (int*)alloc((size_t)N);
  int*   epack = (int*)alloc((size_t)Etot);

  float* h_a = hbuf;
  float* h_b = hbuf + (size_t)Na*128;

  // ---- build dst-sorted CSR once (pure edges; self-loops handled analytically) ----
  hist_init<<<dim3((N+255)/256),dim3(256),0,stream>>>(hist, N);
  hist_count_all<<<dim3((Etot+255)/256),dim3(256),0,stream>>>(ei_aa, ei_ab, ei_ba, Eaa, Eab, Eba, Na, hist);
  scan_excl<<<dim3(1),dim3(1024),0,stream>>>(hist, roff, N);
  hipMemcpyAsync(cursor, roff, (size_t)N*sizeof(int), hipMemcpyDeviceToDevice, stream);
  fill_all<<<dim3((Etot+255)/256),dim3(256),0,stream>>>(ei_aa, ei_ab, ei_ba, Eaa, Eab, Eba, Na, cursor, epack);

  const int RPB = 8;   // back to the R5 occupancy sweet spot; k-step-4 float4 kept
  int nba = (Na + RPB - 1)/RPB, nbb = (Nb + RPB - 1)/RPB;
  const int Ga = 1024, Gb = 1024;

  for (int L = 0; L < 3; L++) {
    const float* xa_in = (L == 0) ? x_a : h_a;
    const float* xb_in = (L == 0) ? x_b : h_b;
    const float* WL = Wkqv + (size_t)L*2*49152;
    const float* bL = bkqv + (size_t)L*2*384;
    rowmm2<RPB><<<dim3(nba + nbb),dim3(128),0,stream>>>(xa_in, xb_in, WL, WL + 49152,
                                                        bL, bL + 384, o_a, o_b, Na, Nb);
    rel3<<<dim3(2*Ga + Gb),dim3(128),0,stream>>>(o_a, o_b,
                                                 arel + (size_t)L*3*4096, mrel + (size_t)L*3*4096,
                                                 prel + (size_t)L*3*4, ktvA, Na, Nb, Ga, Gb);
    seg_attn<<<dim3((N+3)/4),dim3(256),0,stream>>>(o_a, o_b, ktvA, roff, epack, agg, Na, N);
    int do_gelu = (L == 0) ? 0 : 1;
    finish2<RPB><<<dim3(nba + nbb),dim3(128),0,stream>>>(agg, xa_in, xb_in, h_a, h_b,
                                                         Wout + (size_t)L*2*16384,
                                                         bout + (size_t)L*2*128,
                                                         skip + L*2, do_gelu, Na, Nb);
    if (L == 0) {
      ln_gelu2<<<dim3((N+3)/4),dim3(256),0,stream>>>(hbuf, ln_g, ln_b, Na, N);
    }
  }

  // ---- GAT scorer + SAGPool top-k + MLP ----
  gat_x1<<<dim3((N+3)/4),dim3(256),0,stream>>>(hbuf, Wgat, x1buf, N);
  gat_all<<<dim3((N+255)/256),dim3(256),0,stream>>>(x1buf, roff, epack, att_src, att_dst, Na, N, score);
  int tk_blocks = (N + 255)/256;
  topk_stage1<<<dim3(tk_blocks),dim3(256),0,stream>>>(score, bgat, N, cvals, cidx);
  topk_stage2<<<dim3(1),dim3(256),0,stream>>>(cvals, cidx, tk_blocks*8, valsb, permb);
  mlp_final<<<dim3(1),dim3(256),0,stream>>>(hbuf, valsb, permb, W1, b1, W2, b2, W3, b3, (float*)d_out);
}

// Round 8
// 985.521 us; speedup vs baseline: 1.0648x; 1.0462x over previous
//
#include <hip/hip_runtime.h>
#include <math.h>

#define HID 128

__device__ __forceinline__ float gelu_f(float x){
  return 0.5f*x*(1.0f+erff(x*0.70710678118654752440f));
}

// ---------- combined-weight precompute ----------
// Folds per-edge-type relation transforms (and prel/sqrt(d)/log2e scale) into the
// KQV projection:  x@(Wk@arel)*psc + (bk@arel)*psc  ==  ((x@Wk+bk)@arel)*psc.
// Wc layout per layer L: [type a: 128x640 row-major][type b: 128x384 row-major]
//   type a cols: [0..127]=q | [128..383]=et0 ktv | [384..639]=et1 ktv
//   type b cols: [0..127]=q | [128..383]=et2 ktv
//   ktv 256-col block: h-major, per head {k-cols 32 (scaled) | v-cols 32}
// bc per layer: [a 640][b 384].
__global__ void mkw(const float* __restrict__ Wkqv, const float* __restrict__ bkqv,
                    const float* __restrict__ arel, const float* __restrict__ mrel,
                    const float* __restrict__ prel,
                    float* __restrict__ Wc, float* __restrict__ bc) {
  int L = blockIdx.x >> 10;
  int j = blockIdx.x & 1023;          // 0..1023: a cols 0..639, b cols 640..1023
  int t = threadIdx.x;                // k-row 0..127
  int type = (j < 640) ? 0 : 1;
  int jj = (j < 640) ? j : j - 640;
  const float* W    = Wkqv + ((size_t)L*2 + type)*49152;   // 128 x 384 (k|q|v)
  const float* bsrc = bkqv + ((size_t)L*2 + type)*384;
  int stride = type ? 384 : 640;
  float* Wdst = Wc + (size_t)L*(640+384)*128 + (type ? (size_t)640*128 : 0);
  float* bdst = bc + (size_t)L*1024 + (type ? 640 : 0);
  float val, bval;
  if (jj < 128) {                     // q passthrough (q = middle third)
    val  = W[(size_t)t*384 + 128 + jj];
    bval = bsrc[128 + jj];
  } else {
    int u = jj - 128;
    int et = type ? 2 : (u >> 8);
    int r = u & 255;
    int h = r >> 6, wofs = r & 63;
    const float* rel; int coloff; float scl;
    if (wofs < 32) {                  // k-transform col, scale folded
      rel = arel + ((size_t)L*3 + et)*4096 + (size_t)h*32*32 + wofs;
      coloff = h*32;
      scl = prel[((size_t)L*3 + et)*4 + h] * 0.17677669529663688f * 1.4426950408889634f;
    } else {                          // v-transform col
      rel = mrel + ((size_t)L*3 + et)*4096 + (size_t)h*32*32 + (wofs - 32);
      coloff = 256 + h*32;
      scl = 1.0f;
    }
    float a = 0.f, bb = 0.f;
    for (int d = 0; d < 32; d++) {
      float rv = rel[(size_t)d*32];   // rel[h][d][e]
      a  += W[(size_t)t*384 + coloff + d] * rv;
      bb += bsrc[coloff + d] * rv;
    }
    val = a * scl; bval = bb * scl;
  }
  Wdst[(size_t)t*stride + jj] = val;
  if (t == 0) bdst[jj] = bval;
}

// ---- fused projection GEMM: x (nrows x 128) @ Wc (128 x NJ*128) -> qbuf + ktv slots ----
// R5-proven inner loop (k-step-1). jj=0 -> qbuf; jj=1,2 -> ktv[slot0+row]; jj=3,4 -> ktv[slot1+row].
template<int RPB, int NJ>
__global__ void rowmm_f(const float* __restrict__ x, const float* __restrict__ Wc,
                        const float* __restrict__ bc,
                        float* __restrict__ qbuf, float* __restrict__ ktv,
                        int nrows, int qoff, int slot0, int slot1) {
  const int OUT = NJ*128;
  int t = threadIdx.x;                // 128 threads
  int r0 = blockIdx.x * RPB;
  __shared__ float xs[RPB][128];
#pragma unroll
  for (int r = 0; r < RPB; r++) {
    int row = r0 + r;
    xs[r][t] = (row < nrows) ? x[(size_t)row*128 + t] : 0.f;
  }
  __syncthreads();
  float acc[RPB][NJ] = {};
  for (int k = 0; k < 128; k++) {
    float wv[NJ];
#pragma unroll
    for (int jj = 0; jj < NJ; jj++) wv[jj] = Wc[(size_t)k*OUT + t + jj*128];
#pragma unroll
    for (int r = 0; r < RPB; r++) {
      float xv = xs[r][k];
#pragma unroll
      for (int jj = 0; jj < NJ; jj++) acc[r][jj] += xv * wv[jj];
    }
  }
#pragma unroll
  for (int r = 0; r < RPB; r++) {
    int row = r0 + r;
    if (row >= nrows) break;
#pragma unroll
    for (int jj = 0; jj < NJ; jj++) {
      float v = acc[r][jj] + bc[t + jj*128];
      if (jj == 0)      qbuf[(size_t)(qoff + row)*128 + t] = v;
      else if (jj <= 2) ktv[(size_t)(slot0 + row)*256 + (jj-1)*128 + t] = v;
      else              ktv[(size_t)(slot1 + row)*256 + (jj-3)*128 + t] = v;
    }
  }
}

// ---------- CSR build (dst-sorted; pure edges, no self loops) ----------
__global__ void hist_init(int* __restrict__ hist, int N) {
  int i = blockIdx.x*blockDim.x + threadIdx.x;
  if (i < N) hist[i] = 0;
}
__global__ void hist_count_all(const int* __restrict__ aa, const int* __restrict__ ab,
                               const int* __restrict__ ba,
                               int Eaa, int Eab, int Eba, int Na, int* __restrict__ hist) {
  int i = blockIdx.x*blockDim.x + threadIdx.x;
  int tot = Eaa + Eab + Eba;
  if (i >= tot) return;
  int dst;
  if (i < Eaa)            dst = aa[Eaa + i];
  else if (i < Eaa + Eab) dst = ab[Eab + (i - Eaa)] + Na;
  else                    dst = ba[Eba + (i - Eaa - Eab)];
  atomicAdd(hist + dst, 1);
}
__global__ void scan_excl(const int* __restrict__ hist, int* __restrict__ roff, int N) {
  __shared__ int part[1024];
  int t = threadIdx.x;
  int chunk = (N + 1023) / 1024;
  int b = t*chunk, e = b + chunk; if (e > N) e = N; if (b > N) b = N;
  int sum = 0;
  for (int i = b; i < e; i++) sum += hist[i];
  part[t] = sum;
  __syncthreads();
  for (int o = 1; o < 1024; o <<= 1) {
    int v = (t >= o) ? part[t - o] : 0;
    __syncthreads();
    part[t] += v;
    __syncthreads();
  }
  int run = (t == 0) ? 0 : part[t - 1];
  for (int i = b; i < e; i++) { roff[i] = run; run += hist[i]; }
  if (t == 1023) roff[N] = run;
}
// epack stores the unified ktv slot directly.
__global__ void fill_all(const int* __restrict__ aa, const int* __restrict__ ab,
                         const int* __restrict__ ba,
                         int Eaa, int Eab, int Eba, int Na,
                         int* __restrict__ cursor, int* __restrict__ epack) {
  int i = blockIdx.x*blockDim.x + threadIdx.x;
  int tot = Eaa + Eab + Eba;
  if (i >= tot) return;
  int dst, slot;
  if (i < Eaa)            { dst = aa[Eaa + i];                slot = aa[i]; }
  else if (i < Eaa + Eab) { int j = i - Eaa;       dst = ab[Eab + j] + Na; slot = ab[j] + Na; }
  else                    { int j = i - Eaa - Eab; dst = ba[Eba + j];      slot = ba[j] + 2*Na; }
  int pos = atomicAdd(cursor + dst, 1);
  epack[pos] = slot;
}

// ---------- fused HGT attention: score + online softmax (base-2) + aggregate ----------
// one wave per dst node; quarter-wave (16 lanes) per head, 2 dims per lane.
__global__ void seg_attn(const float* __restrict__ qbuf,
                         const float* __restrict__ ktv,
                         const int* __restrict__ roff, const int* __restrict__ epack,
                         float* __restrict__ agg, int Na, int N) {
  int wid = (blockIdx.x*blockDim.x + threadIdx.x) >> 6;
  int lane = threadIdx.x & 63;
  if (wid >= N) return;
  int h = lane >> 4;            // head
  int d0 = (lane & 15) * 2;     // dims d0, d0+1 of head h
  float2 q = *(const float2*)(qbuf + (size_t)wid*128 + h*32 + d0);
  int beg = roff[wid], end = roff[wid + 1];
  float m = -INFINITY, s = 0.f, a0 = 0.f, a1 = 0.f;
  if (beg < end) {
    const float* kp = ktv + (size_t)epack[beg]*256 + h*64 + d0;
    float2 kv = *(const float2*)kp;
    float2 vv = *(const float2*)(kp + 32);
    for (int i = beg; i < end; i++) {
      float2 ck = kv, cv = vv;
      if (i + 1 < end) {   // prefetch next edge
        const float* kpn = ktv + (size_t)epack[i+1]*256 + h*64 + d0;
        kv = *(const float2*)kpn;
        vv = *(const float2*)(kpn + 32);
      }
      float sc = q.x*ck.x + q.y*ck.y;
      sc += __shfl_xor(sc, 1, 64);
      sc += __shfl_xor(sc, 2, 64);
      sc += __shfl_xor(sc, 4, 64);
      sc += __shfl_xor(sc, 8, 64);   // per-head score, base-2 scaled
      float nm = fmaxf(m, sc);
      float scale = exp2f(m - nm);   // first edge: exp2(-inf)=0
      float e = exp2f(sc - nm);
      s  = s*scale  + e;
      a0 = a0*scale + e*cv.x;
      a1 = a1*scale + e*cv.y;
      m = nm;
    }
  }
  float inv = 1.f / (s + 1e-16f);
  float2 o2; o2.x = a0*inv; o2.y = a1*inv;
  *(float2*)(agg + (size_t)wid*128 + h*32 + d0) = o2;
}

// ---- fused finish for both types: gelu(agg) @ Wout + bout, gated skip, opt gelu ----
// R5-proven inner loop (k-step-1).
template<int RPB>
__global__ void finish2(const float* __restrict__ agg,
                        const float* __restrict__ xa, const float* __restrict__ xb,
                        float* __restrict__ ha, float* __restrict__ hb,
                        const float* __restrict__ WoL, const float* __restrict__ boL,
                        const float* __restrict__ skipL, int do_gelu, int Na, int Nb) {
  int nba = (Na + RPB - 1)/RPB;
  const float *xsrc, *Wo, *bo; float* h; float sgraw; int nrows, r0, aggoff;
  if ((int)blockIdx.x < nba) { xsrc=xa; h=ha; Wo=WoL; bo=boL; sgraw=skipL[0]; nrows=Na; r0=blockIdx.x*RPB; aggoff=0; }
  else { xsrc=xb; h=hb; Wo=WoL+16384; bo=boL+128; sgraw=skipL[1]; nrows=Nb; r0=(blockIdx.x-nba)*RPB; aggoff=Na; }
  int t = threadIdx.x;            // 128
  __shared__ float gs[RPB][128];
#pragma unroll
  for (int r = 0; r < RPB; r++) {
    int row = r0 + r;
    float a = (row < nrows) ? agg[(size_t)(row + aggoff)*128 + t] : 0.f;
    gs[r][t] = gelu_f(a);
  }
  __syncthreads();
  float acc[RPB] = {};
  for (int k = 0; k < 128; k++) {
    float wv = Wo[(size_t)k*128 + t];
#pragma unroll
    for (int r = 0; r < RPB; r++) acc[r] += gs[r][k]*wv;
  }
  float sg = 1.f/(1.f + expf(-sgraw));
#pragma unroll
  for (int r = 0; r < RPB; r++) {
    int row = r0 + r;
    if (row >= nrows) break;
    float g = acc[r] + bo[t];
    float v = sg*g + (1.f - sg)*xsrc[(size_t)row*128 + t];
    h[(size_t)row*128 + t] = do_gelu ? gelu_f(v) : v;
  }
}

// LayerNorm over 128 then gelu, in place, both types. One wave per row.
__global__ void ln_gelu2(float* __restrict__ h, const float* __restrict__ g,
                         const float* __restrict__ b, int Na, int N) {
  int idx = blockIdx.x*blockDim.x + threadIdx.x;
  int row = idx >> 6, lane = idx & 63;
  if (row >= N) return;
  int po = (row < Na) ? 0 : 128;
  float x0 = h[(size_t)row*128 + lane];
  float x1 = h[(size_t)row*128 + 64 + lane];
  float sum = x0 + x1;
#pragma unroll
  for (int o = 32; o; o >>= 1) sum += __shfl_xor(sum, o, 64);
  float mu = sum * (1.f/128.f);
  float d0 = x0 - mu, d1 = x1 - mu;
  float vs = d0*d0 + d1*d1;
#pragma unroll
  for (int o = 32; o; o >>= 1) vs += __shfl_xor(vs, o, 64);
  float inv = 1.f / sqrtf(vs*(1.f/128.f) + 1e-5f);
  h[(size_t)row*128 + lane]      = gelu_f(d0*inv*g[po + lane] + b[po + lane]);
  h[(size_t)row*128 + 64 + lane] = gelu_f(d1*inv*g[po + 64 + lane] + b[po + 64 + lane]);
}

// x1[n] = dot(h[n,:], Wgat[:,0]) — one wave per row
__global__ void gat_x1(const float* __restrict__ h, const float* __restrict__ Wg,
                       float* __restrict__ x1, int N) {
  int idx = blockIdx.x*blockDim.x + threadIdx.x;
  int row = idx >> 6, lane = idx & 63;
  if (row >= N) return;
  float a = h[(size_t)row*128 + lane]*Wg[lane] + h[(size_t)row*128 + 64 + lane]*Wg[64 + lane];
#pragma unroll
  for (int o = 32; o; o >>= 1) a += __shfl_xor(a, o, 64);
  if (lane == 0) x1[row] = a;
}

// fused GAT scorer via CSR: thread per node, online softmax (self-loop handled inline)
__global__ void gat_all(const float* __restrict__ x1, const int* __restrict__ roff,
                        const int* __restrict__ epack,
                        const float* __restrict__ asrc, const float* __restrict__ adst,
                        int Na, int N, float* __restrict__ score) {
  int n = blockIdx.x*blockDim.x + threadIdx.x;
  if (n >= N) return;
  float xd = x1[n];
  float as_ = asrc[0], ad = adst[0];
  float e0 = xd*as_ + xd*ad;
  e0 = (e0 > 0.f) ? e0 : 0.2f*e0;
  float m = e0, s = 1.f, acc = xd;
  int beg = roff[n], end = roff[n + 1];
  for (int i = beg; i < end; i++) {
    int slot = epack[i];
    int sg = (slot < Na) ? slot : slot - Na;   // global src node index
    float xs = x1[sg];
    float e = xs*as_ + xd*ad;
    e = (e > 0.f) ? e : 0.2f*e;
    float nm = fmaxf(m, e);
    float sc = __expf(m - nm), ee = __expf(e - nm);
    s = s*sc + ee;  acc = acc*sc + ee*xs;  m = nm;
  }
  score[n] = acc / (s + 1e-16f);
}

// ---- parallel top-8 ----
__global__ void topk_stage1(const float* __restrict__ score, const float* __restrict__ bgat,
                            int N, float* __restrict__ cvals, int* __restrict__ cidx) {
  __shared__ float bv[256];
  __shared__ int   bi[256];
  int t = threadIdx.x;
  int chunk = (N + gridDim.x - 1) / gridDim.x;   // <= 256 by construction
  int i = blockIdx.x * chunk + t;
  float bg = bgat[0];
  bool valid = (t < chunk && i < N);
  float myv = valid ? score[i] + bg : -INFINITY;
  int   myi = valid ? i : 0x7FFFFFFF;
  for (int k = 0; k < 8; k++) {
    bv[t] = myv; bi[t] = myi;
    __syncthreads();
    for (int o = 128; o; o >>= 1) {
      if (t < o) {
        if (bv[t+o] > bv[t] || (bv[t+o] == bv[t] && bi[t+o] < bi[t])) { bv[t]=bv[t+o]; bi[t]=bi[t+o]; }
      }
      __syncthreads();
    }
    if (t == 0) { cvals[blockIdx.x*8 + k] = bv[0]; cidx[blockIdx.x*8 + k] = bi[0]; }
    if (myi == bi[0]) myv = -INFINITY;   // pop winner
    __syncthreads();
  }
}

__global__ void topk_stage2(const float* __restrict__ cvals, const int* __restrict__ cidx,
                            int C, float* __restrict__ vals, int* __restrict__ perm) {
  __shared__ float bv[256];
  __shared__ int   bi[256];
  __shared__ int   seli[8];
  int t = threadIdx.x;
  for (int k = 0; k < 8; k++) {
    float best = -INFINITY; int besti = 0x7FFFFFFF;
    for (int i = t; i < C; i += 256) {
      int id = cidx[i];
      bool taken = false;
      for (int j = 0; j < k; j++) if (seli[j] == id) taken = true;
      if (taken) continue;
      float v = cvals[i];
      if (v > best || (v == best && id < besti)) { best = v; besti = id; }
    }
    bv[t] = best; bi[t] = besti;
    __syncthreads();
    for (int o = 128; o; o >>= 1) {
      if (t < o) {
        if (bv[t+o] > bv[t] || (bv[t+o] == bv[t] && bi[t+o] < bi[t])) { bv[t]=bv[t+o]; bi[t]=bi[t+o]; }
      }
      __syncthreads();
    }
    if (t == 0) { seli[k] = bi[0]; vals[k] = bv[0]; perm[k] = bi[0]; }
    __syncthreads();
  }
}

__global__ void mlp_final(const float* __restrict__ h, const float* __restrict__ vals,
                          const int* __restrict__ perm,
                          const float* __restrict__ W1, const float* __restrict__ b1,
                          const float* __restrict__ W2, const float* __restrict__ b2,
                          const float* __restrict__ W3, const float* __restrict__ b3,
                          float* __restrict__ out) {
  __shared__ float hp[1024], v1[128], v2[64];
  int t = threadIdx.x;  // 256
  for (int i = t; i < 1024; i += 256) {
    int r = i >> 7, d = i & 127;
    hp[i] = h[(size_t)perm[r]*128 + d] * tanhf(vals[r]);
  }
  __syncthreads();
  if (t < 128) {
    float a = 0.f;
    for (int k = 0; k < 1024; k++) a += hp[k]*W1[(size_t)k*128 + t];
    v1[t] = gelu_f(a + b1[t]);
  }
  __syncthreads();
  if (t < 64) {
    float a = 0.f;
    for (int k = 0; k < 128; k++) a += v1[k]*W2[(size_t)k*64 + t];
    v2[t] = gelu_f(a + b2[t]);
  }
  __syncthreads();
  if (t < 16) {
    float a = 0.f;
    for (int k = 0; k < 64; k++) a += v2[k]*W3[(size_t)k*16 + t];
    float r = gelu_f(a + b3[t]);
    if (isnan(r)) r = 0.f;
    else if (isinf(r)) r = (r > 0.f) ? 3.4028234663852886e38f : -3.4028234663852886e38f;
    out[t] = r;
  }
}

extern "C" void kernel_launch(void* const* d_in, const int* in_sizes, int n_in,
                              void* d_out, int out_size, void* d_ws, size_t ws_size,
                              hipStream_t stream) {
  const float* x_a  = (const float*)d_in[0];
  const float* x_b  = (const float*)d_in[1];
  const int* ei_aa  = (const int*)d_in[2];
  const int* ei_ab  = (const int*)d_in[3];
  const int* ei_ba  = (const int*)d_in[4];
  const float* Wkqv = (const float*)d_in[5];
  const float* bkqv = (const float*)d_in[6];
  const float* Wout = (const float*)d_in[7];
  const float* bout = (const float*)d_in[8];
  const float* skip = (const float*)d_in[9];
  const float* arel = (const float*)d_in[10];
  const float* mrel = (const float*)d_in[11];
  const float* prel = (const float*)d_in[12];
  const float* ln_g = (const float*)d_in[13];
  const float* ln_b = (const float*)d_in[14];
  const float* Wgat = (const float*)d_in[15];
  const float* att_src = (const float*)d_in[16];
  const float* att_dst = (const float*)d_in[17];
  const float* bgat = (const float*)d_in[18];
  const float* W1 = (const float*)d_in[19];
  const float* b1 = (const float*)d_in[20];
  const float* W2 = (const float*)d_in[21];
  const float* b2 = (const float*)d_in[22];
  const float* W3 = (const float*)d_in[23];
  const float* b3 = (const float*)d_in[24];

  int Na = in_sizes[0]/128, Nb = in_sizes[1]/128, N = Na + Nb;
  int Eaa = in_sizes[2]/2, Eab = in_sizes[3]/2, Eba = in_sizes[4]/2;
  int Etot = Eaa + Eab + Eba;

  // workspace layout
  float* w = (float*)d_ws;
  size_t off = 0;
  auto alloc = [&](size_t n) { float* p = w + off; off += n; return p; };
  float* hbuf  = alloc((size_t)N*128);
  float* qbuf  = alloc((size_t)N*128);
  float* ktvA  = alloc((size_t)(2*Na + Nb)*256);   // unified, slot-indexed
  float* agg   = alloc((size_t)N*128);
  float* Wc    = alloc((size_t)3*1024*128);        // combined weights, 3 layers x (a640|b384)
  float* bc    = alloc((size_t)3*1024);
  float* x1buf = alloc((size_t)N);
  float* score = alloc((size_t)N);
  float* valsb = alloc(8);
  int*   permb = (int*)alloc(8);
  float* cvals = alloc(2048);
  int*   cidx  = (int*)alloc(2048);
  int*   hist  = (int*)alloc((size_t)N);
  int*   roff  = (int*)alloc((size_t)N + 1);
  int*   cursor= (int*)alloc((size_t)N);
  int*   epack = (int*)alloc((size_t)Etot);

  float* h_a = hbuf;
  float* h_b = hbuf + (size_t)Na*128;

  // ---- precompute combined projection weights (rel transforms folded) ----
  mkw<<<dim3(3*1024),dim3(128),0,stream>>>(Wkqv, bkqv, arel, mrel, prel, Wc, bc);

  // ---- build dst-sorted CSR once (pure edges; self-loops handled analytically) ----
  hist_init<<<dim3((N+255)/256),dim3(256),0,stream>>>(hist, N);
  hist_count_all<<<dim3((Etot+255)/256),dim3(256),0,stream>>>(ei_aa, ei_ab, ei_ba, Eaa, Eab, Eba, Na, hist);
  scan_excl<<<dim3(1),dim3(1024),0,stream>>>(hist, roff, N);
  hipMemcpyAsync(cursor, roff, (size_t)N*sizeof(int), hipMemcpyDeviceToDevice, stream);
  fill_all<<<dim3((Etot+255)/256),dim3(256),0,stream>>>(ei_aa, ei_ab, ei_ba, Eaa, Eab, Eba, Na, cursor, epack);

  const int RPB = 8;
  int nba = (Na + RPB - 1)/RPB, nbb = (Nb + RPB - 1)/RPB;

  for (int L = 0; L < 3; L++) {
    const float* xa_in = (L == 0) ? x_a : h_a;
    const float* xb_in = (L == 0) ? x_b : h_b;
    const float* WcA = Wc + (size_t)L*1024*128;
    const float* WcB = WcA + (size_t)640*128;
    const float* bcA = bc + (size_t)L*1024;
    const float* bcB = bcA + 640;
    // projection GEMMs emit q + relation-transformed ktv directly
    rowmm_f<RPB,5><<<dim3(nba),dim3(128),0,stream>>>(xa_in, WcA, bcA, qbuf, ktvA, Na, 0,  0,    Na);
    rowmm_f<RPB,3><<<dim3(nbb),dim3(128),0,stream>>>(xb_in, WcB, bcB, qbuf, ktvA, Nb, Na, 2*Na, 2*Na);
    seg_attn<<<dim3((N+3)/4),dim3(256),0,stream>>>(qbuf, ktvA, roff, epack, agg, Na, N);
    int do_gelu = (L == 0) ? 0 : 1;
    finish2<RPB><<<dim3(nba + nbb),dim3(128),0,stream>>>(agg, xa_in, xb_in, h_a, h_b,
                                                         Wout + (size_t)L*2*16384,
                                                         bout + (size_t)L*2*128,
                                                         skip + L*2, do_gelu, Na, Nb);
    if (L == 0) {
      ln_gelu2<<<dim3((N+3)/4),dim3(256),0,stream>>>(hbuf, ln_g, ln_b, Na, N);
    }
  }

  // ---- GAT scorer + SAGPool top-k + MLP ----
  gat_x1<<<dim3((N+3)/4),dim3(256),0,stream>>>(hbuf, Wgat, x1buf, N);
  gat_all<<<dim3((N+255)/256),dim3(256),0,stream>>>(x1buf, roff, epack, att_src, att_dst, Na, N, score);
  int tk_blocks = (N + 255)/256;
  topk_stage1<<<dim3(tk_blocks),dim3(256),0,stream>>>(score, bgat, N, cvals, cidx);
  topk_stage2<<<dim3(1),dim3(256),0,stream>>>(cvals, cidx, tk_blocks*8, valsb, permb);
  mlp_final<<<dim3(1),dim3(256),0,stream>>>(hbuf, valsb, permb, W1, b1, W2, b2, W3, b3, (float*)d_out);
}

// Round 9
// 918.368 us; speedup vs baseline: 1.1427x; 1.0731x over previous
//
#include <hip/hip_runtime.h>
#include <math.h>

#define HID 128

__device__ __forceinline__ float gelu_f(float x){
  return 0.5f*x*(1.0f+erff(x*0.70710678118654752440f));
}

// ---------- combined-weight precompute ----------
// Folds per-edge-type relation transforms (and prel/sqrt(d)/log2e scale) into the
// KQV projection:  x@(Wk@arel)*psc + (bk@arel)*psc  ==  ((x@Wk+bk)@arel)*psc.
// Wc layout per layer L: [type a: 128x640 row-major][type b: 128x384 row-major]
//   type a cols: [0..127]=q | [128..383]=et0 ktv | [384..639]=et1 ktv
//   type b cols: [0..127]=q | [128..383]=et2 ktv
//   ktv 256-col block: h-major, per head {k-cols 32 (scaled) | v-cols 32}
// bc per layer: [a 640][b 384].
__global__ void mkw(const float* __restrict__ Wkqv, const float* __restrict__ bkqv,
                    const float* __restrict__ arel, const float* __restrict__ mrel,
                    const float* __restrict__ prel,
                    float* __restrict__ Wc, float* __restrict__ bc) {
  int L = blockIdx.x >> 10;
  int j = blockIdx.x & 1023;          // 0..1023: a cols 0..639, b cols 640..1023
  int t = threadIdx.x;                // k-row 0..127
  int type = (j < 640) ? 0 : 1;
  int jj = (j < 640) ? j : j - 640;
  const float* W    = Wkqv + ((size_t)L*2 + type)*49152;   // 128 x 384 (k|q|v)
  const float* bsrc = bkqv + ((size_t)L*2 + type)*384;
  int stride = type ? 384 : 640;
  float* Wdst = Wc + (size_t)L*(640+384)*128 + (type ? (size_t)640*128 : 0);
  float* bdst = bc + (size_t)L*1024 + (type ? 640 : 0);
  float val, bval;
  if (jj < 128) {                     // q passthrough (q = middle third)
    val  = W[(size_t)t*384 + 128 + jj];
    bval = bsrc[128 + jj];
  } else {
    int u = jj - 128;
    int et = type ? 2 : (u >> 8);
    int r = u & 255;
    int h = r >> 6, wofs = r & 63;
    const float* rel; int coloff; float scl;
    if (wofs < 32) {                  // k-transform col, scale folded
      rel = arel + ((size_t)L*3 + et)*4096 + (size_t)h*32*32 + wofs;
      coloff = h*32;
      scl = prel[((size_t)L*3 + et)*4 + h] * 0.17677669529663688f * 1.4426950408889634f;
    } else {                          // v-transform col
      rel = mrel + ((size_t)L*3 + et)*4096 + (size_t)h*32*32 + (wofs - 32);
      coloff = 256 + h*32;
      scl = 1.0f;
    }
    float a = 0.f, bb = 0.f;
    for (int d = 0; d < 32; d++) {
      float rv = rel[(size_t)d*32];   // rel[h][d][e]
      a  += W[(size_t)t*384 + coloff + d] * rv;
      bb += bsrc[coloff + d] * rv;
    }
    val = a * scl; bval = bb * scl;
  }
  Wdst[(size_t)t*stride + jj] = val;
  if (t == 0) bdst[jj] = bval;
}

// ---------- 128x128 LDS-tiled projection GEMM ----------
// x (nrows x 128) @ Wc (128 x OUT) + bc -> col-tile routed to qbuf / ktv slots.
// 256 threads, 8x8 outputs/thread, K chunked by 32, A staged transposed (+4 pad).
__global__ __launch_bounds__(256, 2)
void gemm_tile(const float* __restrict__ x, const float* __restrict__ Wc,
               const float* __restrict__ bc,
               float* __restrict__ qbuf, float* __restrict__ ktv,
               int nrows, int OUT, int qoff, int slot0, int slot1) {
  __shared__ float xs[32][132];   // [k][row], padded stride 132
  __shared__ float ws[32][128];   // [k][col]
  int tid = threadIdx.x;
  int r0 = blockIdx.x * 128;
  int ct = blockIdx.y;
  int ty = tid >> 4, tx = tid & 15;
  float acc[8][8] = {};
  for (int kc = 0; kc < 128; kc += 32) {
    __syncthreads();
#pragma unroll
    for (int it = 0; it < 4; it++) {          // stage x chunk, transposed
      int idx = it*256 + tid;
      int r = idx >> 3;
      int k4 = (idx & 7) << 2;
      int row = r0 + r;
      float4 v = (row < nrows) ? *(const float4*)(x + (size_t)row*128 + kc + k4)
                               : make_float4(0.f, 0.f, 0.f, 0.f);
      xs[k4+0][r] = v.x; xs[k4+1][r] = v.y; xs[k4+2][r] = v.z; xs[k4+3][r] = v.w;
    }
#pragma unroll
    for (int it = 0; it < 4; it++) {          // stage W chunk
      int idx = it*256 + tid;
      int k = idx >> 5;
      int c4 = (idx & 31) << 2;
      *(float4*)&ws[k][c4] = *(const float4*)(Wc + (size_t)(kc + k)*OUT + ct*128 + c4);
    }
    __syncthreads();
#pragma unroll
    for (int k = 0; k < 32; k++) {
      float4 a0 = *(const float4*)&xs[k][ty*4];
      float4 a1 = *(const float4*)&xs[k][64 + ty*4];
      float4 b0 = *(const float4*)&ws[k][tx*4];
      float4 b1 = *(const float4*)&ws[k][64 + tx*4];
      float av[8] = {a0.x,a0.y,a0.z,a0.w,a1.x,a1.y,a1.z,a1.w};
      float bv[8] = {b0.x,b0.y,b0.z,b0.w,b1.x,b1.y,b1.z,b1.w};
#pragma unroll
      for (int i = 0; i < 8; i++)
#pragma unroll
        for (int j = 0; j < 8; j++)
          acc[i][j] += av[i]*bv[j];
    }
  }
  // epilogue: bias + route by col tile
  bool isq = (ct == 0);
  int sbase = 0, cofs = 0;
  if (!isq) {
    if (ct <= 2) { sbase = slot0; cofs = (ct-1)*128; }
    else         { sbase = slot1; cofs = (ct-3)*128; }
  }
#pragma unroll
  for (int i = 0; i < 8; i++) {
    int r = (i < 4) ? (ty*4 + i) : (64 + ty*4 + i - 4);
    int row = r0 + r;
    if (row >= nrows) continue;
#pragma unroll
    for (int half = 0; half < 2; half++) {
      int c0 = half*64 + tx*4;
      float4 v;
      v.x = acc[i][half*4+0] + bc[ct*128 + c0 + 0];
      v.y = acc[i][half*4+1] + bc[ct*128 + c0 + 1];
      v.z = acc[i][half*4+2] + bc[ct*128 + c0 + 2];
      v.w = acc[i][half*4+3] + bc[ct*128 + c0 + 3];
      if (isq) *(float4*)(qbuf + (size_t)(qoff + row)*128 + c0) = v;
      else     *(float4*)(ktv + (size_t)(sbase + row)*256 + cofs + c0) = v;
    }
  }
}

// ---------- tiled finish: gelu(agg) @ Wout + bout, gated skip, opt gelu ----------
__global__ __launch_bounds__(256, 2)
void finish_tile(const float* __restrict__ agg,
                 const float* __restrict__ xa, const float* __restrict__ xb,
                 float* __restrict__ ha, float* __restrict__ hb,
                 const float* __restrict__ WoL, const float* __restrict__ boL,
                 const float* __restrict__ skipL, int do_gelu, int Na, int Nb) {
  __shared__ float xs[32][132];
  __shared__ float ws[32][128];
  int nba = (Na + 127) >> 7;
  const float *xsrc, *Wo, *bo; float* h; float sgraw; int nrows, r0, aggoff;
  if ((int)blockIdx.x < nba) {
    xsrc = xa; h = ha; Wo = WoL; bo = boL; sgraw = skipL[0];
    nrows = Na; r0 = blockIdx.x*128; aggoff = 0;
  } else {
    xsrc = xb; h = hb; Wo = WoL + 16384; bo = boL + 128; sgraw = skipL[1];
    nrows = Nb; r0 = ((int)blockIdx.x - nba)*128; aggoff = Na;
  }
  int tid = threadIdx.x;
  int ty = tid >> 4, tx = tid & 15;
  float acc[8][8] = {};
  for (int kc = 0; kc < 128; kc += 32) {
    __syncthreads();
#pragma unroll
    for (int it = 0; it < 4; it++) {          // stage gelu(agg) chunk, transposed
      int idx = it*256 + tid;
      int r = idx >> 3;
      int k4 = (idx & 7) << 2;
      int row = r0 + r;
      float4 v = (row < nrows)
        ? *(const float4*)(agg + (size_t)(aggoff + row)*128 + kc + k4)
        : make_float4(0.f, 0.f, 0.f, 0.f);
      xs[k4+0][r] = gelu_f(v.x); xs[k4+1][r] = gelu_f(v.y);
      xs[k4+2][r] = gelu_f(v.z); xs[k4+3][r] = gelu_f(v.w);
    }
#pragma unroll
    for (int it = 0; it < 4; it++) {          // stage Wout chunk
      int idx = it*256 + tid;
      int k = idx >> 5;
      int c4 = (idx & 31) << 2;
      *(float4*)&ws[k][c4] = *(const float4*)(Wo + (size_t)(kc + k)*128 + c4);
    }
    __syncthreads();
#pragma unroll
    for (int k = 0; k < 32; k++) {
      float4 a0 = *(const float4*)&xs[k][ty*4];
      float4 a1 = *(const float4*)&xs[k][64 + ty*4];
      float4 b0 = *(const float4*)&ws[k][tx*4];
      float4 b1 = *(const float4*)&ws[k][64 + tx*4];
      float av[8] = {a0.x,a0.y,a0.z,a0.w,a1.x,a1.y,a1.z,a1.w};
      float bv[8] = {b0.x,b0.y,b0.z,b0.w,b1.x,b1.y,b1.z,b1.w};
#pragma unroll
      for (int i = 0; i < 8; i++)
#pragma unroll
        for (int j = 0; j < 8; j++)
          acc[i][j] += av[i]*bv[j];
    }
  }
  float sg = 1.f/(1.f + expf(-sgraw));
#pragma unroll
  for (int i = 0; i < 8; i++) {
    int r = (i < 4) ? (ty*4 + i) : (64 + ty*4 + i - 4);
    int row = r0 + r;
    if (row >= nrows) continue;
#pragma unroll
    for (int half = 0; half < 2; half++) {
      int c0 = half*64 + tx*4;
      float4 xv = *(const float4*)(xsrc + (size_t)row*128 + c0);
      float4 v;
      v.x = sg*(acc[i][half*4+0] + bo[c0+0]) + (1.f - sg)*xv.x;
      v.y = sg*(acc[i][half*4+1] + bo[c0+1]) + (1.f - sg)*xv.y;
      v.z = sg*(acc[i][half*4+2] + bo[c0+2]) + (1.f - sg)*xv.z;
      v.w = sg*(acc[i][half*4+3] + bo[c0+3]) + (1.f - sg)*xv.w;
      if (do_gelu) { v.x = gelu_f(v.x); v.y = gelu_f(v.y); v.z = gelu_f(v.z); v.w = gelu_f(v.w); }
      *(float4*)(h + (size_t)row*128 + c0) = v;
    }
  }
}

// ---------- CSR build (dst-sorted; pure edges, no self loops) ----------
__global__ void hist_init(int* __restrict__ hist, int N) {
  int i = blockIdx.x*blockDim.x + threadIdx.x;
  if (i < N) hist[i] = 0;
}
__global__ void hist_count_all(const int* __restrict__ aa, const int* __restrict__ ab,
                               const int* __restrict__ ba,
                               int Eaa, int Eab, int Eba, int Na, int* __restrict__ hist) {
  int i = blockIdx.x*blockDim.x + threadIdx.x;
  int tot = Eaa + Eab + Eba;
  if (i >= tot) return;
  int dst;
  if (i < Eaa)            dst = aa[Eaa + i];
  else if (i < Eaa + Eab) dst = ab[Eab + (i - Eaa)] + Na;
  else                    dst = ba[Eba + (i - Eaa - Eab)];
  atomicAdd(hist + dst, 1);
}
__global__ void scan_excl(const int* __restrict__ hist, int* __restrict__ roff, int N) {
  __shared__ int part[1024];
  int t = threadIdx.x;
  int chunk = (N + 1023) / 1024;
  int b = t*chunk, e = b + chunk; if (e > N) e = N; if (b > N) b = N;
  int sum = 0;
  for (int i = b; i < e; i++) sum += hist[i];
  part[t] = sum;
  __syncthreads();
  for (int o = 1; o < 1024; o <<= 1) {
    int v = (t >= o) ? part[t - o] : 0;
    __syncthreads();
    part[t] += v;
    __syncthreads();
  }
  int run = (t == 0) ? 0 : part[t - 1];
  for (int i = b; i < e; i++) { roff[i] = run; run += hist[i]; }
  if (t == 1023) roff[N] = run;
}
// epack stores the unified ktv slot directly.
__global__ void fill_all(const int* __restrict__ aa, const int* __restrict__ ab,
                         const int* __restrict__ ba,
                         int Eaa, int Eab, int Eba, int Na,
                         int* __restrict__ cursor, int* __restrict__ epack) {
  int i = blockIdx.x*blockDim.x + threadIdx.x;
  int tot = Eaa + Eab + Eba;
  if (i >= tot) return;
  int dst, slot;
  if (i < Eaa)            { dst = aa[Eaa + i];                slot = aa[i]; }
  else if (i < Eaa + Eab) { int j = i - Eaa;       dst = ab[Eab + j] + Na; slot = ab[j] + Na; }
  else                    { int j = i - Eaa - Eab; dst = ba[Eba + j];      slot = ba[j] + 2*Na; }
  int pos = atomicAdd(cursor + dst, 1);
  epack[pos] = slot;
}

// ---------- fused HGT attention: score + online softmax (base-2) + aggregate ----------
// one wave per dst node; quarter-wave (16 lanes) per head, 2 dims per lane.
__global__ void seg_attn(const float* __restrict__ qbuf,
                         const float* __restrict__ ktv,
                         const int* __restrict__ roff, const int* __restrict__ epack,
                         float* __restrict__ agg, int Na, int N) {
  int wid = (blockIdx.x*blockDim.x + threadIdx.x) >> 6;
  int lane = threadIdx.x & 63;
  if (wid >= N) return;
  int h = lane >> 4;            // head
  int d0 = (lane & 15) * 2;     // dims d0, d0+1 of head h
  float2 q = *(const float2*)(qbuf + (size_t)wid*128 + h*32 + d0);
  int beg = roff[wid], end = roff[wid + 1];
  float m = -INFINITY, s = 0.f, a0 = 0.f, a1 = 0.f;
  if (beg < end) {
    const float* kp = ktv + (size_t)epack[beg]*256 + h*64 + d0;
    float2 kv = *(const float2*)kp;
    float2 vv = *(const float2*)(kp + 32);
    for (int i = beg; i < end; i++) {
      float2 ck = kv, cv = vv;
      if (i + 1 < end) {   // prefetch next edge
        const float* kpn = ktv + (size_t)epack[i+1]*256 + h*64 + d0;
        kv = *(const float2*)kpn;
        vv = *(const float2*)(kpn + 32);
      }
      float sc = q.x*ck.x + q.y*ck.y;
      sc += __shfl_xor(sc, 1, 64);
      sc += __shfl_xor(sc, 2, 64);
      sc += __shfl_xor(sc, 4, 64);
      sc += __shfl_xor(sc, 8, 64);   // per-head score, base-2 scaled
      float nm = fmaxf(m, sc);
      float scale = exp2f(m - nm);   // first edge: exp2(-inf)=0
      float e = exp2f(sc - nm);
      s  = s*scale  + e;
      a0 = a0*scale + e*cv.x;
      a1 = a1*scale + e*cv.y;
      m = nm;
    }
  }
  float inv = 1.f / (s + 1e-16f);
  float2 o2; o2.x = a0*inv; o2.y = a1*inv;
  *(float2*)(agg + (size_t)wid*128 + h*32 + d0) = o2;
}

// LayerNorm over 128 then gelu, in place, both types. One wave per row.
__global__ void ln_gelu2(float* __restrict__ h, const float* __restrict__ g,
                         const float* __restrict__ b, int Na, int N) {
  int idx = blockIdx.x*blockDim.x + threadIdx.x;
  int row = idx >> 6, lane = idx & 63;
  if (row >= N) return;
  int po = (row < Na) ? 0 : 128;
  float x0 = h[(size_t)row*128 + lane];
  float x1 = h[(size_t)row*128 + 64 + lane];
  float sum = x0 + x1;
#pragma unroll
  for (int o = 32; o; o >>= 1) sum += __shfl_xor(sum, o, 64);
  float mu = sum * (1.f/128.f);
  float d0 = x0 - mu, d1 = x1 - mu;
  float vs = d0*d0 + d1*d1;
#pragma unroll
  for (int o = 32; o; o >>= 1) vs += __shfl_xor(vs, o, 64);
  float inv = 1.f / sqrtf(vs*(1.f/128.f) + 1e-5f);
  h[(size_t)row*128 + lane]      = gelu_f(d0*inv*g[po + lane] + b[po + lane]);
  h[(size_t)row*128 + 64 + lane] = gelu_f(d1*inv*g[po + 64 + lane] + b[po + 64 + lane]);
}

// x1[n] = dot(h[n,:], Wgat[:,0]) — one wave per row
__global__ void gat_x1(const float* __restrict__ h, const float* __restrict__ Wg,
                       float* __restrict__ x1, int N) {
  int idx = blockIdx.x*blockDim.x + threadIdx.x;
  int row = idx >> 6, lane = idx & 63;
  if (row >= N) return;
  float a = h[(size_t)row*128 + lane]*Wg[lane] + h[(size_t)row*128 + 64 + lane]*Wg[64 + lane];
#pragma unroll
  for (int o = 32; o; o >>= 1) a += __shfl_xor(a, o, 64);
  if (lane == 0) x1[row] = a;
}

// fused GAT scorer via CSR: thread per node, online softmax (self-loop handled inline)
__global__ void gat_all(const float* __restrict__ x1, const int* __restrict__ roff,
                        const int* __restrict__ epack,
                        const float* __restrict__ asrc, const float* __restrict__ adst,
                        int Na, int N, float* __restrict__ score) {
  int n = blockIdx.x*blockDim.x + threadIdx.x;
  if (n >= N) return;
  float xd = x1[n];
  float as_ = asrc[0], ad = adst[0];
  float e0 = xd*as_ + xd*ad;
  e0 = (e0 > 0.f) ? e0 : 0.2f*e0;
  float m = e0, s = 1.f, acc = xd;
  int beg = roff[n], end = roff[n + 1];
  for (int i = beg; i < end; i++) {
    int slot = epack[i];
    int sg = (slot < Na) ? slot : slot - Na;   // global src node index
    float xs = x1[sg];
    float e = xs*as_ + xd*ad;
    e = (e > 0.f) ? e : 0.2f*e;
    float nm = fmaxf(m, e);
    float sc = __expf(m - nm), ee = __expf(e - nm);
    s = s*sc + ee;  acc = acc*sc + ee*xs;  m = nm;
  }
  score[n] = acc / (s + 1e-16f);
}

// ---- parallel top-8 ----
__global__ void topk_stage1(const float* __restrict__ score, const float* __restrict__ bgat,
                            int N, float* __restrict__ cvals, int* __restrict__ cidx) {
  __shared__ float bv[256];
  __shared__ int   bi[256];
  int t = threadIdx.x;
  int chunk = (N + gridDim.x - 1) / gridDim.x;   // <= 256 by construction
  int i = blockIdx.x * chunk + t;
  float bg = bgat[0];
  bool valid = (t < chunk && i < N);
  float myv = valid ? score[i] + bg : -INFINITY;
  int   myi = valid ? i : 0x7FFFFFFF;
  for (int k = 0; k < 8; k++) {
    bv[t] = myv; bi[t] = myi;
    __syncthreads();
    for (int o = 128; o; o >>= 1) {
      if (t < o) {
        if (bv[t+o] > bv[t] || (bv[t+o] == bv[t] && bi[t+o] < bi[t])) { bv[t]=bv[t+o]; bi[t]=bi[t+o]; }
      }
      __syncthreads();
    }
    if (t == 0) { cvals[blockIdx.x*8 + k] = bv[0]; cidx[blockIdx.x*8 + k] = bi[0]; }
    if (myi == bi[0]) myv = -INFINITY;   // pop winner
    __syncthreads();
  }
}

__global__ void topk_stage2(const float* __restrict__ cvals, const int* __restrict__ cidx,
                            int C, float* __restrict__ vals, int* __restrict__ perm) {
  __shared__ float bv[256];
  __shared__ int   bi[256];
  __shared__ int   seli[8];
  int t = threadIdx.x;
  for (int k = 0; k < 8; k++) {
    float best = -INFINITY; int besti = 0x7FFFFFFF;
    for (int i = t; i < C; i += 256) {
      int id = cidx[i];
      bool taken = false;
      for (int j = 0; j < k; j++) if (seli[j] == id) taken = true;
      if (taken) continue;
      float v = cvals[i];
      if (v > best || (v == best && id < besti)) { best = v; besti = id; }
    }
    bv[t] = best; bi[t] = besti;
    __syncthreads();
    for (int o = 128; o; o >>= 1) {
      if (t < o) {
        if (bv[t+o] > bv[t] || (bv[t+o] == bv[t] && bi[t+o] < bi[t])) { bv[t]=bv[t+o]; bi[t]=bi[t+o]; }
      }
      __syncthreads();
    }
    if (t == 0) { seli[k] = bi[0]; vals[k] = bv[0]; perm[k] = bi[0]; }
    __syncthreads();
  }
}

__global__ void mlp_final(const float* __restrict__ h, const float* __restrict__ vals,
                          const int* __restrict__ perm,
                          const float* __restrict__ W1, const float* __restrict__ b1,
                          const float* __restrict__ W2, const float* __restrict__ b2,
                          const float* __restrict__ W3, const float* __restrict__ b3,
                          float* __restrict__ out) {
  __shared__ float hp[1024], v1[128], v2[64];
  int t = threadIdx.x;  // 256
  for (int i = t; i < 1024; i += 256) {
    int r = i >> 7, d = i & 127;
    hp[i] = h[(size_t)perm[r]*128 + d] * tanhf(vals[r]);
  }
  __syncthreads();
  if (t < 128) {
    float a = 0.f;
    for (int k = 0; k < 1024; k++) a += hp[k]*W1[(size_t)k*128 + t];
    v1[t] = gelu_f(a + b1[t]);
  }
  __syncthreads();
  if (t < 64) {
    float a = 0.f;
    for (int k = 0; k < 128; k++) a += v1[k]*W2[(size_t)k*64 + t];
    v2[t] = gelu_f(a + b2[t]);
  }
  __syncthreads();
  if (t < 16) {
    float a = 0.f;
    for (int k = 0; k < 64; k++) a += v2[k]*W3[(size_t)k*16 + t];
    float r = gelu_f(a + b3[t]);
    if (isnan(r)) r = 0.f;
    else if (isinf(r)) r = (r > 0.f) ? 3.4028234663852886e38f : -3.4028234663852886e38f;
    out[t] = r;
  }
}

extern "C" void kernel_launch(void* const* d_in, const int* in_sizes, int n_in,
                              void* d_out, int out_size, void* d_ws, size_t ws_size,
                              hipStream_t stream) {
  const float* x_a  = (const float*)d_in[0];
  const float* x_b  = (const float*)d_in[1];
  const int* ei_aa  = (const int*)d_in[2];
  const int* ei_ab  = (const int*)d_in[3];
  const int* ei_ba  = (const int*)d_in[4];
  const float* Wkqv = (const float*)d_in[5];
  const float* bkqv = (const float*)d_in[6];
  const float* Wout = (const float*)d_in[7];
  const float* bout = (const float*)d_in[8];
  const float* skip = (const float*)d_in[9];
  const float* arel = (const float*)d_in[10];
  const float* mrel = (const float*)d_in[11];
  const float* prel = (const float*)d_in[12];
  const float* ln_g = (const float*)d_in[13];
  const float* ln_b = (const float*)d_in[14];
  const float* Wgat = (const float*)d_in[15];
  const float* att_src = (const float*)d_in[16];
  const float* att_dst = (const float*)d_in[17];
  const float* bgat = (const float*)d_in[18];
  const float* W1 = (const float*)d_in[19];
  const float* b1 = (const float*)d_in[20];
  const float* W2 = (const float*)d_in[21];
  const float* b2 = (const float*)d_in[22];
  const float* W3 = (const float*)d_in[23];
  const float* b3 = (const float*)d_in[24];

  int Na = in_sizes[0]/128, Nb = in_sizes[1]/128, N = Na + Nb;
  int Eaa = in_sizes[2]/2, Eab = in_sizes[3]/2, Eba = in_sizes[4]/2;
  int Etot = Eaa + Eab + Eba;

  // workspace layout
  float* w = (float*)d_ws;
  size_t off = 0;
  auto alloc = [&](size_t n) { float* p = w + off; off += n; return p; };
  float* hbuf  = alloc((size_t)N*128);
  float* qbuf  = alloc((size_t)N*128);
  float* ktvA  = alloc((size_t)(2*Na + Nb)*256);   // unified, slot-indexed
  float* agg   = alloc((size_t)N*128);
  float* Wc    = alloc((size_t)3*1024*128);        // combined weights, 3 layers x (a640|b384)
  float* bc    = alloc((size_t)3*1024);
  float* x1buf = alloc((size_t)N);
  float* score = alloc((size_t)N);
  float* valsb = alloc(8);
  int*   permb = (int*)alloc(8);
  float* cvals = alloc(2048);
  int*   cidx  = (int*)alloc(2048);
  int*   hist  = (int*)alloc((size_t)N);
  int*   roff  = (int*)alloc((size_t)N + 1);
  int*   cursor= (int*)alloc((size_t)N);
  int*   epack = (int*)alloc((size_t)Etot);

  float* h_a = hbuf;
  float* h_b = hbuf + (size_t)Na*128;

  // ---- precompute combined projection weights (rel transforms folded) ----
  mkw<<<dim3(3*1024),dim3(128),0,stream>>>(Wkqv, bkqv, arel, mrel, prel, Wc, bc);

  // ---- build dst-sorted CSR once (pure edges; self-loops handled analytically) ----
  hist_init<<<dim3((N+255)/256),dim3(256),0,stream>>>(hist, N);
  hist_count_all<<<dim3((Etot+255)/256),dim3(256),0,stream>>>(ei_aa, ei_ab, ei_ba, Eaa, Eab, Eba, Na, hist);
  scan_excl<<<dim3(1),dim3(1024),0,stream>>>(hist, roff, N);
  hipMemcpyAsync(cursor, roff, (size_t)N*sizeof(int), hipMemcpyDeviceToDevice, stream);
  fill_all<<<dim3((Etot+255)/256),dim3(256),0,stream>>>(ei_aa, ei_ab, ei_ba, Eaa, Eab, Eba, Na, cursor, epack);

  int nba = (Na + 127)/128, nbb = (Nb + 127)/128;

  for (int L = 0; L < 3; L++) {
    const float* xa_in = (L == 0) ? x_a : h_a;
    const float* xb_in = (L == 0) ? x_b : h_b;
    const float* WcA = Wc + (size_t)L*1024*128;
    const float* WcB = WcA + (size_t)640*128;
    const float* bcA = bc + (size_t)L*1024;
    const float* bcB = bcA + 640;
    // tiled projection GEMMs emit q + relation-transformed ktv directly
    gemm_tile<<<dim3(nba, 5),dim3(256),0,stream>>>(xa_in, WcA, bcA, qbuf, ktvA, Na, 640, 0,  0,    Na);
    gemm_tile<<<dim3(nbb, 3),dim3(256),0,stream>>>(xb_in, WcB, bcB, qbuf, ktvA, Nb, 384, Na, 2*Na, 2*Na);
    seg_attn<<<dim3((N+3)/4),dim3(256),0,stream>>>(qbuf, ktvA, roff, epack, agg, Na, N);
    int do_gelu = (L == 0) ? 0 : 1;
    finish_tile<<<dim3(nba + nbb),dim3(256),0,stream>>>(agg, xa_in, xb_in, h_a, h_b,
                                                        Wout + (size_t)L*2*16384,
                                                        bout + (size_t)L*2*128,
                                                        skip + L*2, do_gelu, Na, Nb);
    if (L == 0) {
      ln_gelu2<<<dim3((N+3)/4),dim3(256),0,stream>>>(hbuf, ln_g, ln_b, Na, N);
    }
  }

  // ---- GAT scorer + SAGPool top-k + MLP ----
  gat_x1<<<dim3((N+3)/4),dim3(256),0,stream>>>(hbuf, Wgat, x1buf, N);
  gat_all<<<dim3((N+255)/256),dim3(256),0,stream>>>(x1buf, roff, epack, att_src, att_dst, Na, N, score);
  int tk_blocks = (N + 255)/256;
  topk_stage1<<<dim3(tk_blocks),dim3(256),0,stream>>>(score, bgat, N, cvals, cidx);
  topk_stage2<<<dim3(1),dim3(256),0,stream>>>(cvals, cidx, tk_blocks*8, valsb, permb);
  mlp_final<<<dim3(1),dim3(256),0,stream>>>(hbuf, valsb, permb, W1, b1, W2, b2, W3, b3, (float*)d_out);
}

// Round 10
// 890.841 us; speedup vs baseline: 1.1780x; 1.0309x over previous
//
#include <hip/hip_runtime.h>
#include <math.h>

#define HID 128

__device__ __forceinline__ float gelu_f(float x){
  return 0.5f*x*(1.0f+erff(x*0.70710678118654752440f));
}

// ---------- combined-weight precompute ----------
// Folds per-edge-type relation transforms (and prel/sqrt(d)/log2e scale) into the
// KQV projection:  x@(Wk@arel)*psc + (bk@arel)*psc  ==  ((x@Wk+bk)@arel)*psc.
// Wc layout per layer L: [type a: 128x640 row-major][type b: 128x384 row-major]
//   type a cols: [0..127]=q | [128..383]=et0 ktv | [384..639]=et1 ktv
//   type b cols: [0..127]=q | [128..383]=et2 ktv
//   ktv 256-col block: h-major, per head {k-cols 32 (scaled) | v-cols 32}
// bc per layer: [a 640][b 384].
__global__ void mkw(const float* __restrict__ Wkqv, const float* __restrict__ bkqv,
                    const float* __restrict__ arel, const float* __restrict__ mrel,
                    const float* __restrict__ prel,
                    float* __restrict__ Wc, float* __restrict__ bc) {
  int L = blockIdx.x >> 10;
  int j = blockIdx.x & 1023;          // 0..1023: a cols 0..639, b cols 640..1023
  int t = threadIdx.x;                // k-row 0..127
  int type = (j < 640) ? 0 : 1;
  int jj = (j < 640) ? j : j - 640;
  const float* W    = Wkqv + ((size_t)L*2 + type)*49152;   // 128 x 384 (k|q|v)
  const float* bsrc = bkqv + ((size_t)L*2 + type)*384;
  int stride = type ? 384 : 640;
  float* Wdst = Wc + (size_t)L*(640+384)*128 + (type ? (size_t)640*128 : 0);
  float* bdst = bc + (size_t)L*1024 + (type ? 640 : 0);
  float val, bval;
  if (jj < 128) {                     // q passthrough (q = middle third)
    val  = W[(size_t)t*384 + 128 + jj];
    bval = bsrc[128 + jj];
  } else {
    int u = jj - 128;
    int et = type ? 2 : (u >> 8);
    int r = u & 255;
    int h = r >> 6, wofs = r & 63;
    const float* rel; int coloff; float scl;
    if (wofs < 32) {                  // k-transform col, scale folded
      rel = arel + ((size_t)L*3 + et)*4096 + (size_t)h*32*32 + wofs;
      coloff = h*32;
      scl = prel[((size_t)L*3 + et)*4 + h] * 0.17677669529663688f * 1.4426950408889634f;
    } else {                          // v-transform col
      rel = mrel + ((size_t)L*3 + et)*4096 + (size_t)h*32*32 + (wofs - 32);
      coloff = 256 + h*32;
      scl = 1.0f;
    }
    float a = 0.f, bb = 0.f;
    for (int d = 0; d < 32; d++) {
      float rv = rel[(size_t)d*32];   // rel[h][d][e]
      a  += W[(size_t)t*384 + coloff + d] * rv;
      bb += bsrc[coloff + d] * rv;
    }
    val = a * scl; bval = bb * scl;
  }
  Wdst[(size_t)t*stride + jj] = val;
  if (t == 0) bdst[jj] = bval;
}

// ---------- 128x128 LDS-tiled projection GEMM ----------
__global__ __launch_bounds__(256, 2)
void gemm_tile(const float* __restrict__ x, const float* __restrict__ Wc,
               const float* __restrict__ bc,
               float* __restrict__ qbuf, float* __restrict__ ktv,
               int nrows, int OUT, int qoff, int slot0, int slot1) {
  __shared__ float xs[32][132];   // [k][row], padded stride 132
  __shared__ float ws[32][128];   // [k][col]
  int tid = threadIdx.x;
  int r0 = blockIdx.x * 128;
  int ct = blockIdx.y;
  int ty = tid >> 4, tx = tid & 15;
  float acc[8][8] = {};
  for (int kc = 0; kc < 128; kc += 32) {
    __syncthreads();
#pragma unroll
    for (int it = 0; it < 4; it++) {          // stage x chunk, transposed
      int idx = it*256 + tid;
      int r = idx >> 3;
      int k4 = (idx & 7) << 2;
      int row = r0 + r;
      float4 v = (row < nrows) ? *(const float4*)(x + (size_t)row*128 + kc + k4)
                               : make_float4(0.f, 0.f, 0.f, 0.f);
      xs[k4+0][r] = v.x; xs[k4+1][r] = v.y; xs[k4+2][r] = v.z; xs[k4+3][r] = v.w;
    }
#pragma unroll
    for (int it = 0; it < 4; it++) {          // stage W chunk
      int idx = it*256 + tid;
      int k = idx >> 5;
      int c4 = (idx & 31) << 2;
      *(float4*)&ws[k][c4] = *(const float4*)(Wc + (size_t)(kc + k)*OUT + ct*128 + c4);
    }
    __syncthreads();
#pragma unroll
    for (int k = 0; k < 32; k++) {
      float4 a0 = *(const float4*)&xs[k][ty*4];
      float4 a1 = *(const float4*)&xs[k][64 + ty*4];
      float4 b0 = *(const float4*)&ws[k][tx*4];
      float4 b1 = *(const float4*)&ws[k][64 + tx*4];
      float av[8] = {a0.x,a0.y,a0.z,a0.w,a1.x,a1.y,a1.z,a1.w};
      float bv[8] = {b0.x,b0.y,b0.z,b0.w,b1.x,b1.y,b1.z,b1.w};
#pragma unroll
      for (int i = 0; i < 8; i++)
#pragma unroll
        for (int j = 0; j < 8; j++)
          acc[i][j] += av[i]*bv[j];
    }
  }
  bool isq = (ct == 0);
  int sbase = 0, cofs = 0;
  if (!isq) {
    if (ct <= 2) { sbase = slot0; cofs = (ct-1)*128; }
    else         { sbase = slot1; cofs = (ct-3)*128; }
  }
#pragma unroll
  for (int i = 0; i < 8; i++) {
    int r = (i < 4) ? (ty*4 + i) : (64 + ty*4 + i - 4);
    int row = r0 + r;
    if (row >= nrows) continue;
#pragma unroll
    for (int half = 0; half < 2; half++) {
      int c0 = half*64 + tx*4;
      float4 v;
      v.x = acc[i][half*4+0] + bc[ct*128 + c0 + 0];
      v.y = acc[i][half*4+1] + bc[ct*128 + c0 + 1];
      v.z = acc[i][half*4+2] + bc[ct*128 + c0 + 2];
      v.w = acc[i][half*4+3] + bc[ct*128 + c0 + 3];
      if (isq) *(float4*)(qbuf + (size_t)(qoff + row)*128 + c0) = v;
      else     *(float4*)(ktv + (size_t)(sbase + row)*256 + cofs + c0) = v;
    }
  }
}

// ---------- tiled finish: gelu(agg) @ Wout + bout, gated skip, opt gelu ----------
__global__ __launch_bounds__(256, 2)
void finish_tile(const float* __restrict__ agg,
                 const float* __restrict__ xa, const float* __restrict__ xb,
                 float* __restrict__ ha, float* __restrict__ hb,
                 const float* __restrict__ WoL, const float* __restrict__ boL,
                 const float* __restrict__ skipL, int do_gelu, int Na, int Nb) {
  __shared__ float xs[32][132];
  __shared__ float ws[32][128];
  int nba = (Na + 127) >> 7;
  const float *xsrc, *Wo, *bo; float* h; float sgraw; int nrows, r0, aggoff;
  if ((int)blockIdx.x < nba) {
    xsrc = xa; h = ha; Wo = WoL; bo = boL; sgraw = skipL[0];
    nrows = Na; r0 = blockIdx.x*128; aggoff = 0;
  } else {
    xsrc = xb; h = hb; Wo = WoL + 16384; bo = boL + 128; sgraw = skipL[1];
    nrows = Nb; r0 = ((int)blockIdx.x - nba)*128; aggoff = Na;
  }
  int tid = threadIdx.x;
  int ty = tid >> 4, tx = tid & 15;
  float acc[8][8] = {};
  for (int kc = 0; kc < 128; kc += 32) {
    __syncthreads();
#pragma unroll
    for (int it = 0; it < 4; it++) {          // stage gelu(agg) chunk, transposed
      int idx = it*256 + tid;
      int r = idx >> 3;
      int k4 = (idx & 7) << 2;
      int row = r0 + r;
      float4 v = (row < nrows)
        ? *(const float4*)(agg + (size_t)(aggoff + row)*128 + kc + k4)
        : make_float4(0.f, 0.f, 0.f, 0.f);
      xs[k4+0][r] = gelu_f(v.x); xs[k4+1][r] = gelu_f(v.y);
      xs[k4+2][r] = gelu_f(v.z); xs[k4+3][r] = gelu_f(v.w);
    }
#pragma unroll
    for (int it = 0; it < 4; it++) {          // stage Wout chunk
      int idx = it*256 + tid;
      int k = idx >> 5;
      int c4 = (idx & 31) << 2;
      *(float4*)&ws[k][c4] = *(const float4*)(Wo + (size_t)(kc + k)*128 + c4);
    }
    __syncthreads();
#pragma unroll
    for (int k = 0; k < 32; k++) {
      float4 a0 = *(const float4*)&xs[k][ty*4];
      float4 a1 = *(const float4*)&xs[k][64 + ty*4];
      float4 b0 = *(const float4*)&ws[k][tx*4];
      float4 b1 = *(const float4*)&ws[k][64 + tx*4];
      float av[8] = {a0.x,a0.y,a0.z,a0.w,a1.x,a1.y,a1.z,a1.w};
      float bv[8] = {b0.x,b0.y,b0.z,b0.w,b1.x,b1.y,b1.z,b1.w};
#pragma unroll
      for (int i = 0; i < 8; i++)
#pragma unroll
        for (int j = 0; j < 8; j++)
          acc[i][j] += av[i]*bv[j];
    }
  }
  float sg = 1.f/(1.f + expf(-sgraw));
#pragma unroll
  for (int i = 0; i < 8; i++) {
    int r = (i < 4) ? (ty*4 + i) : (64 + ty*4 + i - 4);
    int row = r0 + r;
    if (row >= nrows) continue;
#pragma unroll
    for (int half = 0; half < 2; half++) {
      int c0 = half*64 + tx*4;
      float4 xv = *(const float4*)(xsrc + (size_t)row*128 + c0);
      float4 v;
      v.x = sg*(acc[i][half*4+0] + bo[c0+0]) + (1.f - sg)*xv.x;
      v.y = sg*(acc[i][half*4+1] + bo[c0+1]) + (1.f - sg)*xv.y;
      v.z = sg*(acc[i][half*4+2] + bo[c0+2]) + (1.f - sg)*xv.z;
      v.w = sg*(acc[i][half*4+3] + bo[c0+3]) + (1.f - sg)*xv.w;
      if (do_gelu) { v.x = gelu_f(v.x); v.y = gelu_f(v.y); v.z = gelu_f(v.z); v.w = gelu_f(v.w); }
      *(float4*)(h + (size_t)row*128 + c0) = v;
    }
  }
}

// ---------- CSR build (dst-sorted; pure edges, no self loops) ----------
__global__ void hist_init(int* __restrict__ hist, int N) {
  int i = blockIdx.x*blockDim.x + threadIdx.x;
  if (i < N) hist[i] = 0;
}
__global__ void hist_count_all(const int* __restrict__ aa, const int* __restrict__ ab,
                               const int* __restrict__ ba,
                               int Eaa, int Eab, int Eba, int Na, int* __restrict__ hist) {
  int i = blockIdx.x*blockDim.x + threadIdx.x;
  int tot = Eaa + Eab + Eba;
  if (i >= tot) return;
  int dst;
  if (i < Eaa)            dst = aa[Eaa + i];
  else if (i < Eaa + Eab) dst = ab[Eab + (i - Eaa)] + Na;
  else                    dst = ba[Eba + (i - Eaa - Eab)];
  atomicAdd(hist + dst, 1);
}
__global__ void scan_excl(const int* __restrict__ hist, int* __restrict__ roff, int N) {
  __shared__ int part[1024];
  int t = threadIdx.x;
  int chunk = (N + 1023) / 1024;
  int b = t*chunk, e = b + chunk; if (e > N) e = N; if (b > N) b = N;
  int sum = 0;
  for (int i = b; i < e; i++) sum += hist[i];
  part[t] = sum;
  __syncthreads();
  for (int o = 1; o < 1024; o <<= 1) {
    int v = (t >= o) ? part[t - o] : 0;
    __syncthreads();
    part[t] += v;
    __syncthreads();
  }
  int run = (t == 0) ? 0 : part[t - 1];
  for (int i = b; i < e; i++) { roff[i] = run; run += hist[i]; }
  if (t == 1023) roff[N] = run;
}
// epack stores the unified ktv slot directly.
__global__ void fill_all(const int* __restrict__ aa, const int* __restrict__ ab,
                         const int* __restrict__ ba,
                         int Eaa, int Eab, int Eba, int Na,
                         int* __restrict__ cursor, int* __restrict__ epack) {
  int i = blockIdx.x*blockDim.x + threadIdx.x;
  int tot = Eaa + Eab + Eba;
  if (i >= tot) return;
  int dst, slot;
  if (i < Eaa)            { dst = aa[Eaa + i];                slot = aa[i]; }
  else if (i < Eaa + Eab) { int j = i - Eaa;       dst = ab[Eab + j] + Na; slot = ab[j] + Na; }
  else                    { int j = i - Eaa - Eab; dst = ba[Eba + j];      slot = ba[j] + 2*Na; }
  int pos = atomicAdd(cursor + dst, 1);
  epack[pos] = slot;
}

// ---------- fused HGT attention, 4-way edge-parallel ----------
// one wave per dst node; quarter-wave (16 lanes) owns edge stream beg+q, beg+q+4, ...
// lane u (0..15) of each quarter covers head u>>2, dims ((u&3)*8 .. +7).
// Independent online-softmax per quarter (base-2), butterfly-merged at the end.
__global__ void seg_attn(const float* __restrict__ qbuf,
                         const float* __restrict__ ktv,
                         const int* __restrict__ roff, const int* __restrict__ epack,
                         float* __restrict__ agg, int Na, int N) {
  int wid = (blockIdx.x*blockDim.x + threadIdx.x) >> 6;
  int lane = threadIdx.x & 63;
  if (wid >= N) return;
  int quarter = lane >> 4;
  int u = lane & 15;
  int h = u >> 2;               // head
  int d0 = (u & 3) * 8;         // 8 dims of head h
  const float* qp = qbuf + (size_t)wid*128 + h*32 + d0;
  float4 qa = *(const float4*)qp;
  float4 qb = *(const float4*)(qp + 4);
  int beg = roff[wid], end = roff[wid + 1];
  float m = -1e30f, s = 0.f;    // finite sentinel: avoids inf-inf NaN in merge
  float4 aA = make_float4(0.f,0.f,0.f,0.f), aB = make_float4(0.f,0.f,0.f,0.f);
  int i = beg + quarter;
  float4 ka, kb, va, vb;
  if (i < end) {
    const float* kp = ktv + (size_t)epack[i]*256 + h*64 + d0;
    ka = *(const float4*)kp;      kb = *(const float4*)(kp + 4);
    va = *(const float4*)(kp+32); vb = *(const float4*)(kp + 36);
  }
  for (; i < end; i += 4) {
    float4 cka = ka, ckb = kb, cva = va, cvb = vb;
    int nx = i + 4;
    if (nx < end) {               // prefetch next edge of this stream
      const float* kp = ktv + (size_t)epack[nx]*256 + h*64 + d0;
      ka = *(const float4*)kp;      kb = *(const float4*)(kp + 4);
      va = *(const float4*)(kp+32); vb = *(const float4*)(kp + 36);
    }
    float sc = qa.x*cka.x + qa.y*cka.y + qa.z*cka.z + qa.w*cka.w
             + qb.x*ckb.x + qb.y*ckb.y + qb.z*ckb.z + qb.w*ckb.w;
    sc += __shfl_xor(sc, 1, 64);
    sc += __shfl_xor(sc, 2, 64);  // full head score (base-2 scaled), uniform in 4-lane group
    float nm = fmaxf(m, sc);
    float scale = exp2f(m - nm);
    float e = exp2f(sc - nm);
    s = s*scale + e;
    aA.x = aA.x*scale + e*cva.x; aA.y = aA.y*scale + e*cva.y;
    aA.z = aA.z*scale + e*cva.z; aA.w = aA.w*scale + e*cva.w;
    aB.x = aB.x*scale + e*cvb.x; aB.y = aB.y*scale + e*cvb.y;
    aB.z = aB.z*scale + e*cvb.z; aB.w = aB.w*scale + e*cvb.w;
    m = nm;
  }
  // merge the 4 quarter states (butterfly over xor 16, 32)
#pragma unroll
  for (int off = 16; off <= 32; off <<= 1) {
    float mo = __shfl_xor(m, off, 64);
    float so = __shfl_xor(s, off, 64);
    float A0 = __shfl_xor(aA.x, off, 64), A1 = __shfl_xor(aA.y, off, 64);
    float A2 = __shfl_xor(aA.z, off, 64), A3 = __shfl_xor(aA.w, off, 64);
    float B0 = __shfl_xor(aB.x, off, 64), B1 = __shfl_xor(aB.y, off, 64);
    float B2 = __shfl_xor(aB.z, off, 64), B3 = __shfl_xor(aB.w, off, 64);
    float nm = fmaxf(m, mo);
    float c1 = exp2f(m - nm), c2 = exp2f(mo - nm);
    s = s*c1 + so*c2;
    aA.x = aA.x*c1 + A0*c2; aA.y = aA.y*c1 + A1*c2;
    aA.z = aA.z*c1 + A2*c2; aA.w = aA.w*c1 + A3*c2;
    aB.x = aB.x*c1 + B0*c2; aB.y = aB.y*c1 + B1*c2;
    aB.z = aB.z*c1 + B2*c2; aB.w = aB.w*c1 + B3*c2;
    m = nm;
  }
  if (quarter == 0) {
    float inv = 1.f / (s + 1e-16f);
    float4 o1, o2;
    o1.x = aA.x*inv; o1.y = aA.y*inv; o1.z = aA.z*inv; o1.w = aA.w*inv;
    o2.x = aB.x*inv; o2.y = aB.y*inv; o2.z = aB.z*inv; o2.w = aB.w*inv;
    float* op = agg + (size_t)wid*128 + h*32 + d0;
    *(float4*)op = o1;
    *(float4*)(op + 4) = o2;
  }
}

// LayerNorm over 128 then gelu, in place, both types. One wave per row.
__global__ void ln_gelu2(float* __restrict__ h, const float* __restrict__ g,
                         const float* __restrict__ b, int Na, int N) {
  int idx = blockIdx.x*blockDim.x + threadIdx.x;
  int row = idx >> 6, lane = idx & 63;
  if (row >= N) return;
  int po = (row < Na) ? 0 : 128;
  float x0 = h[(size_t)row*128 + lane];
  float x1 = h[(size_t)row*128 + 64 + lane];
  float sum = x0 + x1;
#pragma unroll
  for (int o = 32; o; o >>= 1) sum += __shfl_xor(sum, o, 64);
  float mu = sum * (1.f/128.f);
  float d0 = x0 - mu, d1 = x1 - mu;
  float vs = d0*d0 + d1*d1;
#pragma unroll
  for (int o = 32; o; o >>= 1) vs += __shfl_xor(vs, o, 64);
  float inv = 1.f / sqrtf(vs*(1.f/128.f) + 1e-5f);
  h[(size_t)row*128 + lane]      = gelu_f(d0*inv*g[po + lane] + b[po + lane]);
  h[(size_t)row*128 + 64 + lane] = gelu_f(d1*inv*g[po + 64 + lane] + b[po + 64 + lane]);
}

// x1[n] = dot(h[n,:], Wgat[:,0]) — one wave per row
__global__ void gat_x1(const float* __restrict__ h, const float* __restrict__ Wg,
                       float* __restrict__ x1, int N) {
  int idx = blockIdx.x*blockDim.x + threadIdx.x;
  int row = idx >> 6, lane = idx & 63;
  if (row >= N) return;
  float a = h[(size_t)row*128 + lane]*Wg[lane] + h[(size_t)row*128 + 64 + lane]*Wg[64 + lane];
#pragma unroll
  for (int o = 32; o; o >>= 1) a += __shfl_xor(a, o, 64);
  if (lane == 0) x1[row] = a;
}

// fused GAT scorer via CSR: thread per node, online softmax (self-loop handled inline)
__global__ void gat_all(const float* __restrict__ x1, const int* __restrict__ roff,
                        const int* __restrict__ epack,
                        const float* __restrict__ asrc, const float* __restrict__ adst,
                        int Na, int N, float* __restrict__ score) {
  int n = blockIdx.x*blockDim.x + threadIdx.x;
  if (n >= N) return;
  float xd = x1[n];
  float as_ = asrc[0], ad = adst[0];
  float e0 = xd*as_ + xd*ad;
  e0 = (e0 > 0.f) ? e0 : 0.2f*e0;
  float m = e0, s = 1.f, acc = xd;
  int beg = roff[n], end = roff[n + 1];
  for (int i = beg; i < end; i++) {
    int slot = epack[i];
    int sg = (slot < Na) ? slot : slot - Na;   // global src node index
    float xs = x1[sg];
    float e = xs*as_ + xd*ad;
    e = (e > 0.f) ? e : 0.2f*e;
    float nm = fmaxf(m, e);
    float sc = __expf(m - nm), ee = __expf(e - nm);
    s = s*sc + ee;  acc = acc*sc + ee*xs;  m = nm;
  }
  score[n] = acc / (s + 1e-16f);
}

// ---- parallel top-8 ----
__global__ void topk_stage1(const float* __restrict__ score, const float* __restrict__ bgat,
                            int N, float* __restrict__ cvals, int* __restrict__ cidx) {
  __shared__ float bv[256];
  __shared__ int   bi[256];
  int t = threadIdx.x;
  int chunk = (N + gridDim.x - 1) / gridDim.x;   // <= 256 by construction
  int i = blockIdx.x * chunk + t;
  float bg = bgat[0];
  bool valid = (t < chunk && i < N);
  float myv = valid ? score[i] + bg : -INFINITY;
  int   myi = valid ? i : 0x7FFFFFFF;
  for (int k = 0; k < 8; k++) {
    bv[t] = myv; bi[t] = myi;
    __syncthreads();
    for (int o = 128; o; o >>= 1) {
      if (t < o) {
        if (bv[t+o] > bv[t] || (bv[t+o] == bv[t] && bi[t+o] < bi[t])) { bv[t]=bv[t+o]; bi[t]=bi[t+o]; }
      }
      __syncthreads();
    }
    if (t == 0) { cvals[blockIdx.x*8 + k] = bv[0]; cidx[blockIdx.x*8 + k] = bi[0]; }
    if (myi == bi[0]) myv = -INFINITY;   // pop winner
    __syncthreads();
  }
}

__global__ void topk_stage2(const float* __restrict__ cvals, const int* __restrict__ cidx,
                            int C, float* __restrict__ vals, int* __restrict__ perm) {
  __shared__ float bv[256];
  __shared__ int   bi[256];
  __shared__ int   seli[8];
  int t = threadIdx.x;
  for (int k = 0; k < 8; k++) {
    float best = -INFINITY; int besti = 0x7FFFFFFF;
    for (int i = t; i < C; i += 256) {
      int id = cidx[i];
      bool taken = false;
      for (int j = 0; j < k; j++) if (seli[j] == id) taken = true;
      if (taken) continue;
      float v = cvals[i];
      if (v > best || (v == best && id < besti)) { best = v; besti = id; }
    }
    bv[t] = best; bi[t] = besti;
    __syncthreads();
    for (int o = 128; o; o >>= 1) {
      if (t < o) {
        if (bv[t+o] > bv[t] || (bv[t+o] == bv[t] && bi[t+o] < bi[t])) { bv[t]=bv[t+o]; bi[t]=bi[t+o]; }
      }
      __syncthreads();
    }
    if (t == 0) { seli[k] = bi[0]; vals[k] = bv[0]; perm[k] = bi[0]; }
    __syncthreads();
  }
}

__global__ void mlp_final(const float* __restrict__ h, const float* __restrict__ vals,
                          const int* __restrict__ perm,
                          const float* __restrict__ W1, const float* __restrict__ b1,
                          const float* __restrict__ W2, const float* __restrict__ b2,
                          const float* __restrict__ W3, const float* __restrict__ b3,
                          float* __restrict__ out) {
  __shared__ float hp[1024], v1[128], v2[64];
  int t = threadIdx.x;  // 256
  for (int i = t; i < 1024; i += 256) {
    int r = i >> 7, d = i & 127;
    hp[i] = h[(size_t)perm[r]*128 + d] * tanhf(vals[r]);
  }
  __syncthreads();
  if (t < 128) {
    float a = 0.f;
    for (int k = 0; k < 1024; k++) a += hp[k]*W1[(size_t)k*128 + t];
    v1[t] = gelu_f(a + b1[t]);
  }
  __syncthreads();
  if (t < 64) {
    float a = 0.f;
    for (int k = 0; k < 128; k++) a += v1[k]*W2[(size_t)k*64 + t];
    v2[t] = gelu_f(a + b2[t]);
  }
  __syncthreads();
  if (t < 16) {
    float a = 0.f;
    for (int k = 0; k < 64; k++) a += v2[k]*W3[(size_t)k*16 + t];
    float r = gelu_f(a + b3[t]);
    if (isnan(r)) r = 0.f;
    else if (isinf(r)) r = (r > 0.f) ? 3.4028234663852886e38f : -3.4028234663852886e38f;
    out[t] = r;
  }
}

extern "C" void kernel_launch(void* const* d_in, const int* in_sizes, int n_in,
                              void* d_out, int out_size, void* d_ws, size_t ws_size,
                              hipStream_t stream) {
  const float* x_a  = (const float*)d_in[0];
  const float* x_b  = (const float*)d_in[1];
  const int* ei_aa  = (const int*)d_in[2];
  const int* ei_ab  = (const int*)d_in[3];
  const int* ei_ba  = (const int*)d_in[4];
  const float* Wkqv = (const float*)d_in[5];
  const float* bkqv = (const float*)d_in[6];
  const float* Wout = (const float*)d_in[7];
  const float* bout = (const float*)d_in[8];
  const float* skip = (const float*)d_in[9];
  const float* arel = (const float*)d_in[10];
  const float* mrel = (const float*)d_in[11];
  const float* prel = (const float*)d_in[12];
  const float* ln_g = (const float*)d_in[13];
  const float* ln_b = (const float*)d_in[14];
  const float* Wgat = (const float*)d_in[15];
  const float* att_src = (const float*)d_in[16];
  const float* att_dst = (const float*)d_in[17];
  const float* bgat = (const float*)d_in[18];
  const float* W1 = (const float*)d_in[19];
  const float* b1 = (const float*)d_in[20];
  const float* W2 = (const float*)d_in[21];
  const float* b2 = (const float*)d_in[22];
  const float* W3 = (const float*)d_in[23];
  const float* b3 = (const float*)d_in[24];

  int Na = in_sizes[0]/128, Nb = in_sizes[1]/128, N = Na + Nb;
  int Eaa = in_sizes[2]/2, Eab = in_sizes[3]/2, Eba = in_sizes[4]/2;
  int Etot = Eaa + Eab + Eba;

  // workspace layout
  float* w = (float*)d_ws;
  size_t off = 0;
  auto alloc = [&](size_t n) { float* p = w + off; off += n; return p; };
  float* hbuf  = alloc((size_t)N*128);
  float* qbuf  = alloc((size_t)N*128);
  float* ktvA  = alloc((size_t)(2*Na + Nb)*256);   // unified, slot-indexed
  float* agg   = alloc((size_t)N*128);
  float* Wc    = alloc((size_t)3*1024*128);        // combined weights, 3 layers x (a640|b384)
  float* bc    = alloc((size_t)3*1024);
  float* x1buf = alloc((size_t)N);
  float* score = alloc((size_t)N);
  float* valsb = alloc(8);
  int*   permb = (int*)alloc(8);
  float* cvals = alloc(2048);
  int*   cidx  = (int*)alloc(2048);
  int*   hist  = (int*)alloc((size_t)N);
  int*   roff  = (int*)alloc((size_t)N + 1);
  int*   cursor= (int*)alloc((size_t)N);
  int*   epack = (int*)alloc((size_t)Etot);

  float* h_a = hbuf;
  float* h_b = hbuf + (size_t)Na*128;

  // ---- precompute combined projection weights (rel transforms folded) ----
  mkw<<<dim3(3*1024),dim3(128),0,stream>>>(Wkqv, bkqv, arel, mrel, prel, Wc, bc);

  // ---- build dst-sorted CSR once (pure edges; self-loops handled analytically) ----
  hist_init<<<dim3((N+255)/256),dim3(256),0,stream>>>(hist, N);
  hist_count_all<<<dim3((Etot+255)/256),dim3(256),0,stream>>>(ei_aa, ei_ab, ei_ba, Eaa, Eab, Eba, Na, hist);
  scan_excl<<<dim3(1),dim3(1024),0,stream>>>(hist, roff, N);
  hipMemcpyAsync(cursor, roff, (size_t)N*sizeof(int), hipMemcpyDeviceToDevice, stream);
  fill_all<<<dim3((Etot+255)/256),dim3(256),0,stream>>>(ei_aa, ei_ab, ei_ba, Eaa, Eab, Eba, Na, cursor, epack);

  int nba = (Na + 127)/128, nbb = (Nb + 127)/128;

  for (int L = 0; L < 3; L++) {
    const float* xa_in = (L == 0) ? x_a : h_a;
    const float* xb_in = (L == 0) ? x_b : h_b;
    const float* WcA = Wc + (size_t)L*1024*128;
    const float* WcB = WcA + (size_t)640*128;
    const float* bcA = bc + (size_t)L*1024;
    const float* bcB = bcA + 640;
    // tiled projection GEMMs emit q + relation-transformed ktv directly
    gemm_tile<<<dim3(nba, 5),dim3(256),0,stream>>>(xa_in, WcA, bcA, qbuf, ktvA, Na, 640, 0,  0,    Na);
    gemm_tile<<<dim3(nbb, 3),dim3(256),0,stream>>>(xb_in, WcB, bcB, qbuf, ktvA, Nb, 384, Na, 2*Na, 2*Na);
    seg_attn<<<dim3((N+3)/4),dim3(256),0,stream>>>(qbuf, ktvA, roff, epack, agg, Na, N);
    int do_gelu = (L == 0) ? 0 : 1;
    finish_tile<<<dim3(nba + nbb),dim3(256),0,stream>>>(agg, xa_in, xb_in, h_a, h_b,
                                                        Wout + (size_t)L*2*16384,
                                                        bout + (size_t)L*2*128,
                                                        skip + L*2, do_gelu, Na, Nb);
    if (L == 0) {
      ln_gelu2<<<dim3((N+3)/4),dim3(256),0,stream>>>(hbuf, ln_g, ln_b, Na, N);
    }
  }

  // ---- GAT scorer + SAGPool top-k + MLP ----
  gat_x1<<<dim3((N+3)/4),dim3(256),0,stream>>>(hbuf, Wgat, x1buf, N);
  gat_all<<<dim3((N+255)/256),dim3(256),0,stream>>>(x1buf, roff, epack, att_src, att_dst, Na, N, score);
  int tk_blocks = (N + 255)/256;
  topk_stage1<<<dim3(tk_blocks),dim3(256),0,stream>>>(score, bgat, N, cvals, cidx);
  topk_stage2<<<dim3(1),dim3(256),0,stream>>>(cvals, cidx, tk_blocks*8, valsb, permb);
  mlp_final<<<dim3(1),dim3(256),0,stream>>>(hbuf, valsb, permb, W1, b1, W2, b2, W3, b3, (float*)d_out);
}

// Round 11
// 821.960 us; speedup vs baseline: 1.2767x; 1.0838x over previous
//
#include <hip/hip_runtime.h>
#include <math.h>

#define HID 128

__device__ __forceinline__ float gelu_f(float x){
  return 0.5f*x*(1.0f+erff(x*0.70710678118654752440f));
}

// ---------- combined-weight precompute ----------
// Folds per-edge-type relation transforms (and prel/sqrt(d)/log2e scale) into the
// KQV projection:  x@(Wk@arel)*psc + (bk@arel)*psc  ==  ((x@Wk+bk)@arel)*psc.
// Wc layout per layer L: [type a: 128x640 row-major][type b: 128x384 row-major]
//   type a cols: [0..127]=q | [128..383]=et0 ktv | [384..639]=et1 ktv
//   type b cols: [0..127]=q | [128..383]=et2 ktv
//   ktv 256-col block: h-major, per head {k-cols 32 (scaled) | v-cols 32}
// bc per layer: [a 640][b 384].
__global__ void mkw(const float* __restrict__ Wkqv, const float* __restrict__ bkqv,
                    const float* __restrict__ arel, const float* __restrict__ mrel,
                    const float* __restrict__ prel,
                    float* __restrict__ Wc, float* __restrict__ bc) {
  int L = blockIdx.x >> 10;
  int j = blockIdx.x & 1023;          // 0..1023: a cols 0..639, b cols 640..1023
  int t = threadIdx.x;                // k-row 0..127
  int type = (j < 640) ? 0 : 1;
  int jj = (j < 640) ? j : j - 640;
  const float* W    = Wkqv + ((size_t)L*2 + type)*49152;   // 128 x 384 (k|q|v)
  const float* bsrc = bkqv + ((size_t)L*2 + type)*384;
  int stride = type ? 384 : 640;
  float* Wdst = Wc + (size_t)L*(640+384)*128 + (type ? (size_t)640*128 : 0);
  float* bdst = bc + (size_t)L*1024 + (type ? 640 : 0);
  float val, bval;
  if (jj < 128) {                     // q passthrough (q = middle third)
    val  = W[(size_t)t*384 + 128 + jj];
    bval = bsrc[128 + jj];
  } else {
    int u = jj - 128;
    int et = type ? 2 : (u >> 8);
    int r = u & 255;
    int h = r >> 6, wofs = r & 63;
    const float* rel; int coloff; float scl;
    if (wofs < 32) {                  // k-transform col, scale folded
      rel = arel + ((size_t)L*3 + et)*4096 + (size_t)h*32*32 + wofs;
      coloff = h*32;
      scl = prel[((size_t)L*3 + et)*4 + h] * 0.17677669529663688f * 1.4426950408889634f;
    } else {                          // v-transform col
      rel = mrel + ((size_t)L*3 + et)*4096 + (size_t)h*32*32 + (wofs - 32);
      coloff = 256 + h*32;
      scl = 1.0f;
    }
    float a = 0.f, bb = 0.f;
    for (int d = 0; d < 32; d++) {
      float rv = rel[(size_t)d*32];   // rel[h][d][e]
      a  += W[(size_t)t*384 + coloff + d] * rv;
      bb += bsrc[coloff + d] * rv;
    }
    val = a * scl; bval = bb * scl;
  }
  Wdst[(size_t)t*stride + jj] = val;
  if (t == 0) bdst[jj] = bval;
}

// ---------- 128x128 LDS-tiled projection GEMM ----------
__global__ __launch_bounds__(256, 2)
void gemm_tile(const float* __restrict__ x, const float* __restrict__ Wc,
               const float* __restrict__ bc,
               float* __restrict__ qbuf, float* __restrict__ ktv,
               int nrows, int OUT, int qoff, int slot0, int slot1) {
  __shared__ float xs[32][132];   // [k][row], padded stride 132
  __shared__ float ws[32][128];   // [k][col]
  int tid = threadIdx.x;
  int r0 = blockIdx.x * 128;
  int ct = blockIdx.y;
  int ty = tid >> 4, tx = tid & 15;
  float acc[8][8] = {};
  for (int kc = 0; kc < 128; kc += 32) {
    __syncthreads();
#pragma unroll
    for (int it = 0; it < 4; it++) {          // stage x chunk, transposed
      int idx = it*256 + tid;
      int r = idx >> 3;
      int k4 = (idx & 7) << 2;
      int row = r0 + r;
      float4 v = (row < nrows) ? *(const float4*)(x + (size_t)row*128 + kc + k4)
                               : make_float4(0.f, 0.f, 0.f, 0.f);
      xs[k4+0][r] = v.x; xs[k4+1][r] = v.y; xs[k4+2][r] = v.z; xs[k4+3][r] = v.w;
    }
#pragma unroll
    for (int it = 0; it < 4; it++) {          // stage W chunk
      int idx = it*256 + tid;
      int k = idx >> 5;
      int c4 = (idx & 31) << 2;
      *(float4*)&ws[k][c4] = *(const float4*)(Wc + (size_t)(kc + k)*OUT + ct*128 + c4);
    }
    __syncthreads();
#pragma unroll
    for (int k = 0; k < 32; k++) {
      float4 a0 = *(const float4*)&xs[k][ty*4];
      float4 a1 = *(const float4*)&xs[k][64 + ty*4];
      float4 b0 = *(const float4*)&ws[k][tx*4];
      float4 b1 = *(const float4*)&ws[k][64 + tx*4];
      float av[8] = {a0.x,a0.y,a0.z,a0.w,a1.x,a1.y,a1.z,a1.w};
      float bv[8] = {b0.x,b0.y,b0.z,b0.w,b1.x,b1.y,b1.z,b1.w};
#pragma unroll
      for (int i = 0; i < 8; i++)
#pragma unroll
        for (int j = 0; j < 8; j++)
          acc[i][j] += av[i]*bv[j];
    }
  }
  bool isq = (ct == 0);
  int sbase = 0, cofs = 0;
  if (!isq) {
    if (ct <= 2) { sbase = slot0; cofs = (ct-1)*128; }
    else         { sbase = slot1; cofs = (ct-3)*128; }
  }
#pragma unroll
  for (int i = 0; i < 8; i++) {
    int r = (i < 4) ? (ty*4 + i) : (64 + ty*4 + i - 4);
    int row = r0 + r;
    if (row >= nrows) continue;
#pragma unroll
    for (int half = 0; half < 2; half++) {
      int c0 = half*64 + tx*4;
      float4 v;
      v.x = acc[i][half*4+0] + bc[ct*128 + c0 + 0];
      v.y = acc[i][half*4+1] + bc[ct*128 + c0 + 1];
      v.z = acc[i][half*4+2] + bc[ct*128 + c0 + 2];
      v.w = acc[i][half*4+3] + bc[ct*128 + c0 + 3];
      if (isq) *(float4*)(qbuf + (size_t)(qoff + row)*128 + c0) = v;
      else     *(float4*)(ktv + (size_t)(sbase + row)*256 + cofs + c0) = v;
    }
  }
}

// ---------- tiled finish: gelu(agg) @ Wout + bout, gated skip, opt gelu ----------
__global__ __launch_bounds__(256, 2)
void finish_tile(const float* __restrict__ agg,
                 const float* __restrict__ xa, const float* __restrict__ xb,
                 float* __restrict__ ha, float* __restrict__ hb,
                 const float* __restrict__ WoL, const float* __restrict__ boL,
                 const float* __restrict__ skipL, int do_gelu, int Na, int Nb) {
  __shared__ float xs[32][132];
  __shared__ float ws[32][128];
  int nba = (Na + 127) >> 7;
  const float *xsrc, *Wo, *bo; float* h; float sgraw; int nrows, r0, aggoff;
  if ((int)blockIdx.x < nba) {
    xsrc = xa; h = ha; Wo = WoL; bo = boL; sgraw = skipL[0];
    nrows = Na; r0 = blockIdx.x*128; aggoff = 0;
  } else {
    xsrc = xb; h = hb; Wo = WoL + 16384; bo = boL + 128; sgraw = skipL[1];
    nrows = Nb; r0 = ((int)blockIdx.x - nba)*128; aggoff = Na;
  }
  int tid = threadIdx.x;
  int ty = tid >> 4, tx = tid & 15;
  float acc[8][8] = {};
  for (int kc = 0; kc < 128; kc += 32) {
    __syncthreads();
#pragma unroll
    for (int it = 0; it < 4; it++) {          // stage gelu(agg) chunk, transposed
      int idx = it*256 + tid;
      int r = idx >> 3;
      int k4 = (idx & 7) << 2;
      int row = r0 + r;
      float4 v = (row < nrows)
        ? *(const float4*)(agg + (size_t)(aggoff + row)*128 + kc + k4)
        : make_float4(0.f, 0.f, 0.f, 0.f);
      xs[k4+0][r] = gelu_f(v.x); xs[k4+1][r] = gelu_f(v.y);
      xs[k4+2][r] = gelu_f(v.z); xs[k4+3][r] = gelu_f(v.w);
    }
#pragma unroll
    for (int it = 0; it < 4; it++) {          // stage Wout chunk
      int idx = it*256 + tid;
      int k = idx >> 5;
      int c4 = (idx & 31) << 2;
      *(float4*)&ws[k][c4] = *(const float4*)(Wo + (size_t)(kc + k)*128 + c4);
    }
    __syncthreads();
#pragma unroll
    for (int k = 0; k < 32; k++) {
      float4 a0 = *(const float4*)&xs[k][ty*4];
      float4 a1 = *(const float4*)&xs[k][64 + ty*4];
      float4 b0 = *(const float4*)&ws[k][tx*4];
      float4 b1 = *(const float4*)&ws[k][64 + tx*4];
      float av[8] = {a0.x,a0.y,a0.z,a0.w,a1.x,a1.y,a1.z,a1.w};
      float bv[8] = {b0.x,b0.y,b0.z,b0.w,b1.x,b1.y,b1.z,b1.w};
#pragma unroll
      for (int i = 0; i < 8; i++)
#pragma unroll
        for (int j = 0; j < 8; j++)
          acc[i][j] += av[i]*bv[j];
    }
  }
  float sg = 1.f/(1.f + expf(-sgraw));
#pragma unroll
  for (int i = 0; i < 8; i++) {
    int r = (i < 4) ? (ty*4 + i) : (64 + ty*4 + i - 4);
    int row = r0 + r;
    if (row >= nrows) continue;
#pragma unroll
    for (int half = 0; half < 2; half++) {
      int c0 = half*64 + tx*4;
      float4 xv = *(const float4*)(xsrc + (size_t)row*128 + c0);
      float4 v;
      v.x = sg*(acc[i][half*4+0] + bo[c0+0]) + (1.f - sg)*xv.x;
      v.y = sg*(acc[i][half*4+1] + bo[c0+1]) + (1.f - sg)*xv.y;
      v.z = sg*(acc[i][half*4+2] + bo[c0+2]) + (1.f - sg)*xv.z;
      v.w = sg*(acc[i][half*4+3] + bo[c0+3]) + (1.f - sg)*xv.w;
      if (do_gelu) { v.x = gelu_f(v.x); v.y = gelu_f(v.y); v.z = gelu_f(v.z); v.w = gelu_f(v.w); }
      *(float4*)(h + (size_t)row*128 + c0) = v;
    }
  }
}

// ---------- CSR build (dst-sorted; pure edges, no self loops) ----------
__global__ void hist_init(int* __restrict__ hist, int N) {
  int i = blockIdx.x*blockDim.x + threadIdx.x;
  if (i < N) hist[i] = 0;
}
__global__ void hist_count_all(const int* __restrict__ aa, const int* __restrict__ ab,
                               const int* __restrict__ ba,
                               int Eaa, int Eab, int Eba, int Na, int* __restrict__ hist) {
  int i = blockIdx.x*blockDim.x + threadIdx.x;
  int tot = Eaa + Eab + Eba;
  if (i >= tot) return;
  int dst;
  if (i < Eaa)            dst = aa[Eaa + i];
  else if (i < Eaa + Eab) dst = ab[Eab + (i - Eaa)] + Na;
  else                    dst = ba[Eba + (i - Eaa - Eab)];
  atomicAdd(hist + dst, 1);
}
// ---- three-stage parallel exclusive scan (replaces single-block scan_excl) ----
// stage 1: per-block (256-chunk) sums
__global__ void scan_part(const int* __restrict__ hist, int* __restrict__ bsum, int N) {
  __shared__ int sd[256];
  int t = threadIdx.x;
  int i = blockIdx.x*256 + t;
  sd[t] = (i < N) ? hist[i] : 0;
  __syncthreads();
  for (int o = 128; o; o >>= 1) { if (t < o) sd[t] += sd[t+o]; __syncthreads(); }
  if (t == 0) bsum[blockIdx.x] = sd[0];
}
// stage 2: single small block, inclusive scan of block sums (nb <= 1024)
__global__ void scan_bsum(int* __restrict__ bsum, int nb) {
  __shared__ int sd[1024];
  int t = threadIdx.x;
  sd[t] = (t < nb) ? bsum[t] : 0;
  __syncthreads();
  for (int o = 1; o < 1024; o <<= 1) {
    int v = (t >= o) ? sd[t-o] : 0;
    __syncthreads();
    sd[t] += v;
    __syncthreads();
  }
  if (t < nb) bsum[t] = sd[t];
}
// stage 3: local inclusive scan + block offset -> exclusive roff (and cursor copy)
__global__ void scan_fill(const int* __restrict__ hist, const int* __restrict__ bsum,
                          int* __restrict__ roff, int* __restrict__ cursor, int N) {
  __shared__ int sd[256];
  int t = threadIdx.x;
  int i = blockIdx.x*256 + t;
  int v = (i < N) ? hist[i] : 0;
  sd[t] = v;
  __syncthreads();
  for (int o = 1; o < 256; o <<= 1) {
    int u = (t >= o) ? sd[t-o] : 0;
    __syncthreads();
    sd[t] += u;
    __syncthreads();
  }
  int boff = (blockIdx.x == 0) ? 0 : bsum[blockIdx.x - 1];
  if (i < N) {
    int excl = boff + sd[t] - v;
    roff[i] = excl;
    cursor[i] = excl;
    if (i == N - 1) roff[N] = boff + sd[t];
  }
}
// epack stores the unified ktv slot directly.
__global__ void fill_all(const int* __restrict__ aa, const int* __restrict__ ab,
                         const int* __restrict__ ba,
                         int Eaa, int Eab, int Eba, int Na,
                         int* __restrict__ cursor, int* __restrict__ epack) {
  int i = blockIdx.x*blockDim.x + threadIdx.x;
  int tot = Eaa + Eab + Eba;
  if (i >= tot) return;
  int dst, slot;
  if (i < Eaa)            { dst = aa[Eaa + i];                slot = aa[i]; }
  else if (i < Eaa + Eab) { int j = i - Eaa;       dst = ab[Eab + j] + Na; slot = ab[j] + Na; }
  else                    { int j = i - Eaa - Eab; dst = ba[Eba + j];      slot = ba[j] + 2*Na; }
  int pos = atomicAdd(cursor + dst, 1);
  epack[pos] = slot;
}

// ---------- fused HGT attention, 4-way edge-parallel ----------
// one wave per dst node; quarter-wave (16 lanes) owns edge stream beg+q, beg+q+4, ...
// lane u (0..15) of each quarter covers head u>>2, dims ((u&3)*8 .. +7).
// Independent online-softmax per quarter (base-2), butterfly-merged at the end.
__global__ void seg_attn(const float* __restrict__ qbuf,
                         const float* __restrict__ ktv,
                         const int* __restrict__ roff, const int* __restrict__ epack,
                         float* __restrict__ agg, int Na, int N) {
  int wid = (blockIdx.x*blockDim.x + threadIdx.x) >> 6;
  int lane = threadIdx.x & 63;
  if (wid >= N) return;
  int quarter = lane >> 4;
  int u = lane & 15;
  int h = u >> 2;               // head
  int d0 = (u & 3) * 8;         // 8 dims of head h
  const float* qp = qbuf + (size_t)wid*128 + h*32 + d0;
  float4 qa = *(const float4*)qp;
  float4 qb = *(const float4*)(qp + 4);
  int beg = roff[wid], end = roff[wid + 1];
  float m = -1e30f, s = 0.f;    // finite sentinel: avoids inf-inf NaN in merge
  float4 aA = make_float4(0.f,0.f,0.f,0.f), aB = make_float4(0.f,0.f,0.f,0.f);
  int i = beg + quarter;
  float4 ka, kb, va, vb;
  if (i < end) {
    const float* kp = ktv + (size_t)epack[i]*256 + h*64 + d0;
    ka = *(const float4*)kp;      kb = *(const float4*)(kp + 4);
    va = *(const float4*)(kp+32); vb = *(const float4*)(kp + 36);
  }
  for (; i < end; i += 4) {
    float4 cka = ka, ckb = kb, cva = va, cvb = vb;
    int nx = i + 4;
    if (nx < end) {               // prefetch next edge of this stream
      const float* kp = ktv + (size_t)epack[nx]*256 + h*64 + d0;
      ka = *(const float4*)kp;      kb = *(const float4*)(kp + 4);
      va = *(const float4*)(kp+32); vb = *(const float4*)(kp + 36);
    }
    float sc = qa.x*cka.x + qa.y*cka.y + qa.z*cka.z + qa.w*cka.w
             + qb.x*ckb.x + qb.y*ckb.y + qb.z*ckb.z + qb.w*ckb.w;
    sc += __shfl_xor(sc, 1, 64);
    sc += __shfl_xor(sc, 2, 64);  // full head score (base-2 scaled), uniform in 4-lane group
    float nm = fmaxf(m, sc);
    float scale = exp2f(m - nm);
    float e = exp2f(sc - nm);
    s = s*scale + e;
    aA.x = aA.x*scale + e*cva.x; aA.y = aA.y*scale + e*cva.y;
    aA.z = aA.z*scale + e*cva.z; aA.w = aA.w*scale + e*cva.w;
    aB.x = aB.x*scale + e*cvb.x; aB.y = aB.y*scale + e*cvb.y;
    aB.z = aB.z*scale + e*cvb.z; aB.w = aB.w*scale + e*cvb.w;
    m = nm;
  }
  // merge the 4 quarter states (butterfly over xor 16, 32)
#pragma unroll
  for (int off = 16; off <= 32; off <<= 1) {
    float mo = __shfl_xor(m, off, 64);
    float so = __shfl_xor(s, off, 64);
    float A0 = __shfl_xor(aA.x, off, 64), A1 = __shfl_xor(aA.y, off, 64);
    float A2 = __shfl_xor(aA.z, off, 64), A3 = __shfl_xor(aA.w, off, 64);
    float B0 = __shfl_xor(aB.x, off, 64), B1 = __shfl_xor(aB.y, off, 64);
    float B2 = __shfl_xor(aB.z, off, 64), B3 = __shfl_xor(aB.w, off, 64);
    float nm = fmaxf(m, mo);
    float c1 = exp2f(m - nm), c2 = exp2f(mo - nm);
    s = s*c1 + so*c2;
    aA.x = aA.x*c1 + A0*c2; aA.y = aA.y*c1 + A1*c2;
    aA.z = aA.z*c1 + A2*c2; aA.w = aA.w*c1 + A3*c2;
    aB.x = aB.x*c1 + B0*c2; aB.y = aB.y*c1 + B1*c2;
    aB.z = aB.z*c1 + B2*c2; aB.w = aB.w*c1 + B3*c2;
    m = nm;
  }
  if (quarter == 0) {
    float inv = 1.f / (s + 1e-16f);
    float4 o1, o2;
    o1.x = aA.x*inv; o1.y = aA.y*inv; o1.z = aA.z*inv; o1.w = aA.w*inv;
    o2.x = aB.x*inv; o2.y = aB.y*inv; o2.z = aB.z*inv; o2.w = aB.w*inv;
    float* op = agg + (size_t)wid*128 + h*32 + d0;
    *(float4*)op = o1;
    *(float4*)(op + 4) = o2;
  }
}

// LayerNorm over 128 then gelu, in place, both types. One wave per row.
__global__ void ln_gelu2(float* __restrict__ h, const float* __restrict__ g,
                         const float* __restrict__ b, int Na, int N) {
  int idx = blockIdx.x*blockDim.x + threadIdx.x;
  int row = idx >> 6, lane = idx & 63;
  if (row >= N) return;
  int po = (row < Na) ? 0 : 128;
  float x0 = h[(size_t)row*128 + lane];
  float x1 = h[(size_t)row*128 + 64 + lane];
  float sum = x0 + x1;
#pragma unroll
  for (int o = 32; o; o >>= 1) sum += __shfl_xor(sum, o, 64);
  float mu = sum * (1.f/128.f);
  float d0 = x0 - mu, d1 = x1 - mu;
  float vs = d0*d0 + d1*d1;
#pragma unroll
  for (int o = 32; o; o >>= 1) vs += __shfl_xor(vs, o, 64);
  float inv = 1.f / sqrtf(vs*(1.f/128.f) + 1e-5f);
  h[(size_t)row*128 + lane]      = gelu_f(d0*inv*g[po + lane] + b[po + lane]);
  h[(size_t)row*128 + 64 + lane] = gelu_f(d1*inv*g[po + 64 + lane] + b[po + 64 + lane]);
}

// x1[n] = dot(h[n,:], Wgat[:,0]) — one wave per row
__global__ void gat_x1(const float* __restrict__ h, const float* __restrict__ Wg,
                       float* __restrict__ x1, int N) {
  int idx = blockIdx.x*blockDim.x + threadIdx.x;
  int row = idx >> 6, lane = idx & 63;
  if (row >= N) return;
  float a = h[(size_t)row*128 + lane]*Wg[lane] + h[(size_t)row*128 + 64 + lane]*Wg[64 + lane];
#pragma unroll
  for (int o = 32; o; o >>= 1) a += __shfl_xor(a, o, 64);
  if (lane == 0) x1[row] = a;
}

// fused GAT scorer via CSR: thread per node, online softmax (self-loop handled inline)
__global__ void gat_all(const float* __restrict__ x1, const int* __restrict__ roff,
                        const int* __restrict__ epack,
                        const float* __restrict__ asrc, const float* __restrict__ adst,
                        int Na, int N, float* __restrict__ score) {
  int n = blockIdx.x*blockDim.x + threadIdx.x;
  if (n >= N) return;
  float xd = x1[n];
  float as_ = asrc[0], ad = adst[0];
  float e0 = xd*as_ + xd*ad;
  e0 = (e0 > 0.f) ? e0 : 0.2f*e0;
  float m = e0, s = 1.f, acc = xd;
  int beg = roff[n], end = roff[n + 1];
  for (int i = beg; i < end; i++) {
    int slot = epack[i];
    int sg = (slot < Na) ? slot : slot - Na;   // global src node index
    float xs = x1[sg];
    float e = xs*as_ + xd*ad;
    e = (e > 0.f) ? e : 0.2f*e;
    float nm = fmaxf(m, e);
    float sc = __expf(m - nm), ee = __expf(e - nm);
    s = s*sc + ee;  acc = acc*sc + ee*xs;  m = nm;
  }
  score[n] = acc / (s + 1e-16f);
}

// ---- parallel top-8 ----
__global__ void topk_stage1(const float* __restrict__ score, const float* __restrict__ bgat,
                            int N, float* __restrict__ cvals, int* __restrict__ cidx) {
  __shared__ float bv[256];
  __shared__ int   bi[256];
  int t = threadIdx.x;
  int chunk = (N + gridDim.x - 1) / gridDim.x;   // <= 256 by construction
  int i = blockIdx.x * chunk + t;
  float bg = bgat[0];
  bool valid = (t < chunk && i < N);
  float myv = valid ? score[i] + bg : -INFINITY;
  int   myi = valid ? i : 0x7FFFFFFF;
  for (int k = 0; k < 8; k++) {
    bv[t] = myv; bi[t] = myi;
    __syncthreads();
    for (int o = 128; o; o >>= 1) {
      if (t < o) {
        if (bv[t+o] > bv[t] || (bv[t+o] == bv[t] && bi[t+o] < bi[t])) { bv[t]=bv[t+o]; bi[t]=bi[t+o]; }
      }
      __syncthreads();
    }
    if (t == 0) { cvals[blockIdx.x*8 + k] = bv[0]; cidx[blockIdx.x*8 + k] = bi[0]; }
    if (myi == bi[0]) myv = -INFINITY;   // pop winner
    __syncthreads();
  }
}

__global__ void topk_stage2(const float* __restrict__ cvals, const int* __restrict__ cidx,
                            int C, float* __restrict__ vals, int* __restrict__ perm) {
  __shared__ float bv[256];
  __shared__ int   bi[256];
  __shared__ int   seli[8];
  int t = threadIdx.x;
  for (int k = 0; k < 8; k++) {
    float best = -INFINITY; int besti = 0x7FFFFFFF;
    for (int i = t; i < C; i += 256) {
      int id = cidx[i];
      bool taken = false;
      for (int j = 0; j < k; j++) if (seli[j] == id) taken = true;
      if (taken) continue;
      float v = cvals[i];
      if (v > best || (v == best && id < besti)) { best = v; besti = id; }
    }
    bv[t] = best; bi[t] = besti;
    __syncthreads();
    for (int o = 128; o; o >>= 1) {
      if (t < o) {
        if (bv[t+o] > bv[t] || (bv[t+o] == bv[t] && bi[t+o] < bi[t])) { bv[t]=bv[t+o]; bi[t]=bi[t+o]; }
      }
      __syncthreads();
    }
    if (t == 0) { seli[k] = bi[0]; vals[k] = bv[0]; perm[k] = bi[0]; }
    __syncthreads();
  }
}

__global__ void mlp_final(const float* __restrict__ h, const float* __restrict__ vals,
                          const int* __restrict__ perm,
                          const float* __restrict__ W1, const float* __restrict__ b1,
                          const float* __restrict__ W2, const float* __restrict__ b2,
                          const float* __restrict__ W3, const float* __restrict__ b3,
                          float* __restrict__ out) {
  __shared__ float hp[1024], v1[128], v2[64];
  int t = threadIdx.x;  // 256
  for (int i = t; i < 1024; i += 256) {
    int r = i >> 7, d = i & 127;
    hp[i] = h[(size_t)perm[r]*128 + d] * tanhf(vals[r]);
  }
  __syncthreads();
  if (t < 128) {
    float a = 0.f;
    for (int k = 0; k < 1024; k++) a += hp[k]*W1[(size_t)k*128 + t];
    v1[t] = gelu_f(a + b1[t]);
  }
  __syncthreads();
  if (t < 64) {
    float a = 0.f;
    for (int k = 0; k < 128; k++) a += v1[k]*W2[(size_t)k*64 + t];
    v2[t] = gelu_f(a + b2[t]);
  }
  __syncthreads();
  if (t < 16) {
    float a = 0.f;
    for (int k = 0; k < 64; k++) a += v2[k]*W3[(size_t)k*16 + t];
    float r = gelu_f(a + b3[t]);
    if (isnan(r)) r = 0.f;
    else if (isinf(r)) r = (r > 0.f) ? 3.4028234663852886e38f : -3.4028234663852886e38f;
    out[t] = r;
  }
}

extern "C" void kernel_launch(void* const* d_in, const int* in_sizes, int n_in,
                              void* d_out, int out_size, void* d_ws, size_t ws_size,
                              hipStream_t stream) {
  const float* x_a  = (const float*)d_in[0];
  const float* x_b  = (const float*)d_in[1];
  const int* ei_aa  = (const int*)d_in[2];
  const int* ei_ab  = (const int*)d_in[3];
  const int* ei_ba  = (const int*)d_in[4];
  const float* Wkqv = (const float*)d_in[5];
  const float* bkqv = (const float*)d_in[6];
  const float* Wout = (const float*)d_in[7];
  const float* bout = (const float*)d_in[8];
  const float* skip = (const float*)d_in[9];
  const float* arel = (const float*)d_in[10];
  const float* mrel = (const float*)d_in[11];
  const float* prel = (const float*)d_in[12];
  const float* ln_g = (const float*)d_in[13];
  const float* ln_b = (const float*)d_in[14];
  const float* Wgat = (const float*)d_in[15];
  const float* att_src = (const float*)d_in[16];
  const float* att_dst = (const float*)d_in[17];
  const float* bgat = (const float*)d_in[18];
  const float* W1 = (const float*)d_in[19];
  const float* b1 = (const float*)d_in[20];
  const float* W2 = (const float*)d_in[21];
  const float* b2 = (const float*)d_in[22];
  const float* W3 = (const float*)d_in[23];
  const float* b3 = (const float*)d_in[24];

  int Na = in_sizes[0]/128, Nb = in_sizes[1]/128, N = Na + Nb;
  int Eaa = in_sizes[2]/2, Eab = in_sizes[3]/2, Eba = in_sizes[4]/2;
  int Etot = Eaa + Eab + Eba;

  // workspace layout
  float* w = (float*)d_ws;
  size_t off = 0;
  auto alloc = [&](size_t n) { float* p = w + off; off += n; return p; };
  float* hbuf  = alloc((size_t)N*128);
  float* qbuf  = alloc((size_t)N*128);
  float* ktvA  = alloc((size_t)(2*Na + Nb)*256);   // unified, slot-indexed
  float* agg   = alloc((size_t)N*128);
  float* Wc    = alloc((size_t)3*1024*128);        // combined weights, 3 layers x (a640|b384)
  float* bc    = alloc((size_t)3*1024);
  float* x1buf = alloc((size_t)N);
  float* score = alloc((size_t)N);
  float* valsb = alloc(8);
  int*   permb = (int*)alloc(8);
  float* cvals = alloc(2048);
  int*   cidx  = (int*)alloc(2048);
  int*   hist  = (int*)alloc((size_t)N);
  int*   roff  = (int*)alloc((size_t)N + 1);
  int*   cursor= (int*)alloc((size_t)N);
  int*   bsum  = (int*)alloc(1024);
  int*   epack = (int*)alloc((size_t)Etot);

  float* h_a = hbuf;
  float* h_b = hbuf + (size_t)Na*128;

  // ---- precompute combined projection weights (rel transforms folded) ----
  mkw<<<dim3(3*1024),dim3(128),0,stream>>>(Wkqv, bkqv, arel, mrel, prel, Wc, bc);

  // ---- build dst-sorted CSR once (pure edges; self-loops handled analytically) ----
  int nsb = (N + 255)/256;   // scan blocks (<= 1024)
  hist_init<<<dim3(nsb),dim3(256),0,stream>>>(hist, N);
  hist_count_all<<<dim3((Etot+255)/256),dim3(256),0,stream>>>(ei_aa, ei_ab, ei_ba, Eaa, Eab, Eba, Na, hist);
  scan_part<<<dim3(nsb),dim3(256),0,stream>>>(hist, bsum, N);
  scan_bsum<<<dim3(1),dim3(1024),0,stream>>>(bsum, nsb);
  scan_fill<<<dim3(nsb),dim3(256),0,stream>>>(hist, bsum, roff, cursor, N);
  fill_all<<<dim3((Etot+255)/256),dim3(256),0,stream>>>(ei_aa, ei_ab, ei_ba, Eaa, Eab, Eba, Na, cursor, epack);

  int nba = (Na + 127)/128, nbb = (Nb + 127)/128;

  for (int L = 0; L < 3; L++) {
    const float* xa_in = (L == 0) ? x_a : h_a;
    const float* xb_in = (L == 0) ? x_b : h_b;
    const float* WcA = Wc + (size_t)L*1024*128;
    const float* WcB = WcA + (size_t)640*128;
    const float* bcA = bc + (size_t)L*1024;
    const float* bcB = bcA + 640;
    // tiled projection GEMMs emit q + relation-transformed ktv directly
    gemm_tile<<<dim3(nba, 5),dim3(256),0,stream>>>(xa_in, WcA, bcA, qbuf, ktvA, Na, 640, 0,  0,    Na);
    gemm_tile<<<dim3(nbb, 3),dim3(256),0,stream>>>(xb_in, WcB, bcB, qbuf, ktvA, Nb, 384, Na, 2*Na, 2*Na);
    seg_attn<<<dim3((N+3)/4),dim3(256),0,stream>>>(qbuf, ktvA, roff, epack, agg, Na, N);
    int do_gelu = (L == 0) ? 0 : 1;
    finish_tile<<<dim3(nba + nbb),dim3(256),0,stream>>>(agg, xa_in, xb_in, h_a, h_b,
                                                        Wout + (size_t)L*2*16384,
                                                        bout + (size_t)L*2*128,
                                                        skip + L*2, do_gelu, Na, Nb);
    if (L == 0) {
      ln_gelu2<<<dim3((N+3)/4),dim3(256),0,stream>>>(hbuf, ln_g, ln_b, Na, N);
    }
  }

  // ---- GAT scorer + SAGPool top-k + MLP ----
  gat_x1<<<dim3((N+3)/4),dim3(256),0,stream>>>(hbuf, Wgat, x1buf, N);
  gat_all<<<dim3((N+255)/256),dim3(256),0,stream>>>(x1buf, roff, epack, att_src, att_dst, Na, N, score);
  int tk_blocks = (N + 255)/256;
  topk_stage1<<<dim3(tk_blocks),dim3(256),0,stream>>>(score, bgat, N, cvals, cidx);
  topk_stage2<<<dim3(1),dim3(256),0,stream>>>(cvals, cidx, tk_blocks*8, valsb, permb);
  mlp_final<<<dim3(1),dim3(256),0,stream>>>(hbuf, valsb, permb, W1, b1, W2, b2, W3, b3, (float*)d_out);
}

// Round 12
// 781.243 us; speedup vs baseline: 1.3432x; 1.0521x over previous
//
#include <hip/hip_runtime.h>
#include <math.h>

#define HID 128

__device__ __forceinline__ float gelu_f(float x){
  return 0.5f*x*(1.0f+erff(x*0.70710678118654752440f));
}

// ---------- combined-weight precompute ----------
// Folds per-edge-type relation transforms (and prel/sqrt(d)/log2e scale) into the
// KQV projection. Wc layout per layer L: [a: 128x640][b: 128x384], bc: [a 640][b 384].
__global__ void mkw(const float* __restrict__ Wkqv, const float* __restrict__ bkqv,
                    const float* __restrict__ arel, const float* __restrict__ mrel,
                    const float* __restrict__ prel,
                    float* __restrict__ Wc, float* __restrict__ bc) {
  int L = blockIdx.x >> 10;
  int j = blockIdx.x & 1023;          // 0..1023: a cols 0..639, b cols 640..1023
  int t = threadIdx.x;                // k-row 0..127
  int type = (j < 640) ? 0 : 1;
  int jj = (j < 640) ? j : j - 640;
  const float* W    = Wkqv + ((size_t)L*2 + type)*49152;   // 128 x 384 (k|q|v)
  const float* bsrc = bkqv + ((size_t)L*2 + type)*384;
  int stride = type ? 384 : 640;
  float* Wdst = Wc + (size_t)L*(640+384)*128 + (type ? (size_t)640*128 : 0);
  float* bdst = bc + (size_t)L*1024 + (type ? 640 : 0);
  float val, bval;
  if (jj < 128) {                     // q passthrough
    val  = W[(size_t)t*384 + 128 + jj];
    bval = bsrc[128 + jj];
  } else {
    int u = jj - 128;
    int et = type ? 2 : (u >> 8);
    int r = u & 255;
    int h = r >> 6, wofs = r & 63;
    const float* rel; int coloff; float scl;
    if (wofs < 32) {                  // k-transform col, scale folded
      rel = arel + ((size_t)L*3 + et)*4096 + (size_t)h*32*32 + wofs;
      coloff = h*32;
      scl = prel[((size_t)L*3 + et)*4 + h] * 0.17677669529663688f * 1.4426950408889634f;
    } else {                          // v-transform col
      rel = mrel + ((size_t)L*3 + et)*4096 + (size_t)h*32*32 + (wofs - 32);
      coloff = 256 + h*32;
      scl = 1.0f;
    }
    float a = 0.f, bb = 0.f;
    for (int d = 0; d < 32; d++) {
      float rv = rel[(size_t)d*32];
      a  += W[(size_t)t*384 + coloff + d] * rv;
      bb += bsrc[coloff + d] * rv;
    }
    val = a * scl; bval = bb * scl;
  }
  Wdst[(size_t)t*stride + jj] = val;
  if (t == 0) bdst[jj] = bval;
}

// ---------- fused 128x128 LDS-tiled projection GEMM, both node types ----------
// grid.x = nba*5 + nbb*3; each block: one 128-row strip x one 128-col tile.
__global__ __launch_bounds__(256, 2)
void gemm_tile2(const float* __restrict__ xa, const float* __restrict__ xb,
                const float* __restrict__ WcA, const float* __restrict__ WcB,
                const float* __restrict__ bcA, const float* __restrict__ bcB,
                float* __restrict__ qbuf, float* __restrict__ ktv,
                int Na, int Nb, int nba, int nbb) {
  __shared__ float xs[32][132];
  __shared__ float ws[32][128];
  int bid = blockIdx.x;
  bool typeA = bid < nba*5;
  const float *x, *Wc, *bc;
  int nrows, r0, ct, OUT;
  if (typeA) { ct = bid / nba; int rb = bid % nba; x = xa; Wc = WcA; bc = bcA; nrows = Na; r0 = rb*128; OUT = 640; }
  else { int idx = bid - nba*5; ct = idx / nbb; int rb = idx % nbb; x = xb; Wc = WcB; bc = bcB; nrows = Nb; r0 = rb*128; OUT = 384; }
  int tid = threadIdx.x;
  int ty = tid >> 4, tx = tid & 15;
  float acc[8][8] = {};
  for (int kc = 0; kc < 128; kc += 32) {
    __syncthreads();
#pragma unroll
    for (int it = 0; it < 4; it++) {
      int idx = it*256 + tid;
      int r = idx >> 3;
      int k4 = (idx & 7) << 2;
      int row = r0 + r;
      float4 v = (row < nrows) ? *(const float4*)(x + (size_t)row*128 + kc + k4)
                               : make_float4(0.f, 0.f, 0.f, 0.f);
      xs[k4+0][r] = v.x; xs[k4+1][r] = v.y; xs[k4+2][r] = v.z; xs[k4+3][r] = v.w;
    }
#pragma unroll
    for (int it = 0; it < 4; it++) {
      int idx = it*256 + tid;
      int k = idx >> 5;
      int c4 = (idx & 31) << 2;
      *(float4*)&ws[k][c4] = *(const float4*)(Wc + (size_t)(kc + k)*OUT + ct*128 + c4);
    }
    __syncthreads();
#pragma unroll
    for (int k = 0; k < 32; k++) {
      float4 a0 = *(const float4*)&xs[k][ty*4];
      float4 a1 = *(const float4*)&xs[k][64 + ty*4];
      float4 b0 = *(const float4*)&ws[k][tx*4];
      float4 b1 = *(const float4*)&ws[k][64 + tx*4];
      float av[8] = {a0.x,a0.y,a0.z,a0.w,a1.x,a1.y,a1.z,a1.w};
      float bv[8] = {b0.x,b0.y,b0.z,b0.w,b1.x,b1.y,b1.z,b1.w};
#pragma unroll
      for (int i = 0; i < 8; i++)
#pragma unroll
        for (int j = 0; j < 8; j++)
          acc[i][j] += av[i]*bv[j];
    }
  }
  bool isq = (ct == 0);
  int qoff = typeA ? 0 : Na;
  int sbase = 0, cofs = 0;
  if (!isq) {
    if (typeA) { if (ct <= 2) { sbase = 0;  cofs = (ct-1)*128; } else { sbase = Na; cofs = (ct-3)*128; } }
    else       { sbase = 2*Na; cofs = (ct-1)*128; }
  }
#pragma unroll
  for (int i = 0; i < 8; i++) {
    int r = (i < 4) ? (ty*4 + i) : (64 + ty*4 + i - 4);
    int row = r0 + r;
    if (row >= nrows) continue;
#pragma unroll
    for (int half = 0; half < 2; half++) {
      int c0 = half*64 + tx*4;
      float4 v;
      v.x = acc[i][half*4+0] + bc[ct*128 + c0 + 0];
      v.y = acc[i][half*4+1] + bc[ct*128 + c0 + 1];
      v.z = acc[i][half*4+2] + bc[ct*128 + c0 + 2];
      v.w = acc[i][half*4+3] + bc[ct*128 + c0 + 3];
      if (isq) *(float4*)(qbuf + (size_t)(qoff + row)*128 + c0) = v;
      else     *(float4*)(ktv + (size_t)(sbase + row)*256 + cofs + c0) = v;
    }
  }
}

// ---------- tiled finish: gelu(agg)@Wout + gated skip, fused LN (L0) / x1 (L2) ----------
// mode: 0 = LN then gelu (layer 0); 1 = gelu; 2 = gelu + write x1 = dot(h, Wgat)
__global__ __launch_bounds__(256, 2)
void finish_tile(const float* __restrict__ agg,
                 const float* __restrict__ xa, const float* __restrict__ xb,
                 float* __restrict__ ha, float* __restrict__ hb,
                 const float* __restrict__ WoL, const float* __restrict__ boL,
                 const float* __restrict__ skipL,
                 const float* __restrict__ lng, const float* __restrict__ lnb,
                 const float* __restrict__ Wg, float* __restrict__ x1,
                 int mode, int Na, int Nb) {
  __shared__ float xs[32][132];
  __shared__ float ws[32][128];
  int nba = (Na + 127) >> 7;
  const float *xsrc, *Wo, *bo; float* h; float sgraw; int nrows, r0, aggoff, po;
  if ((int)blockIdx.x < nba) {
    xsrc = xa; h = ha; Wo = WoL; bo = boL; sgraw = skipL[0];
    nrows = Na; r0 = blockIdx.x*128; aggoff = 0; po = 0;
  } else {
    xsrc = xb; h = hb; Wo = WoL + 16384; bo = boL + 128; sgraw = skipL[1];
    nrows = Nb; r0 = ((int)blockIdx.x - nba)*128; aggoff = Na; po = 128;
  }
  int tid = threadIdx.x;
  int ty = tid >> 4, tx = tid & 15;
  float acc[8][8] = {};
  for (int kc = 0; kc < 128; kc += 32) {
    __syncthreads();
#pragma unroll
    for (int it = 0; it < 4; it++) {
      int idx = it*256 + tid;
      int r = idx >> 3;
      int k4 = (idx & 7) << 2;
      int row = r0 + r;
      float4 v = (row < nrows)
        ? *(const float4*)(agg + (size_t)(aggoff + row)*128 + kc + k4)
        : make_float4(0.f, 0.f, 0.f, 0.f);
      xs[k4+0][r] = gelu_f(v.x); xs[k4+1][r] = gelu_f(v.y);
      xs[k4+2][r] = gelu_f(v.z); xs[k4+3][r] = gelu_f(v.w);
    }
#pragma unroll
    for (int it = 0; it < 4; it++) {
      int idx = it*256 + tid;
      int k = idx >> 5;
      int c4 = (idx & 31) << 2;
      *(float4*)&ws[k][c4] = *(const float4*)(Wo + (size_t)(kc + k)*128 + c4);
    }
    __syncthreads();
#pragma unroll
    for (int k = 0; k < 32; k++) {
      float4 a0 = *(const float4*)&xs[k][ty*4];
      float4 a1 = *(const float4*)&xs[k][64 + ty*4];
      float4 b0 = *(const float4*)&ws[k][tx*4];
      float4 b1 = *(const float4*)&ws[k][64 + tx*4];
      float av[8] = {a0.x,a0.y,a0.z,a0.w,a1.x,a1.y,a1.z,a1.w};
      float bv[8] = {b0.x,b0.y,b0.z,b0.w,b1.x,b1.y,b1.z,b1.w};
#pragma unroll
      for (int i = 0; i < 8; i++)
#pragma unroll
        for (int j = 0; j < 8; j++)
          acc[i][j] += av[i]*bv[j];
    }
  }
  float sg = 1.f/(1.f + expf(-sgraw));
#pragma unroll
  for (int i = 0; i < 8; i++) {
    int r = (i < 4) ? (ty*4 + i) : (64 + ty*4 + i - 4);
    int row = r0 + r;
    if (row >= nrows) continue;   // all 16 lanes of this row-group skip together
    int c0 = tx*4, c1 = 64 + tx*4;
    float4 xv0 = *(const float4*)(xsrc + (size_t)row*128 + c0);
    float4 xv1 = *(const float4*)(xsrc + (size_t)row*128 + c1);
    float v[8];
    v[0] = sg*(acc[i][0] + bo[c0+0]) + (1.f-sg)*xv0.x;
    v[1] = sg*(acc[i][1] + bo[c0+1]) + (1.f-sg)*xv0.y;
    v[2] = sg*(acc[i][2] + bo[c0+2]) + (1.f-sg)*xv0.z;
    v[3] = sg*(acc[i][3] + bo[c0+3]) + (1.f-sg)*xv0.w;
    v[4] = sg*(acc[i][4] + bo[c1+0]) + (1.f-sg)*xv1.x;
    v[5] = sg*(acc[i][5] + bo[c1+1]) + (1.f-sg)*xv1.y;
    v[6] = sg*(acc[i][6] + bo[c1+2]) + (1.f-sg)*xv1.z;
    v[7] = sg*(acc[i][7] + bo[c1+3]) + (1.f-sg)*xv1.w;
    if (mode == 0) {
      // LayerNorm over the 128-col row (16 consecutive lanes share the row)
      float sum = v[0]+v[1]+v[2]+v[3]+v[4]+v[5]+v[6]+v[7];
      sum += __shfl_xor(sum, 1, 64); sum += __shfl_xor(sum, 2, 64);
      sum += __shfl_xor(sum, 4, 64); sum += __shfl_xor(sum, 8, 64);
      float mu = sum * (1.f/128.f);
      float var = 0.f;
#pragma unroll
      for (int j = 0; j < 8; j++) { float d = v[j]-mu; var += d*d; }
      var += __shfl_xor(var, 1, 64); var += __shfl_xor(var, 2, 64);
      var += __shfl_xor(var, 4, 64); var += __shfl_xor(var, 8, 64);
      float inv = 1.f / sqrtf(var*(1.f/128.f) + 1e-5f);
#pragma unroll
      for (int j = 0; j < 8; j++) {
        int c = (j < 4) ? (c0 + j) : (c1 + j - 4);
        v[j] = gelu_f((v[j]-mu)*inv*lng[po + c] + lnb[po + c]);
      }
    } else {
#pragma unroll
      for (int j = 0; j < 8; j++) v[j] = gelu_f(v[j]);
    }
    float4 o0; o0.x=v[0]; o0.y=v[1]; o0.z=v[2]; o0.w=v[3];
    float4 o1; o1.x=v[4]; o1.y=v[5]; o1.z=v[6]; o1.w=v[7];
    *(float4*)(h + (size_t)row*128 + c0) = o0;
    *(float4*)(h + (size_t)row*128 + c1) = o1;
    if (mode == 2) {
      float s1 = v[0]*Wg[c0+0] + v[1]*Wg[c0+1] + v[2]*Wg[c0+2] + v[3]*Wg[c0+3]
               + v[4]*Wg[c1+0] + v[5]*Wg[c1+1] + v[6]*Wg[c1+2] + v[7]*Wg[c1+3];
      s1 += __shfl_xor(s1, 1, 64); s1 += __shfl_xor(s1, 2, 64);
      s1 += __shfl_xor(s1, 4, 64); s1 += __shfl_xor(s1, 8, 64);
      if (tx == 0) x1[(size_t)aggoff ? (size_t)row + Na : (size_t)row] = s1;  // global node idx
    }
  }
}

// ---------- CSR build (dst-sorted; pure edges, no self loops) ----------
__global__ void hist_init(int* __restrict__ hist, int N) {
  int i = blockIdx.x*blockDim.x + threadIdx.x;
  if (i < N) hist[i] = 0;
}
__global__ void hist_count_all(const int* __restrict__ aa, const int* __restrict__ ab,
                               const int* __restrict__ ba,
                               int Eaa, int Eab, int Eba, int Na, int* __restrict__ hist) {
  int i = blockIdx.x*blockDim.x + threadIdx.x;
  int tot = Eaa + Eab + Eba;
  if (i >= tot) return;
  int dst;
  if (i < Eaa)            dst = aa[Eaa + i];
  else if (i < Eaa + Eab) dst = ab[Eab + (i - Eaa)] + Na;
  else                    dst = ba[Eba + (i - Eaa - Eab)];
  atomicAdd(hist + dst, 1);
}
// three-stage parallel exclusive scan
__global__ void scan_part(const int* __restrict__ hist, int* __restrict__ bsum, int N) {
  __shared__ int sd[256];
  int t = threadIdx.x;
  int i = blockIdx.x*256 + t;
  sd[t] = (i < N) ? hist[i] : 0;
  __syncthreads();
  for (int o = 128; o; o >>= 1) { if (t < o) sd[t] += sd[t+o]; __syncthreads(); }
  if (t == 0) bsum[blockIdx.x] = sd[0];
}
__global__ void scan_bsum(int* __restrict__ bsum, int nb) {
  __shared__ int sd[1024];
  int t = threadIdx.x;
  sd[t] = (t < nb) ? bsum[t] : 0;
  __syncthreads();
  for (int o = 1; o < 1024; o <<= 1) {
    int v = (t >= o) ? sd[t-o] : 0;
    __syncthreads();
    sd[t] += v;
    __syncthreads();
  }
  if (t < nb) bsum[t] = sd[t];
}
__global__ void scan_fill(const int* __restrict__ hist, const int* __restrict__ bsum,
                          int* __restrict__ roff, int* __restrict__ cursor, int N) {
  __shared__ int sd[256];
  int t = threadIdx.x;
  int i = blockIdx.x*256 + t;
  int v = (i < N) ? hist[i] : 0;
  sd[t] = v;
  __syncthreads();
  for (int o = 1; o < 256; o <<= 1) {
    int u = (t >= o) ? sd[t-o] : 0;
    __syncthreads();
    sd[t] += u;
    __syncthreads();
  }
  int boff = (blockIdx.x == 0) ? 0 : bsum[blockIdx.x - 1];
  if (i < N) {
    int excl = boff + sd[t] - v;
    roff[i] = excl;
    cursor[i] = excl;
    if (i == N - 1) roff[N] = boff + sd[t];
  }
}
__global__ void fill_all(const int* __restrict__ aa, const int* __restrict__ ab,
                         const int* __restrict__ ba,
                         int Eaa, int Eab, int Eba, int Na,
                         int* __restrict__ cursor, int* __restrict__ epack) {
  int i = blockIdx.x*blockDim.x + threadIdx.x;
  int tot = Eaa + Eab + Eba;
  if (i >= tot) return;
  int dst, slot;
  if (i < Eaa)            { dst = aa[Eaa + i];                slot = aa[i]; }
  else if (i < Eaa + Eab) { int j = i - Eaa;       dst = ab[Eab + j] + Na; slot = ab[j] + Na; }
  else                    { int j = i - Eaa - Eab; dst = ba[Eba + j];      slot = ba[j] + 2*Na; }
  int pos = atomicAdd(cursor + dst, 1);
  epack[pos] = slot;
}

// ---------- fused HGT attention, 4-way edge-parallel, depth-2 prefetch ----------
__global__ void seg_attn(const float* __restrict__ qbuf,
                         const float* __restrict__ ktv,
                         const int* __restrict__ roff, const int* __restrict__ epack,
                         float* __restrict__ agg, int Na, int N) {
  int wid = (blockIdx.x*blockDim.x + threadIdx.x) >> 6;
  int lane = threadIdx.x & 63;
  if (wid >= N) return;
  int quarter = lane >> 4;
  int u = lane & 15;
  int h = u >> 2;               // head
  int d0 = (u & 3) * 8;         // 8 dims of head h
  const float* qp = qbuf + (size_t)wid*128 + h*32 + d0;
  float4 qa = *(const float4*)qp;
  float4 qb = *(const float4*)(qp + 4);
  int beg = roff[wid], end = roff[wid + 1];
  float m = -1e30f, s = 0.f;
  float4 aA = make_float4(0.f,0.f,0.f,0.f), aB = make_float4(0.f,0.f,0.f,0.f);
  int i = beg + quarter;
  float4 ka0, kb0, va0, vb0, ka1, kb1, va1, vb1;
  if (i < end) {
    const float* kp = ktv + (size_t)epack[i]*256 + h*64 + d0;
    ka0 = *(const float4*)kp;      kb0 = *(const float4*)(kp + 4);
    va0 = *(const float4*)(kp+32); vb0 = *(const float4*)(kp + 36);
  }
  if (i + 4 < end) {
    const float* kp = ktv + (size_t)epack[i+4]*256 + h*64 + d0;
    ka1 = *(const float4*)kp;      kb1 = *(const float4*)(kp + 4);
    va1 = *(const float4*)(kp+32); vb1 = *(const float4*)(kp + 36);
  }
  for (; i < end; i += 4) {
    float4 cka = ka0, ckb = kb0, cva = va0, cvb = vb0;
    ka0 = ka1; kb0 = kb1; va0 = va1; vb0 = vb1;
    int nx = i + 8;
    if (nx < end) {               // prefetch 2 ahead in this stream
      const float* kp = ktv + (size_t)epack[nx]*256 + h*64 + d0;
      ka1 = *(const float4*)kp;      kb1 = *(const float4*)(kp + 4);
      va1 = *(const float4*)(kp+32); vb1 = *(const float4*)(kp + 36);
    }
    float sc = qa.x*cka.x + qa.y*cka.y + qa.z*cka.z + qa.w*cka.w
             + qb.x*ckb.x + qb.y*ckb.y + qb.z*ckb.z + qb.w*ckb.w;
    sc += __shfl_xor(sc, 1, 64);
    sc += __shfl_xor(sc, 2, 64);
    float nm = fmaxf(m, sc);
    float scale = exp2f(m - nm);
    float e = exp2f(sc - nm);
    s = s*scale + e;
    aA.x = aA.x*scale + e*cva.x; aA.y = aA.y*scale + e*cva.y;
    aA.z = aA.z*scale + e*cva.z; aA.w = aA.w*scale + e*cva.w;
    aB.x = aB.x*scale + e*cvb.x; aB.y = aB.y*scale + e*cvb.y;
    aB.z = aB.z*scale + e*cvb.z; aB.w = aB.w*scale + e*cvb.w;
    m = nm;
  }
  // merge the 4 quarter states (butterfly over xor 16, 32)
#pragma unroll
  for (int off = 16; off <= 32; off <<= 1) {
    float mo = __shfl_xor(m, off, 64);
    float so = __shfl_xor(s, off, 64);
    float A0 = __shfl_xor(aA.x, off, 64), A1 = __shfl_xor(aA.y, off, 64);
    float A2 = __shfl_xor(aA.z, off, 64), A3 = __shfl_xor(aA.w, off, 64);
    float B0 = __shfl_xor(aB.x, off, 64), B1 = __shfl_xor(aB.y, off, 64);
    float B2 = __shfl_xor(aB.z, off, 64), B3 = __shfl_xor(aB.w, off, 64);
    float nm = fmaxf(m, mo);
    float c1 = exp2f(m - nm), c2 = exp2f(mo - nm);
    s = s*c1 + so*c2;
    aA.x = aA.x*c1 + A0*c2; aA.y = aA.y*c1 + A1*c2;
    aA.z = aA.z*c1 + A2*c2; aA.w = aA.w*c1 + A3*c2;
    aB.x = aB.x*c1 + B0*c2; aB.y = aB.y*c1 + B1*c2;
    aB.z = aB.z*c1 + B2*c2; aB.w = aB.w*c1 + B3*c2;
    m = nm;
  }
  if (quarter == 0) {
    float inv = 1.f / (s + 1e-16f);
    float4 o1, o2;
    o1.x = aA.x*inv; o1.y = aA.y*inv; o1.z = aA.z*inv; o1.w = aA.w*inv;
    o2.x = aB.x*inv; o2.y = aB.y*inv; o2.z = aB.z*inv; o2.w = aB.w*inv;
    float* op = agg + (size_t)wid*128 + h*32 + d0;
    *(float4*)op = o1;
    *(float4*)(op + 4) = o2;
  }
}

// fused GAT scorer via CSR: thread per node, online softmax (self-loop inline)
__global__ void gat_all(const float* __restrict__ x1, const int* __restrict__ roff,
                        const int* __restrict__ epack,
                        const float* __restrict__ asrc, const float* __restrict__ adst,
                        int Na, int N, float* __restrict__ score) {
  int n = blockIdx.x*blockDim.x + threadIdx.x;
  if (n >= N) return;
  float xd = x1[n];
  float as_ = asrc[0], ad = adst[0];
  float e0 = xd*as_ + xd*ad;
  e0 = (e0 > 0.f) ? e0 : 0.2f*e0;
  float m = e0, s = 1.f, acc = xd;
  int beg = roff[n], end = roff[n + 1];
  for (int i = beg; i < end; i++) {
    int slot = epack[i];
    int sg = (slot < Na) ? slot : slot - Na;
    float xs = x1[sg];
    float e = xs*as_ + xd*ad;
    e = (e > 0.f) ? e : 0.2f*e;
    float nm = fmaxf(m, e);
    float sc = __expf(m - nm), ee = __expf(e - nm);
    s = s*sc + ee;  acc = acc*sc + ee*xs;  m = nm;
  }
  score[n] = acc / (s + 1e-16f);
}

// ---- parallel top-8 ----
__global__ void topk_stage1(const float* __restrict__ score, const float* __restrict__ bgat,
                            int N, float* __restrict__ cvals, int* __restrict__ cidx) {
  __shared__ float bv[256];
  __shared__ int   bi[256];
  int t = threadIdx.x;
  int chunk = (N + gridDim.x - 1) / gridDim.x;
  int i = blockIdx.x * chunk + t;
  float bg = bgat[0];
  bool valid = (t < chunk && i < N);
  float myv = valid ? score[i] + bg : -INFINITY;
  int   myi = valid ? i : 0x7FFFFFFF;
  for (int k = 0; k < 8; k++) {
    bv[t] = myv; bi[t] = myi;
    __syncthreads();
    for (int o = 128; o; o >>= 1) {
      if (t < o) {
        if (bv[t+o] > bv[t] || (bv[t+o] == bv[t] && bi[t+o] < bi[t])) { bv[t]=bv[t+o]; bi[t]=bi[t+o]; }
      }
      __syncthreads();
    }
    if (t == 0) { cvals[blockIdx.x*8 + k] = bv[0]; cidx[blockIdx.x*8 + k] = bi[0]; }
    if (myi == bi[0]) myv = -INFINITY;
    __syncthreads();
  }
}

// merged: top-8 merge + scorer-gated MLP head (single block)
__global__ void topk_mlp(const float* __restrict__ cvals, const int* __restrict__ cidx, int C,
                         const float* __restrict__ h,
                         const float* __restrict__ W1, const float* __restrict__ b1,
                         const float* __restrict__ W2, const float* __restrict__ b2,
                         const float* __restrict__ W3, const float* __restrict__ b3,
                         float* __restrict__ out) {
  __shared__ float bv[256];
  __shared__ int   bi[256];
  __shared__ int   seli[8];
  __shared__ float sval[8];
  __shared__ float hp[1024], v1[128], v2[64];
  int t = threadIdx.x;
  for (int k = 0; k < 8; k++) {
    float best = -INFINITY; int besti = 0x7FFFFFFF;
    for (int i = t; i < C; i += 256) {
      int id = cidx[i];
      bool taken = false;
      for (int j = 0; j < k; j++) if (seli[j] == id) taken = true;
      if (taken) continue;
      float v = cvals[i];
      if (v > best || (v == best && id < besti)) { best = v; besti = id; }
    }
    bv[t] = best; bi[t] = besti;
    __syncthreads();
    for (int o = 128; o; o >>= 1) {
      if (t < o) {
        if (bv[t+o] > bv[t] || (bv[t+o] == bv[t] && bi[t+o] < bi[t])) { bv[t]=bv[t+o]; bi[t]=bi[t+o]; }
      }
      __syncthreads();
    }
    if (t == 0) { seli[k] = bi[0]; sval[k] = bv[0]; }
    __syncthreads();
  }
  for (int i = t; i < 1024; i += 256) {
    int r = i >> 7, d = i & 127;
    hp[i] = h[(size_t)seli[r]*128 + d] * tanhf(sval[r]);
  }
  __syncthreads();
  if (t < 128) {
    float a = 0.f;
    for (int k = 0; k < 1024; k++) a += hp[k]*W1[(size_t)k*128 + t];
    v1[t] = gelu_f(a + b1[t]);
  }
  __syncthreads();
  if (t < 64) {
    float a = 0.f;
    for (int k = 0; k < 128; k++) a += v1[k]*W2[(size_t)k*64 + t];
    v2[t] = gelu_f(a + b2[t]);
  }
  __syncthreads();
  if (t < 16) {
    float a = 0.f;
    for (int k = 0; k < 64; k++) a += v2[k]*W3[(size_t)k*16 + t];
    float r = gelu_f(a + b3[t]);
    if (isnan(r)) r = 0.f;
    else if (isinf(r)) r = (r > 0.f) ? 3.4028234663852886e38f : -3.4028234663852886e38f;
    out[t] = r;
  }
}

extern "C" void kernel_launch(void* const* d_in, const int* in_sizes, int n_in,
                              void* d_out, int out_size, void* d_ws, size_t ws_size,
                              hipStream_t stream) {
  const float* x_a  = (const float*)d_in[0];
  const float* x_b  = (const float*)d_in[1];
  const int* ei_aa  = (const int*)d_in[2];
  const int* ei_ab  = (const int*)d_in[3];
  const int* ei_ba  = (const int*)d_in[4];
  const float* Wkqv = (const float*)d_in[5];
  const float* bkqv = (const float*)d_in[6];
  const float* Wout = (const float*)d_in[7];
  const float* bout = (const float*)d_in[8];
  const float* skip = (const float*)d_in[9];
  const float* arel = (const float*)d_in[10];
  const float* mrel = (const float*)d_in[11];
  const float* prel = (const float*)d_in[12];
  const float* ln_g = (const float*)d_in[13];
  const float* ln_b = (const float*)d_in[14];
  const float* Wgat = (const float*)d_in[15];
  const float* att_src = (const float*)d_in[16];
  const float* att_dst = (const float*)d_in[17];
  const float* bgat = (const float*)d_in[18];
  const float* W1 = (const float*)d_in[19];
  const float* b1 = (const float*)d_in[20];
  const float* W2 = (const float*)d_in[21];
  const float* b2 = (const float*)d_in[22];
  const float* W3 = (const float*)d_in[23];
  const float* b3 = (const float*)d_in[24];

  int Na = in_sizes[0]/128, Nb = in_sizes[1]/128, N = Na + Nb;
  int Eaa = in_sizes[2]/2, Eab = in_sizes[3]/2, Eba = in_sizes[4]/2;
  int Etot = Eaa + Eab + Eba;

  // workspace layout
  float* w = (float*)d_ws;
  size_t off = 0;
  auto alloc = [&](size_t n) { float* p = w + off; off += n; return p; };
  float* hbuf  = alloc((size_t)N*128);
  float* qbuf  = alloc((size_t)N*128);
  float* ktvA  = alloc((size_t)(2*Na + Nb)*256);
  float* agg   = alloc((size_t)N*128);
  float* Wc    = alloc((size_t)3*1024*128);
  float* bc    = alloc((size_t)3*1024);
  float* x1buf = alloc((size_t)N);
  float* score = alloc((size_t)N);
  float* cvals = alloc(2048);
  int*   cidx  = (int*)alloc(2048);
  int*   hist  = (int*)alloc((size_t)N);
  int*   roff  = (int*)alloc((size_t)N + 1);
  int*   cursor= (int*)alloc((size_t)N);
  int*   bsum  = (int*)alloc(1024);
  int*   epack = (int*)alloc((size_t)Etot);

  float* h_a = hbuf;
  float* h_b = hbuf + (size_t)Na*128;

  // ---- precompute combined projection weights ----
  mkw<<<dim3(3*1024),dim3(128),0,stream>>>(Wkqv, bkqv, arel, mrel, prel, Wc, bc);

  // ---- build dst-sorted CSR once ----
  int nsb = (N + 255)/256;
  hist_init<<<dim3(nsb),dim3(256),0,stream>>>(hist, N);
  hist_count_all<<<dim3((Etot+255)/256),dim3(256),0,stream>>>(ei_aa, ei_ab, ei_ba, Eaa, Eab, Eba, Na, hist);
  scan_part<<<dim3(nsb),dim3(256),0,stream>>>(hist, bsum, N);
  scan_bsum<<<dim3(1),dim3(1024),0,stream>>>(bsum, nsb);
  scan_fill<<<dim3(nsb),dim3(256),0,stream>>>(hist, bsum, roff, cursor, N);
  fill_all<<<dim3((Etot+255)/256),dim3(256),0,stream>>>(ei_aa, ei_ab, ei_ba, Eaa, Eab, Eba, Na, cursor, epack);

  int nba = (Na + 127)/128, nbb = (Nb + 127)/128;

  for (int L = 0; L < 3; L++) {
    const float* xa_in = (L == 0) ? x_a : h_a;
    const float* xb_in = (L == 0) ? x_b : h_b;
    const float* WcA = Wc + (size_t)L*1024*128;
    const float* WcB = WcA + (size_t)640*128;
    const float* bcA = bc + (size_t)L*1024;
    const float* bcB = bcA + 640;
    gemm_tile2<<<dim3(nba*5 + nbb*3),dim3(256),0,stream>>>(xa_in, xb_in, WcA, WcB, bcA, bcB,
                                                           qbuf, ktvA, Na, Nb, nba, nbb);
    seg_attn<<<dim3((N+3)/4),dim3(256),0,stream>>>(qbuf, ktvA, roff, epack, agg, Na, N);
    int mode = (L == 0) ? 0 : (L == 2 ? 2 : 1);
    finish_tile<<<dim3(nba + nbb),dim3(256),0,stream>>>(agg, xa_in, xb_in, h_a, h_b,
                                                        Wout + (size_t)L*2*16384,
                                                        bout + (size_t)L*2*128,
                                                        skip + L*2, ln_g, ln_b,
                                                        Wgat, x1buf, mode, Na, Nb);
  }

  // ---- GAT scorer + SAGPool top-k + MLP ----
  gat_all<<<dim3((N+255)/256),dim3(256),0,stream>>>(x1buf, roff, epack, att_src, att_dst, Na, N, score);
  int tk_blocks = (N + 255)/256;
  topk_stage1<<<dim3(tk_blocks),dim3(256),0,stream>>>(score, bgat, N, cvals, cidx);
  topk_mlp<<<dim3(1),dim3(256),0,stream>>>(cvals, cidx, tk_blocks*8, hbuf,
                                           W1, b1, W2, b2, W3, b3, (float*)d_out);
}